// Round 2
// baseline (5044.822 us; speedup 1.0000x reference)
//
#include <hip/hip_runtime.h>

constexpr int N_ = 10000, H_ = 64, P_ = 12, NB_ = 3, IN_ = 3, E_ = 160000, B_ = 2;
constexpr int S_  = B_ * P_;     // 24 slices (b,p)
constexpr int NH_ = N_ * H_;     // 640000 elements per slice
constexpr float EPS_ = 1e-5f;

#define DEVFN __device__ __forceinline__

DEVFN float softmax4(const float* a, int k) {
    float m = fmaxf(fmaxf(a[0], a[1]), fmaxf(a[2], a[3]));
    float e0 = __expf(a[0] - m), e1 = __expf(a[1] - m);
    float e2 = __expf(a[2] - m), e3 = __expf(a[3] - m);
    float s = e0 + e1 + e2 + e3;
    float ek = (k == 0 ? e0 : k == 1 ? e1 : k == 2 ? e2 : e3);
    return ek / s;
}

DEVFN float wred(float v) {
#pragma unroll
    for (int d = 32; d; d >>= 1) v += __shfl_xor(v, d, 64);
    return v;
}

// ---- CSR build -------------------------------------------------------------
__global__ void k_deg(const int* __restrict__ ei, int* __restrict__ deg) {
    int e = blockIdx.x * 256 + threadIdx.x;
    if (e < E_) atomicAdd(&deg[ei[E_ + e]], 1);
}

__global__ void k_scan(const int* __restrict__ deg, int* __restrict__ offs,
                       int* __restrict__ cursor, float* __restrict__ dis) {
    __shared__ int part[1024];
    int t = threadIdx.x;
    int base = t * 10;
    int cnt = 0;
    for (int k = 0; k < 10; k++) { int i = base + k; if (i < N_) cnt += deg[i]; }
    part[t] = cnt;
    __syncthreads();
    for (int d = 1; d < 1024; d <<= 1) {
        int v = 0;
        if (t >= d) v = part[t - d];
        __syncthreads();
        if (t >= d) part[t] += v;
        __syncthreads();
    }
    int run = (t > 0) ? part[t - 1] : 0;
    for (int k = 0; k < 10; k++) {
        int i = base + k;
        if (i < N_) {
            offs[i] = run; cursor[i] = run;
            int dg = deg[i];
            dis[i] = dg > 0 ? rsqrtf((float)dg) : 0.f;
            run += dg;
        }
    }
    if (t == 1023) offs[N_] = part[1023];
}

__global__ void k_scatter(const int* __restrict__ ei, const float* __restrict__ dis,
                          int* __restrict__ cursor, int* __restrict__ csr_row,
                          float* __restrict__ csr_nrm) {
    int e = blockIdx.x * 256 + threadIdx.x;
    if (e >= E_) return;
    int r = ei[e], c = ei[E_ + e];
    float nm = dis[r] * dis[c];
    int p = atomicAdd(&cursor[c], 1);
    csr_row[p] = r;
    csr_nrm[p] = nm;
}

// ---- pos projection: pos[N,64] -> pp[N,64] ---------------------------------
__global__ void k_posproj(const float* __restrict__ pos, const float* __restrict__ w1,
                          const float* __restrict__ b1, const float* __restrict__ w2,
                          const float* __restrict__ b2, float* __restrict__ out) {
    __shared__ float w1T[64 * 65], w2T[64 * 65];
    __shared__ float stage[4][64];
    int t = threadIdx.x;
    for (int k = t; k < 4096; k += 256) {
        int o = k >> 6, j = k & 63;
        w1T[j * 65 + o] = w1[k];
        w2T[j * 65 + o] = w2[k];
    }
    __syncthreads();
    int w = t >> 6, lane = t & 63;
    int n = blockIdx.x * 4 + w;
    float v = pos[n * 64 + lane];
    stage[w][lane] = v;
    float h = b1[lane];
#pragma unroll
    for (int j = 0; j < 64; j++) h = fmaf(w1T[j * 65 + lane], stage[w][j], h);
    h = fmaxf(h, 0.f);
    stage[w][lane] = h;
    float o2 = b2[lane];
#pragma unroll
    for (int j = 0; j < 64; j++) o2 = fmaf(w2T[j * 65 + lane], stage[w][j], o2);
    out[n * 64 + lane] = o2;
}

// ---- input projection + pos add + acc init + stats -------------------------
__global__ void k_in(const float* __restrict__ xin, const float* __restrict__ iw1,
                     const float* __restrict__ ib1, const float* __restrict__ iw2,
                     const float* __restrict__ ib2, const float* __restrict__ pp,
                     const float* __restrict__ attn, float* __restrict__ x0,
                     float* __restrict__ acc, float* __restrict__ st1) {
    __shared__ float w2T[64 * 65];
    __shared__ float stage[4][64];
    __shared__ float bs[2];
    __shared__ float sa0;
    int t = threadIdx.x;
    for (int k = t; k < 4096; k += 256) {
        int o = k >> 6, j = k & 63;
        w2T[j * 65 + o] = iw2[k];
    }
    if (t == 0) { bs[0] = 0.f; bs[1] = 0.f; sa0 = softmax4(attn, 0); }
    __syncthreads();
    int w = t >> 6, lane = t & 63;
    int wid = blockIdx.x * 4 + w;          // < S_*N_ ; all 4 waves share s (2500 blocks/slice)
    int s = wid / N_, n = wid % N_;
    const float* xi = xin + ((size_t)s * N_ + n) * IN_;
    float a0 = xi[0], a1 = xi[1], a2 = xi[2];
    float h = ib1[lane] + iw1[lane * 3 + 0] * a0 + iw1[lane * 3 + 1] * a1 + iw1[lane * 3 + 2] * a2;
    h = fmaxf(h, 0.f);
    stage[w][lane] = h;
    float v = ib2[lane];
#pragma unroll
    for (int j = 0; j < 64; j++) v = fmaf(w2T[j * 65 + lane], stage[w][j], v);
    v += pp[n * 64 + lane];
    size_t idx = (size_t)s * NH_ + n * 64 + lane;
    x0[idx] = v;
    acc[idx] = sa0 * v;
    float sm = wred(v), sq = wred(v * v);
    if (lane == 0) { atomicAdd(&bs[0], sm); atomicAdd(&bs[1], sq); }
    __syncthreads();
    if (t == 0) { atomicAdd(&st1[s * 2], bs[0]); atomicAdd(&st1[s * 2 + 1], bs[1]); }
}

// ---- in-place LayerNorm apply (per-slice scalar stats) ---------------------
__global__ void k_ln(float* __restrict__ x, const float* __restrict__ w,
                     const float* __restrict__ b, const float* __restrict__ st) {
    int g = blockIdx.x * 256 + threadIdx.x;  // float4 index, < S_*NH_/4
    int s = g / (NH_ / 4);
    int r = g % (NH_ / 4);
    float mu = st[s * 2] * (1.f / NH_);
    float var = st[s * 2 + 1] * (1.f / NH_) - mu * mu;
    float rs = rsqrtf(var + EPS_);
    float4 xv = ((const float4*)x)[g];
    float4 wv = ((const float4*)w)[r];
    float4 bv = ((const float4*)b)[r];
    float4 o;
    o.x = (xv.x - mu) * rs * wv.x + bv.x;
    o.y = (xv.y - mu) * rs * wv.y + bv.y;
    o.z = (xv.z - mu) * rs * wv.z + bv.z;
    o.w = (xv.w - mu) * rs * wv.w + bv.w;
    ((float4*)x)[g] = o;
}

// ---- LightGCN propagate (gather over CSR) + stats of output ----------------
__global__ void k_prop(const float* __restrict__ x, const int* __restrict__ offs,
                       const int* __restrict__ csr_row, const float* __restrict__ csr_nrm,
                       float* __restrict__ y, float* __restrict__ st2) {
    __shared__ float bs[2];
    int t = threadIdx.x;
    if (t == 0) { bs[0] = 0.f; bs[1] = 0.f; }
    __syncthreads();
    int w = t >> 6, lane = t & 63;
    int wid = blockIdx.x * 4 + w;
    int s = wid / N_, n = wid % N_;
    const float* xs = x + (size_t)s * NH_;
    int e0 = offs[n], e1 = offs[n + 1];
    float acc = 0.f;
    for (int e = e0; e < e1; e++) {
        int r = csr_row[e];
        float nm = csr_nrm[e];
        acc = fmaf(nm, xs[r * 64 + lane], acc);
    }
    y[(size_t)s * NH_ + n * 64 + lane] = acc;
    float sm = wred(acc), sq = wred(acc * acc);
    if (lane == 0) { atomicAdd(&bs[0], sm); atomicAdd(&bs[1], sq); }
    __syncthreads();
    if (t == 0) { atomicAdd(&st2[s * 2], bs[0]); atomicAdd(&st2[s * 2 + 1], bs[1]); }
}

// ---- LN2 (inline) + 12x12 period mix + skip-acc + next-iter stats ----------
__global__ void k_mix(const float* __restrict__ y, const float* __restrict__ tnw,
                      const float* __restrict__ tnb, const float* __restrict__ tcw,
                      const float* __restrict__ tcb, const float* __restrict__ st2,
                      const float* __restrict__ attn, int ai, float* __restrict__ xn,
                      float* __restrict__ acc, float* __restrict__ st1n) {
    __shared__ float smu[12], srs[12], scw[144], scb[12], sstat[24];
    __shared__ float sa;
    int t = threadIdx.x;
    int gt = blockIdx.x * 256 + t;         // < B_*NH_ ; all threads in block share b
    int b = gt / NH_, r = gt % NH_;
    if (t < 12) {
        int s = b * 12 + t;
        float mu = st2[s * 2] * (1.f / NH_);
        float var = st2[s * 2 + 1] * (1.f / NH_) - mu * mu;
        smu[t] = mu;
        srs[t] = rsqrtf(var + EPS_);
        scb[t] = tcb[t];
    }
    if (t < 144) scw[t] = tcw[t];
    if (t < 24) sstat[t] = 0.f;
    if (t == 0) sa = softmax4(attn, ai);
    __syncthreads();
    float wv = tnw[r], bv = tnb[r];
    float yn[12];
#pragma unroll
    for (int p = 0; p < 12; p++) {
        float v = y[(size_t)(b * 12 + p) * NH_ + r];
        yn[p] = (v - smu[p]) * srs[p] * wv + bv;
    }
    float ov[12];
#pragma unroll
    for (int q = 0; q < 12; q++) {
        float o = scb[q];
#pragma unroll
        for (int p = 0; p < 12; p++) o = fmaf(scw[q * 12 + p], yn[p], o);
        ov[q] = o;
        size_t idx = (size_t)(b * 12 + q) * NH_ + r;
        xn[idx] = o;
        acc[idx] += sa * o;
    }
    int lane = t & 63;
#pragma unroll
    for (int q = 0; q < 12; q++) {
        float sm = wred(ov[q]);
        float sq = wred(ov[q] * ov[q]);
        if (lane == 0) { atomicAdd(&sstat[q * 2], sm); atomicAdd(&sstat[q * 2 + 1], sq); }
    }
    __syncthreads();
    if (t < 24) {
        int q = t >> 1, c = t & 1;
        atomicAdd(&st1n[(b * 12 + q) * 2 + c], sstat[t]);
    }
}

// ---- final output projection, in-place on d_out ----------------------------
__global__ void k_out(float* __restrict__ io, const float* __restrict__ w1,
                      const float* __restrict__ b1, const float* __restrict__ w2,
                      const float* __restrict__ b2) {
    __shared__ float w1T[64 * 65], w2T[64 * 65];
    __shared__ float stage[4][64];
    int t = threadIdx.x;
    for (int k = t; k < 4096; k += 256) {
        int o = k >> 6, j = k & 63;
        w1T[j * 65 + o] = w1[k];
        w2T[j * 65 + o] = w2[k];
    }
    __syncthreads();
    int w = t >> 6, lane = t & 63;
    int wid = blockIdx.x * 4 + w;
    int s = wid / N_, n = wid % N_;
    size_t base = (size_t)s * NH_ + n * 64;
    float v = io[base + lane];
    stage[w][lane] = v;
    float h = b1[lane];
#pragma unroll
    for (int j = 0; j < 64; j++) h = fmaf(w1T[j * 65 + lane], stage[w][j], h);
    h = fmaxf(h, 0.f);
    stage[w][lane] = h;
    float o2 = b2[lane];
#pragma unroll
    for (int j = 0; j < 64; j++) o2 = fmaf(w2T[j * 65 + lane], stage[w][j], o2);
    io[base + lane] = o2;
}

extern "C" void kernel_launch(void* const* d_in, const int* in_sizes, int n_in,
                              void* d_out, int out_size, void* d_ws, size_t ws_size,
                              hipStream_t stream) {
    (void)in_sizes; (void)n_in; (void)out_size; (void)ws_size;
    const float* x    = (const float*)d_in[0];
    const int*   ei   = (const int*)d_in[1];
    const float* pos  = (const float*)d_in[2];
    const float* iw1  = (const float*)d_in[3];
    const float* ib1  = (const float*)d_in[4];
    const float* iw2  = (const float*)d_in[5];
    const float* ib2  = (const float*)d_in[6];
    const float* pw1  = (const float*)d_in[7];
    const float* pb1  = (const float*)d_in[8];
    const float* pw2  = (const float*)d_in[9];
    const float* pb2  = (const float*)d_in[10];
    const float* attn = (const float*)d_in[11];
    const float* gnw  = (const float*)d_in[12];
    const float* gnb  = (const float*)d_in[13];
    const float* tnw  = (const float*)d_in[14];
    const float* tnb  = (const float*)d_in[15];
    const float* tcw  = (const float*)d_in[16];
    const float* tcb  = (const float*)d_in[17];
    const float* ow1  = (const float*)d_in[18];
    const float* ob1  = (const float*)d_in[19];
    const float* ow2  = (const float*)d_in[20];
    const float* ob2  = (const float*)d_in[21];
    float* out = (float*)d_out;

    float* xA = (float*)d_ws;
    float* xB = xA + (size_t)S_ * NH_;
    float* yb = xB + (size_t)S_ * NH_;
    float* pp = yb + (size_t)S_ * NH_;
    float* csr_nrm = pp + NH_;
    int* csr_row = (int*)(csr_nrm + E_);
    int* deg     = csr_row + E_;
    int* offs    = deg + N_;
    int* cursor  = offs + N_ + 1;
    float* dis   = (float*)(cursor + N_);
    float* st1   = dis + N_;             // 4 iters * 24 slices * 2
    float* st2   = st1 + 4 * S_ * 2;     // 3 iters * 24 slices * 2

    size_t zbytes = (size_t)((char*)(st2 + 3 * S_ * 2) - (char*)deg);
    hipMemsetAsync(deg, 0, zbytes, stream);

    k_deg<<<(E_ + 255) / 256, 256, 0, stream>>>(ei, deg);
    k_scan<<<1, 1024, 0, stream>>>(deg, offs, cursor, dis);
    k_scatter<<<(E_ + 255) / 256, 256, 0, stream>>>(ei, dis, cursor, csr_row, csr_nrm);
    k_posproj<<<N_ / 4, 256, 0, stream>>>(pos, pw1, pb1, pw2, pb2, pp);
    k_in<<<S_ * N_ / 4, 256, 0, stream>>>(x, iw1, ib1, iw2, ib2, pp, attn, xA, out, st1);

    float* cur = xA;
    float* nxt = xB;
    for (int i = 0; i < NB_; i++) {
        k_ln<<<S_ * NH_ / 4 / 256, 256, 0, stream>>>(cur, gnw + (size_t)i * NH_,
                                                     gnb + (size_t)i * NH_, st1 + i * S_ * 2);
        k_prop<<<S_ * N_ / 4, 256, 0, stream>>>(cur, offs, csr_row, csr_nrm, yb,
                                                st2 + i * S_ * 2);
        k_mix<<<B_ * NH_ / 256, 256, 0, stream>>>(yb, tnw + (size_t)i * NH_,
                                                  tnb + (size_t)i * NH_, tcw + i * 144,
                                                  tcb + i * 12, st2 + i * S_ * 2, attn, i + 1,
                                                  nxt, out, st1 + (i + 1) * S_ * 2);
        float* tmp = cur; cur = nxt; nxt = tmp;
    }
    k_out<<<S_ * N_ / 4, 256, 0, stream>>>(out, ow1, ob1, ow2, ob2);
}

// Round 3
// 4751.535 us; speedup vs baseline: 1.0617x; 1.0617x over previous
//
#include <hip/hip_runtime.h>

constexpr int N_ = 10000, H_ = 64, P_ = 12, NB_ = 3, IN_ = 3, E_ = 160000, B_ = 2;
constexpr int S_  = B_ * P_;     // 24 slices (b,p)
constexpr int NH_ = N_ * H_;     // 640000 elements per slice
constexpr float EPS_ = 1e-5f;

#define DEVFN __device__ __forceinline__

DEVFN float softmax4(const float* a, int k) {
    float m = fmaxf(fmaxf(a[0], a[1]), fmaxf(a[2], a[3]));
    float e0 = __expf(a[0] - m), e1 = __expf(a[1] - m);
    float e2 = __expf(a[2] - m), e3 = __expf(a[3] - m);
    float s = e0 + e1 + e2 + e3;
    float ek = (k == 0 ? e0 : k == 1 ? e1 : k == 2 ? e2 : e3);
    return ek / s;
}

DEVFN float wred(float v) {
#pragma unroll
    for (int d = 32; d; d >>= 1) v += __shfl_xor(v, d, 64);
    return v;
}

// ---- CSR build -------------------------------------------------------------
__global__ void k_deg(const int* __restrict__ ei, int* __restrict__ deg) {
    int e = blockIdx.x * 256 + threadIdx.x;
    if (e < E_) atomicAdd(&deg[ei[E_ + e]], 1);
}

__global__ void k_scan(const int* __restrict__ deg, int* __restrict__ offs,
                       int* __restrict__ cursor, float* __restrict__ dis) {
    __shared__ int part[1024];
    int t = threadIdx.x;
    int base = t * 10;
    int cnt = 0;
    for (int k = 0; k < 10; k++) { int i = base + k; if (i < N_) cnt += deg[i]; }
    part[t] = cnt;
    __syncthreads();
    for (int d = 1; d < 1024; d <<= 1) {
        int v = 0;
        if (t >= d) v = part[t - d];
        __syncthreads();
        if (t >= d) part[t] += v;
        __syncthreads();
    }
    int run = (t > 0) ? part[t - 1] : 0;
    for (int k = 0; k < 10; k++) {
        int i = base + k;
        if (i < N_) {
            offs[i] = run; cursor[i] = run;
            int dg = deg[i];
            dis[i] = dg > 0 ? rsqrtf((float)dg) : 0.f;
            run += dg;
        }
    }
    if (t == 1023) offs[N_] = part[1023];
}

__global__ void k_scatter(const int* __restrict__ ei, const float* __restrict__ dis,
                          int* __restrict__ cursor, int* __restrict__ csr_row,
                          float* __restrict__ csr_nrm) {
    int e = blockIdx.x * 256 + threadIdx.x;
    if (e >= E_) return;
    int r = ei[e], c = ei[E_ + e];
    float nm = dis[r] * dis[c];
    int p = atomicAdd(&cursor[c], 1);
    csr_row[p] = r;
    csr_nrm[p] = nm;
}

// ---- pos projection: pos[N,64] -> pp[N,64] ---------------------------------
__global__ void k_posproj(const float* __restrict__ pos, const float* __restrict__ w1,
                          const float* __restrict__ b1, const float* __restrict__ w2,
                          const float* __restrict__ b2, float* __restrict__ out) {
    __shared__ float w1T[64 * 65], w2T[64 * 65];
    __shared__ float stage[4][64];
    int t = threadIdx.x;
    for (int k = t; k < 4096; k += 256) {
        int o = k >> 6, j = k & 63;
        w1T[j * 65 + o] = w1[k];
        w2T[j * 65 + o] = w2[k];
    }
    __syncthreads();
    int w = t >> 6, lane = t & 63;
    int n = blockIdx.x * 4 + w;
    float v = pos[n * 64 + lane];
    stage[w][lane] = v;
    float h = b1[lane];
#pragma unroll
    for (int j = 0; j < 64; j++) h = fmaf(w1T[j * 65 + lane], stage[w][j], h);
    h = fmaxf(h, 0.f);
    stage[w][lane] = h;
    float o2 = b2[lane];
#pragma unroll
    for (int j = 0; j < 64; j++) o2 = fmaf(w2T[j * 65 + lane], stage[w][j], o2);
    out[n * 64 + lane] = o2;
}

// ---- input projection + pos add + acc init + stats -------------------------
__global__ void k_in(const float* __restrict__ xin, const float* __restrict__ iw1,
                     const float* __restrict__ ib1, const float* __restrict__ iw2,
                     const float* __restrict__ ib2, const float* __restrict__ pp,
                     const float* __restrict__ attn, float* __restrict__ x0,
                     float* __restrict__ acc, float* __restrict__ st1) {
    __shared__ float w2T[64 * 65];
    __shared__ float stage[4][64];
    __shared__ float bs[2];
    __shared__ float sa0;
    int t = threadIdx.x;
    for (int k = t; k < 4096; k += 256) {
        int o = k >> 6, j = k & 63;
        w2T[j * 65 + o] = iw2[k];
    }
    if (t == 0) { bs[0] = 0.f; bs[1] = 0.f; sa0 = softmax4(attn, 0); }
    __syncthreads();
    int w = t >> 6, lane = t & 63;
    int wid = blockIdx.x * 4 + w;          // < S_*N_ ; all 4 waves share s (2500 blocks/slice)
    int s = wid / N_, n = wid % N_;
    const float* xi = xin + ((size_t)s * N_ + n) * IN_;
    float a0 = xi[0], a1 = xi[1], a2 = xi[2];
    float h = ib1[lane] + iw1[lane * 3 + 0] * a0 + iw1[lane * 3 + 1] * a1 + iw1[lane * 3 + 2] * a2;
    h = fmaxf(h, 0.f);
    stage[w][lane] = h;
    float v = ib2[lane];
#pragma unroll
    for (int j = 0; j < 64; j++) v = fmaf(w2T[j * 65 + lane], stage[w][j], v);
    v += pp[n * 64 + lane];
    size_t idx = (size_t)s * NH_ + n * 64 + lane;
    x0[idx] = v;
    acc[idx] = sa0 * v;
    float sm = wred(v), sq = wred(v * v);
    if (lane == 0) { atomicAdd(&bs[0], sm); atomicAdd(&bs[1], sq); }
    __syncthreads();
    if (t == 0) { atomicAdd(&st1[s * 2], bs[0]); atomicAdd(&st1[s * 2 + 1], bs[1]); }
}

// ---- in-place LayerNorm apply (per-slice scalar stats) ---------------------
__global__ void k_ln(float* __restrict__ x, const float* __restrict__ w,
                     const float* __restrict__ b, const float* __restrict__ st) {
    int g = blockIdx.x * 256 + threadIdx.x;  // float4 index, < S_*NH_/4
    int s = g / (NH_ / 4);
    int r = g % (NH_ / 4);
    float mu = st[s * 2] * (1.f / NH_);
    float var = st[s * 2 + 1] * (1.f / NH_) - mu * mu;
    float rs = rsqrtf(var + EPS_);
    float4 xv = ((const float4*)x)[g];
    float4 wv = ((const float4*)w)[r];
    float4 bv = ((const float4*)b)[r];
    float4 o;
    o.x = (xv.x - mu) * rs * wv.x + bv.x;
    o.y = (xv.y - mu) * rs * wv.y + bv.y;
    o.z = (xv.z - mu) * rs * wv.z + bv.z;
    o.w = (xv.w - mu) * rs * wv.w + bv.w;
    ((float4*)x)[g] = o;
}

// ---- LightGCN propagate (gather over CSR, 4 edge-streams/wave) -------------
__global__ void k_prop(const float* __restrict__ x, const int* __restrict__ offs,
                       const int* __restrict__ csr_row, const float* __restrict__ csr_nrm,
                       float* __restrict__ y, float* __restrict__ st2) {
    __shared__ float bs[2];
    int t = threadIdx.x;
    if (t == 0) { bs[0] = 0.f; bs[1] = 0.f; }
    __syncthreads();
    int w = t >> 6, lane = t & 63;
    int sub = lane >> 4;        // 0..3: edge sub-stream
    int hl  = lane & 15;        // float4 column (h = 4*hl .. 4*hl+3)
    int wid = blockIdx.x * 4 + w;
    int s = wid / N_, n = wid % N_;
    const float4* xs = (const float4*)(x + (size_t)s * NH_);
    int e0 = offs[n], e1 = offs[n + 1];
    float4 acc = make_float4(0.f, 0.f, 0.f, 0.f);
    int e = e0 + sub;
    // 2-deep pipeline x 4 sub-streams = 8 edges in flight per wave
    for (; e + 4 < e1; e += 8) {
        int   r0 = csr_row[e];
        int   r1 = csr_row[e + 4];
        float m0 = csr_nrm[e];
        float m1 = csr_nrm[e + 4];
        float4 a = xs[r0 * 16 + hl];
        float4 b = xs[r1 * 16 + hl];
        acc.x = fmaf(m0, a.x, acc.x); acc.y = fmaf(m0, a.y, acc.y);
        acc.z = fmaf(m0, a.z, acc.z); acc.w = fmaf(m0, a.w, acc.w);
        acc.x = fmaf(m1, b.x, acc.x); acc.y = fmaf(m1, b.y, acc.y);
        acc.z = fmaf(m1, b.z, acc.z); acc.w = fmaf(m1, b.w, acc.w);
    }
    if (e < e1) {
        int r = csr_row[e];
        float m = csr_nrm[e];
        float4 a = xs[r * 16 + hl];
        acc.x = fmaf(m, a.x, acc.x); acc.y = fmaf(m, a.y, acc.y);
        acc.z = fmaf(m, a.z, acc.z); acc.w = fmaf(m, a.w, acc.w);
    }
    // reduce the 4 sub-streams (lanes differing in bits 4..5)
    acc.x += __shfl_xor(acc.x, 16, 64); acc.y += __shfl_xor(acc.y, 16, 64);
    acc.z += __shfl_xor(acc.z, 16, 64); acc.w += __shfl_xor(acc.w, 16, 64);
    acc.x += __shfl_xor(acc.x, 32, 64); acc.y += __shfl_xor(acc.y, 32, 64);
    acc.z += __shfl_xor(acc.z, 32, 64); acc.w += __shfl_xor(acc.w, 32, 64);
    if (sub == 0) ((float4*)(y + (size_t)s * NH_ + n * 64))[hl] = acc;
    float sm = 0.f, sq = 0.f;
    if (sub == 0) {
        sm = acc.x + acc.y + acc.z + acc.w;
        sq = acc.x * acc.x + acc.y * acc.y + acc.z * acc.z + acc.w * acc.w;
    }
    sm = wred(sm);
    sq = wred(sq);
    if (lane == 0) { atomicAdd(&bs[0], sm); atomicAdd(&bs[1], sq); }
    __syncthreads();
    if (t == 0) { atomicAdd(&st2[s * 2], bs[0]); atomicAdd(&st2[s * 2 + 1], bs[1]); }
}

// ---- LN2 (inline) + 12x12 period mix + skip-acc + next-iter stats ----------
__global__ void k_mix(const float* __restrict__ y, const float* __restrict__ tnw,
                      const float* __restrict__ tnb, const float* __restrict__ tcw,
                      const float* __restrict__ tcb, const float* __restrict__ st2,
                      const float* __restrict__ attn, int ai, float* __restrict__ xn,
                      float* __restrict__ acc, float* __restrict__ st1n) {
    __shared__ float smu[12], srs[12], scw[144], scb[12], sstat[24];
    __shared__ float sa;
    int t = threadIdx.x;
    int gt = blockIdx.x * 256 + t;         // < B_*NH_ ; all threads in block share b
    int b = gt / NH_, r = gt % NH_;
    if (t < 12) {
        int s = b * 12 + t;
        float mu = st2[s * 2] * (1.f / NH_);
        float var = st2[s * 2 + 1] * (1.f / NH_) - mu * mu;
        smu[t] = mu;
        srs[t] = rsqrtf(var + EPS_);
        scb[t] = tcb[t];
    }
    if (t < 144) scw[t] = tcw[t];
    if (t < 24) sstat[t] = 0.f;
    if (t == 0) sa = softmax4(attn, ai);
    __syncthreads();
    float wv = tnw[r], bv = tnb[r];
    float yn[12];
#pragma unroll
    for (int p = 0; p < 12; p++) {
        float v = y[(size_t)(b * 12 + p) * NH_ + r];
        yn[p] = (v - smu[p]) * srs[p] * wv + bv;
    }
    float ov[12];
#pragma unroll
    for (int q = 0; q < 12; q++) {
        float o = scb[q];
#pragma unroll
        for (int p = 0; p < 12; p++) o = fmaf(scw[q * 12 + p], yn[p], o);
        ov[q] = o;
        size_t idx = (size_t)(b * 12 + q) * NH_ + r;
        xn[idx] = o;
        acc[idx] += sa * o;
    }
    int lane = t & 63;
#pragma unroll
    for (int q = 0; q < 12; q++) {
        float sm = wred(ov[q]);
        float sq = wred(ov[q] * ov[q]);
        if (lane == 0) { atomicAdd(&sstat[q * 2], sm); atomicAdd(&sstat[q * 2 + 1], sq); }
    }
    __syncthreads();
    if (t < 24) {
        int q = t >> 1, c = t & 1;
        atomicAdd(&st1n[(b * 12 + q) * 2 + c], sstat[t]);
    }
}

// ---- final output projection, in-place on d_out ----------------------------
__global__ void k_out(float* __restrict__ io, const float* __restrict__ w1,
                      const float* __restrict__ b1, const float* __restrict__ w2,
                      const float* __restrict__ b2) {
    __shared__ float w1T[64 * 65], w2T[64 * 65];
    __shared__ float stage[4][64];
    int t = threadIdx.x;
    for (int k = t; k < 4096; k += 256) {
        int o = k >> 6, j = k & 63;
        w1T[j * 65 + o] = w1[k];
        w2T[j * 65 + o] = w2[k];
    }
    __syncthreads();
    int w = t >> 6, lane = t & 63;
    int wid = blockIdx.x * 4 + w;
    int s = wid / N_, n = wid % N_;
    size_t base = (size_t)s * NH_ + n * 64;
    float v = io[base + lane];
    stage[w][lane] = v;
    float h = b1[lane];
#pragma unroll
    for (int j = 0; j < 64; j++) h = fmaf(w1T[j * 65 + lane], stage[w][j], h);
    h = fmaxf(h, 0.f);
    stage[w][lane] = h;
    float o2 = b2[lane];
#pragma unroll
    for (int j = 0; j < 64; j++) o2 = fmaf(w2T[j * 65 + lane], stage[w][j], o2);
    io[base + lane] = o2;
}

extern "C" void kernel_launch(void* const* d_in, const int* in_sizes, int n_in,
                              void* d_out, int out_size, void* d_ws, size_t ws_size,
                              hipStream_t stream) {
    (void)in_sizes; (void)n_in; (void)out_size; (void)ws_size;
    const float* x    = (const float*)d_in[0];
    const int*   ei   = (const int*)d_in[1];
    const float* pos  = (const float*)d_in[2];
    const float* iw1  = (const float*)d_in[3];
    const float* ib1  = (const float*)d_in[4];
    const float* iw2  = (const float*)d_in[5];
    const float* ib2  = (const float*)d_in[6];
    const float* pw1  = (const float*)d_in[7];
    const float* pb1  = (const float*)d_in[8];
    const float* pw2  = (const float*)d_in[9];
    const float* pb2  = (const float*)d_in[10];
    const float* attn = (const float*)d_in[11];
    const float* gnw  = (const float*)d_in[12];
    const float* gnb  = (const float*)d_in[13];
    const float* tnw  = (const float*)d_in[14];
    const float* tnb  = (const float*)d_in[15];
    const float* tcw  = (const float*)d_in[16];
    const float* tcb  = (const float*)d_in[17];
    const float* ow1  = (const float*)d_in[18];
    const float* ob1  = (const float*)d_in[19];
    const float* ow2  = (const float*)d_in[20];
    const float* ob2  = (const float*)d_in[21];
    float* out = (float*)d_out;

    float* xA = (float*)d_ws;
    float* xB = xA + (size_t)S_ * NH_;
    float* yb = xB + (size_t)S_ * NH_;
    float* pp = yb + (size_t)S_ * NH_;
    float* csr_nrm = pp + NH_;
    int* csr_row = (int*)(csr_nrm + E_);
    int* deg     = csr_row + E_;
    int* offs    = deg + N_;
    int* cursor  = offs + N_ + 1;
    float* dis   = (float*)(cursor + N_);
    float* st1   = dis + N_;             // 4 iters * 24 slices * 2
    float* st2   = st1 + 4 * S_ * 2;     // 3 iters * 24 slices * 2

    size_t zbytes = (size_t)((char*)(st2 + 3 * S_ * 2) - (char*)deg);
    hipMemsetAsync(deg, 0, zbytes, stream);

    k_deg<<<(E_ + 255) / 256, 256, 0, stream>>>(ei, deg);
    k_scan<<<1, 1024, 0, stream>>>(deg, offs, cursor, dis);
    k_scatter<<<(E_ + 255) / 256, 256, 0, stream>>>(ei, dis, cursor, csr_row, csr_nrm);
    k_posproj<<<N_ / 4, 256, 0, stream>>>(pos, pw1, pb1, pw2, pb2, pp);
    k_in<<<S_ * N_ / 4, 256, 0, stream>>>(x, iw1, ib1, iw2, ib2, pp, attn, xA, out, st1);

    float* cur = xA;
    float* nxt = xB;
    for (int i = 0; i < NB_; i++) {
        k_ln<<<S_ * NH_ / 4 / 256, 256, 0, stream>>>(cur, gnw + (size_t)i * NH_,
                                                     gnb + (size_t)i * NH_, st1 + i * S_ * 2);
        k_prop<<<S_ * N_ / 4, 256, 0, stream>>>(cur, offs, csr_row, csr_nrm, yb,
                                                st2 + i * S_ * 2);
        k_mix<<<B_ * NH_ / 256, 256, 0, stream>>>(yb, tnw + (size_t)i * NH_,
                                                  tnb + (size_t)i * NH_, tcw + i * 144,
                                                  tcb + i * 12, st2 + i * S_ * 2, attn, i + 1,
                                                  nxt, out, st1 + (i + 1) * S_ * 2);
        float* tmp = cur; cur = nxt; nxt = tmp;
    }
    k_out<<<S_ * N_ / 4, 256, 0, stream>>>(out, ow1, ob1, ow2, ob2);
}

// Round 4
// 1200.315 us; speedup vs baseline: 4.2029x; 3.9586x over previous
//
#include <hip/hip_runtime.h>
#include <stdint.h>

constexpr int N_ = 10000, H_ = 64, P_ = 12, NB_ = 3, IN_ = 3, E_ = 160000, B_ = 2;
constexpr int S_  = B_ * P_;     // 24 slices (b,p)
constexpr int NH_ = N_ * H_;     // 640000 elements per slice
constexpr int BPS_ = N_ / 4;     // 2500 blocks per slice for node-kernels
constexpr float EPS_ = 1e-5f;

#define DEVFN __device__ __forceinline__

DEVFN float softmax4(const float* a, int k) {
    float m = fmaxf(fmaxf(a[0], a[1]), fmaxf(a[2], a[3]));
    float e0 = __expf(a[0] - m), e1 = __expf(a[1] - m);
    float e2 = __expf(a[2] - m), e3 = __expf(a[3] - m);
    float s = e0 + e1 + e2 + e3;
    float ek = (k == 0 ? e0 : k == 1 ? e1 : k == 2 ? e2 : e3);
    return ek / s;
}

DEVFN float wred(float v) {
#pragma unroll
    for (int d = 32; d; d >>= 1) v += __shfl_xor(v, d, 64);
    return v;
}

// ---- CSR build -------------------------------------------------------------
__global__ void k_deg(const int* __restrict__ ei, int* __restrict__ deg) {
    int e = blockIdx.x * 256 + threadIdx.x;
    if (e < E_) atomicAdd(&deg[ei[E_ + e]], 1);
}

__global__ void k_scan(const int* __restrict__ deg, int* __restrict__ offs,
                       int* __restrict__ cursor, float* __restrict__ dis) {
    __shared__ int part[1024];
    int t = threadIdx.x;
    int base = t * 10;
    int cnt = 0;
    for (int k = 0; k < 10; k++) { int i = base + k; if (i < N_) cnt += deg[i]; }
    part[t] = cnt;
    __syncthreads();
    for (int d = 1; d < 1024; d <<= 1) {
        int v = 0;
        if (t >= d) v = part[t - d];
        __syncthreads();
        if (t >= d) part[t] += v;
        __syncthreads();
    }
    int run = (t > 0) ? part[t - 1] : 0;
    for (int k = 0; k < 10; k++) {
        int i = base + k;
        if (i < N_) {
            offs[i] = run; cursor[i] = run;
            int dg = deg[i];
            dis[i] = dg > 0 ? rsqrtf((float)dg) : 0.f;
            run += dg;
        }
    }
    if (t == 1023) offs[N_] = part[1023];
}

__global__ void k_scatter(const int* __restrict__ ei, const float* __restrict__ dis,
                          int* __restrict__ cursor, int* __restrict__ csr_row,
                          float* __restrict__ csr_nrm) {
    int e = blockIdx.x * 256 + threadIdx.x;
    if (e >= E_) return;
    int r = ei[e], c = ei[E_ + e];
    float nm = dis[r] * dis[c];
    int p = atomicAdd(&cursor[c], 1);
    csr_row[p] = r;
    csr_nrm[p] = nm;
}

// ---- per-slice stats reduce: part[s][0..2500) -> st[s*2], st[s*2+1] --------
__global__ void k_red(const float2* __restrict__ part, float* __restrict__ st) {
    __shared__ float rsm[4], rsq[4];
    int s = blockIdx.x, t = threadIdx.x, w = t >> 6, lane = t & 63;
    float sm = 0.f, sq = 0.f;
    for (int k = t; k < BPS_; k += 256) {
        float2 p = part[s * BPS_ + k];
        sm += p.x; sq += p.y;
    }
    sm = wred(sm); sq = wred(sq);
    if (lane == 0) { rsm[w] = sm; rsq[w] = sq; }
    __syncthreads();
    if (t == 0) {
        st[s * 2]     = rsm[0] + rsm[1] + rsm[2] + rsm[3];
        st[s * 2 + 1] = rsq[0] + rsq[1] + rsq[2] + rsq[3];
    }
}

// ---- pos projection: pos[N,64] -> pp[N,64] ---------------------------------
__global__ void k_posproj(const float* __restrict__ pos, const float* __restrict__ w1,
                          const float* __restrict__ b1, const float* __restrict__ w2,
                          const float* __restrict__ b2, float* __restrict__ out) {
    __shared__ float w1T[64 * 65], w2T[64 * 65];
    __shared__ float stage[4][64];
    int t = threadIdx.x;
    for (int k = t; k < 4096; k += 256) {
        int o = k >> 6, j = k & 63;
        w1T[j * 65 + o] = w1[k];
        w2T[j * 65 + o] = w2[k];
    }
    __syncthreads();
    int w = t >> 6, lane = t & 63;
    int n = blockIdx.x * 4 + w;
    float v = pos[n * 64 + lane];
    stage[w][lane] = v;
    float h = b1[lane];
#pragma unroll
    for (int j = 0; j < 64; j++) h = fmaf(w1T[j * 65 + lane], stage[w][j], h);
    h = fmaxf(h, 0.f);
    stage[w][lane] = h;
    float o2 = b2[lane];
#pragma unroll
    for (int j = 0; j < 64; j++) o2 = fmaf(w2T[j * 65 + lane], stage[w][j], o2);
    out[n * 64 + lane] = o2;
}

// ---- input projection + pos add + acc init + stats partials ----------------
__global__ void k_in(const float* __restrict__ xin, const float* __restrict__ iw1,
                     const float* __restrict__ ib1, const float* __restrict__ iw2,
                     const float* __restrict__ ib2, const float* __restrict__ pp,
                     const float* __restrict__ attn, float* __restrict__ x0,
                     float* __restrict__ acc, float2* __restrict__ part) {
    __shared__ float w2T[64 * 65];
    __shared__ float stage[4][64];
    __shared__ float bsm[4], bsq[4];
    __shared__ float sa0;
    int t = threadIdx.x;
    for (int k = t; k < 4096; k += 256) {
        int o = k >> 6, j = k & 63;
        w2T[j * 65 + o] = iw2[k];
    }
    if (t == 0) sa0 = softmax4(attn, 0);
    __syncthreads();
    int w = t >> 6, lane = t & 63;
    int wid = blockIdx.x * 4 + w;          // all 4 waves share slice s
    int s = wid / N_, n = wid % N_;
    const float* xi = xin + ((size_t)s * N_ + n) * IN_;
    float a0 = xi[0], a1 = xi[1], a2 = xi[2];
    float h = ib1[lane] + iw1[lane * 3 + 0] * a0 + iw1[lane * 3 + 1] * a1 + iw1[lane * 3 + 2] * a2;
    h = fmaxf(h, 0.f);
    stage[w][lane] = h;
    float v = ib2[lane];
#pragma unroll
    for (int j = 0; j < 64; j++) v = fmaf(w2T[j * 65 + lane], stage[w][j], v);
    v += pp[n * 64 + lane];
    size_t idx = (size_t)s * NH_ + n * 64 + lane;
    x0[idx] = v;
    acc[idx] = sa0 * v;
    float sm = wred(v), sq = wred(v * v);
    if (lane == 0) { bsm[w] = sm; bsq[w] = sq; }
    __syncthreads();
    if (t == 0) {
        float2 p;
        p.x = bsm[0] + bsm[1] + bsm[2] + bsm[3];
        p.y = bsq[0] + bsq[1] + bsq[2] + bsq[3];
        part[s * BPS_ + (blockIdx.x % BPS_)] = p;
    }
}

// ---- in-place LayerNorm apply (per-slice scalar stats) ---------------------
__global__ void k_ln(float* __restrict__ x, const float* __restrict__ w,
                     const float* __restrict__ b, const float* __restrict__ st) {
    int g = blockIdx.x * 256 + threadIdx.x;  // float4 index, < S_*NH_/4
    int s = g / (NH_ / 4);
    int r = g % (NH_ / 4);
    float mu = st[s * 2] * (1.f / NH_);
    float var = st[s * 2 + 1] * (1.f / NH_) - mu * mu;
    float rs = rsqrtf(var + EPS_);
    float4 xv = ((const float4*)x)[g];
    float4 wv = ((const float4*)w)[r];
    float4 bv = ((const float4*)b)[r];
    float4 o;
    o.x = (xv.x - mu) * rs * wv.x + bv.x;
    o.y = (xv.y - mu) * rs * wv.y + bv.y;
    o.z = (xv.z - mu) * rs * wv.z + bv.z;
    o.w = (xv.w - mu) * rs * wv.w + bv.w;
    ((float4*)x)[g] = o;
}

// ---- LightGCN propagate (gather over CSR, 4 edge-streams/wave) -------------
__global__ void k_prop(const float* __restrict__ x, const int* __restrict__ offs,
                       const int* __restrict__ csr_row, const float* __restrict__ csr_nrm,
                       float* __restrict__ y, float2* __restrict__ part) {
    __shared__ float bsm[4], bsq[4];
    int t = threadIdx.x;
    int w = t >> 6, lane = t & 63;
    int sub = lane >> 4;        // 0..3: edge sub-stream
    int hl  = lane & 15;        // float4 column (h = 4*hl .. 4*hl+3)
    int wid = blockIdx.x * 4 + w;
    int s = wid / N_, n = wid % N_;
    const float4* xs = (const float4*)(x + (size_t)s * NH_);
    int e0 = offs[n], e1 = offs[n + 1];
    float4 acc = make_float4(0.f, 0.f, 0.f, 0.f);
    int e = e0 + sub;
    // 2-deep pipeline x 4 sub-streams = 8 edges in flight per wave
    for (; e + 4 < e1; e += 8) {
        int   r0 = csr_row[e];
        int   r1 = csr_row[e + 4];
        float m0 = csr_nrm[e];
        float m1 = csr_nrm[e + 4];
        float4 a = xs[r0 * 16 + hl];
        float4 b = xs[r1 * 16 + hl];
        acc.x = fmaf(m0, a.x, acc.x); acc.y = fmaf(m0, a.y, acc.y);
        acc.z = fmaf(m0, a.z, acc.z); acc.w = fmaf(m0, a.w, acc.w);
        acc.x = fmaf(m1, b.x, acc.x); acc.y = fmaf(m1, b.y, acc.y);
        acc.z = fmaf(m1, b.z, acc.z); acc.w = fmaf(m1, b.w, acc.w);
    }
    if (e < e1) {
        int r = csr_row[e];
        float m = csr_nrm[e];
        float4 a = xs[r * 16 + hl];
        acc.x = fmaf(m, a.x, acc.x); acc.y = fmaf(m, a.y, acc.y);
        acc.z = fmaf(m, a.z, acc.z); acc.w = fmaf(m, a.w, acc.w);
    }
    // reduce the 4 sub-streams (lanes differing in bits 4..5)
    acc.x += __shfl_xor(acc.x, 16, 64); acc.y += __shfl_xor(acc.y, 16, 64);
    acc.z += __shfl_xor(acc.z, 16, 64); acc.w += __shfl_xor(acc.w, 16, 64);
    acc.x += __shfl_xor(acc.x, 32, 64); acc.y += __shfl_xor(acc.y, 32, 64);
    acc.z += __shfl_xor(acc.z, 32, 64); acc.w += __shfl_xor(acc.w, 32, 64);
    if (sub == 0) ((float4*)(y + (size_t)s * NH_ + n * 64))[hl] = acc;
    float sm = 0.f, sq = 0.f;
    if (sub == 0) {
        sm = acc.x + acc.y + acc.z + acc.w;
        sq = acc.x * acc.x + acc.y * acc.y + acc.z * acc.z + acc.w * acc.w;
    }
    sm = wred(sm);
    sq = wred(sq);
    if (lane == 0) { bsm[w] = sm; bsq[w] = sq; }
    __syncthreads();
    if (t == 0) {
        float2 p;
        p.x = bsm[0] + bsm[1] + bsm[2] + bsm[3];
        p.y = bsq[0] + bsq[1] + bsq[2] + bsq[3];
        part[s * BPS_ + (blockIdx.x % BPS_)] = p;
    }
}

// ---- LN2 (inline) + 12x12 period mix + skip-acc + stats partials -----------
__global__ void k_mix(const float* __restrict__ y, const float* __restrict__ tnw,
                      const float* __restrict__ tnb, const float* __restrict__ tcw,
                      const float* __restrict__ tcb, const float* __restrict__ st2,
                      const float* __restrict__ attn, int ai, float* __restrict__ xn,
                      float* __restrict__ acc, float2* __restrict__ part) {
    __shared__ float smu[12], srs[12], scw[144], scb[12], sstat[24];
    __shared__ float sa;
    int t = threadIdx.x;
    int gt = blockIdx.x * 256 + t;         // < B_*NH_ ; all threads in block share b
    int b = gt / NH_, r = gt % NH_;
    if (t < 12) {
        int s = b * 12 + t;
        float mu = st2[s * 2] * (1.f / NH_);
        float var = st2[s * 2 + 1] * (1.f / NH_) - mu * mu;
        smu[t] = mu;
        srs[t] = rsqrtf(var + EPS_);
        scb[t] = tcb[t];
    }
    if (t < 144) scw[t] = tcw[t];
    if (t < 24) sstat[t] = 0.f;
    if (t == 0) sa = softmax4(attn, ai);
    __syncthreads();
    float wv = tnw[r], bv = tnb[r];
    float yn[12];
#pragma unroll
    for (int p = 0; p < 12; p++) {
        float v = y[(size_t)(b * 12 + p) * NH_ + r];
        yn[p] = (v - smu[p]) * srs[p] * wv + bv;
    }
    float ov[12];
#pragma unroll
    for (int q = 0; q < 12; q++) {
        float o = scb[q];
#pragma unroll
        for (int p = 0; p < 12; p++) o = fmaf(scw[q * 12 + p], yn[p], o);
        ov[q] = o;
        size_t idx = (size_t)(b * 12 + q) * NH_ + r;
        xn[idx] = o;
        acc[idx] += sa * o;
    }
    int lane = t & 63;
#pragma unroll
    for (int q = 0; q < 12; q++) {
        float sm = wred(ov[q]);
        float sq = wred(ov[q] * ov[q]);
        if (lane == 0) { atomicAdd(&sstat[q * 2], sm); atomicAdd(&sstat[q * 2 + 1], sq); }
    }
    __syncthreads();
    if (t < 12) {
        // one float2 partial per (slice q of this b) per block
        int jb = blockIdx.x % BPS_;        // 2500 blocks per b
        float2 p; p.x = sstat[t * 2]; p.y = sstat[t * 2 + 1];
        part[(b * 12 + t) * BPS_ + jb] = p;
    }
}

// ---- final output projection, in-place on d_out ----------------------------
__global__ void k_out(float* __restrict__ io, const float* __restrict__ w1,
                      const float* __restrict__ b1, const float* __restrict__ w2,
                      const float* __restrict__ b2) {
    __shared__ float w1T[64 * 65], w2T[64 * 65];
    __shared__ float stage[4][64];
    int t = threadIdx.x;
    for (int k = t; k < 4096; k += 256) {
        int o = k >> 6, j = k & 63;
        w1T[j * 65 + o] = w1[k];
        w2T[j * 65 + o] = w2[k];
    }
    __syncthreads();
    int w = t >> 6, lane = t & 63;
    int wid = blockIdx.x * 4 + w;
    int s = wid / N_, n = wid % N_;
    size_t base = (size_t)s * NH_ + n * 64;
    float v = io[base + lane];
    stage[w][lane] = v;
    float h = b1[lane];
#pragma unroll
    for (int j = 0; j < 64; j++) h = fmaf(w1T[j * 65 + lane], stage[w][j], h);
    h = fmaxf(h, 0.f);
    stage[w][lane] = h;
    float o2 = b2[lane];
#pragma unroll
    for (int j = 0; j < 64; j++) o2 = fmaf(w2T[j * 65 + lane], stage[w][j], o2);
    io[base + lane] = o2;
}

extern "C" void kernel_launch(void* const* d_in, const int* in_sizes, int n_in,
                              void* d_out, int out_size, void* d_ws, size_t ws_size,
                              hipStream_t stream) {
    (void)in_sizes; (void)n_in; (void)out_size; (void)ws_size;
    const float* x    = (const float*)d_in[0];
    const int*   ei   = (const int*)d_in[1];
    const float* pos  = (const float*)d_in[2];
    const float* iw1  = (const float*)d_in[3];
    const float* ib1  = (const float*)d_in[4];
    const float* iw2  = (const float*)d_in[5];
    const float* ib2  = (const float*)d_in[6];
    const float* pw1  = (const float*)d_in[7];
    const float* pb1  = (const float*)d_in[8];
    const float* pw2  = (const float*)d_in[9];
    const float* pb2  = (const float*)d_in[10];
    const float* attn = (const float*)d_in[11];
    const float* gnw  = (const float*)d_in[12];
    const float* gnb  = (const float*)d_in[13];
    const float* tnw  = (const float*)d_in[14];
    const float* tnb  = (const float*)d_in[15];
    const float* tcw  = (const float*)d_in[16];
    const float* tcb  = (const float*)d_in[17];
    const float* ow1  = (const float*)d_in[18];
    const float* ob1  = (const float*)d_in[19];
    const float* ow2  = (const float*)d_in[20];
    const float* ob2  = (const float*)d_in[21];
    float* out = (float*)d_out;

    float* xA = (float*)d_ws;
    float* xB = xA + (size_t)S_ * NH_;
    float* yb = xB + (size_t)S_ * NH_;
    float* pp = yb + (size_t)S_ * NH_;
    float* csr_nrm = pp + NH_;
    int* csr_row = (int*)(csr_nrm + E_);
    int* deg     = csr_row + E_;
    int* offs    = deg + N_;
    int* cursor  = offs + N_ + 1;
    float* dis   = (float*)(cursor + N_);
    float* st1   = dis + N_;             // 4 iters * 24 slices * 2
    float* st2   = st1 + 4 * S_ * 2;     // 3 iters * 24 slices * 2
    float2* partA = (float2*)(((uintptr_t)(st2 + 3 * S_ * 2) + 15) & ~(uintptr_t)15);

    hipMemsetAsync(deg, 0, N_ * sizeof(int), stream);

    k_deg<<<(E_ + 255) / 256, 256, 0, stream>>>(ei, deg);
    k_scan<<<1, 1024, 0, stream>>>(deg, offs, cursor, dis);
    k_scatter<<<(E_ + 255) / 256, 256, 0, stream>>>(ei, dis, cursor, csr_row, csr_nrm);
    k_posproj<<<N_ / 4, 256, 0, stream>>>(pos, pw1, pb1, pw2, pb2, pp);
    k_in<<<S_ * N_ / 4, 256, 0, stream>>>(x, iw1, ib1, iw2, ib2, pp, attn, xA, out, partA);
    k_red<<<S_, 256, 0, stream>>>(partA, st1 + 0 * S_ * 2);

    float* cur = xA;
    float* nxt = xB;
    for (int i = 0; i < NB_; i++) {
        k_ln<<<S_ * NH_ / 4 / 256, 256, 0, stream>>>(cur, gnw + (size_t)i * NH_,
                                                     gnb + (size_t)i * NH_, st1 + i * S_ * 2);
        k_prop<<<S_ * N_ / 4, 256, 0, stream>>>(cur, offs, csr_row, csr_nrm, yb, partA);
        k_red<<<S_, 256, 0, stream>>>(partA, st2 + i * S_ * 2);
        k_mix<<<B_ * NH_ / 256, 256, 0, stream>>>(yb, tnw + (size_t)i * NH_,
                                                  tnb + (size_t)i * NH_, tcw + i * 144,
                                                  tcb + i * 12, st2 + i * S_ * 2, attn, i + 1,
                                                  nxt, out, partA);
        k_red<<<S_, 256, 0, stream>>>(partA, st1 + (i + 1) * S_ * 2);
        float* tmp = cur; cur = nxt; nxt = tmp;
    }
    k_out<<<S_ * N_ / 4, 256, 0, stream>>>(out, ow1, ob1, ow2, ob2);
}

// Round 5
// 938.382 us; speedup vs baseline: 5.3761x; 1.2791x over previous
//
#include <hip/hip_runtime.h>
#include <stdint.h>

constexpr int N_ = 10000, H_ = 64, P_ = 12, NB_ = 3, IN_ = 3, E_ = 160000, B_ = 2;
constexpr int S_  = B_ * P_;       // 24 slices (b,p)
constexpr int NH_ = N_ * H_;       // 640000 elements per slice
constexpr int BPS_ = N_ / 4;       // 2500 partials/slice for prop/mix
constexpr int NB64_ = (N_ + 63) / 64;  // 157 64-node tiles per slice
constexpr float EPS_ = 1e-5f;

#define DEVFN __device__ __forceinline__

DEVFN float softmax4(const float* a, int k) {
    float m = fmaxf(fmaxf(a[0], a[1]), fmaxf(a[2], a[3]));
    float e0 = __expf(a[0] - m), e1 = __expf(a[1] - m);
    float e2 = __expf(a[2] - m), e3 = __expf(a[3] - m);
    float s = e0 + e1 + e2 + e3;
    float ek = (k == 0 ? e0 : k == 1 ? e1 : k == 2 ? e2 : e3);
    return ek / s;
}

DEVFN float wred(float v) {
#pragma unroll
    for (int d = 32; d; d >>= 1) v += __shfl_xor(v, d, 64);
    return v;
}

// ---- swizzled 64x64 tile helpers -------------------------------------------
// element [r][c] stored at dst[r*64 + ((c>>2 ^ r>>2)<<2) + (c&3)]
DEVFN void stage_swz(const float4* __restrict__ src, float* __restrict__ dst, int t) {
    for (int f = t; f < 1024; f += 256) {
        int r = f >> 4, c4 = f & 15;
        float4 v = src[f];
        *(float4*)&dst[r * 64 + ((c4 ^ (r >> 2)) << 2)] = v;
    }
}

DEVFN void stage_swz_guard(const float4* __restrict__ src, float* __restrict__ dst,
                           int t, int nvalid) {
    for (int f = t; f < 1024; f += 256) {
        int r = f >> 4, c4 = f & 15;
        float4 v = make_float4(0.f, 0.f, 0.f, 0.f);
        if (r < nvalid) v = src[f];
        *(float4*)&dst[r * 64 + ((c4 ^ (r >> 2)) << 2)] = v;
    }
}

// ov[i][k] += sum_j A[4tn+i][j] * W[4to+k][j]   (tn4 = tn<<2, to4 = to<<2)
DEVFN void gemm64(const float* __restrict__ As, const float* __restrict__ Bs,
                  int tn4, int to4, float ov[4][4]) {
    const float* arow = As + tn4 * 64;
    const float* brow = Bs + to4 * 64;
#pragma unroll 4
    for (int j4 = 0; j4 < 16; ++j4) {
        int ca = (j4 << 2) ^ tn4;
        int cb = (j4 << 2) ^ to4;
        float4 a[4], b[4];
#pragma unroll
        for (int i = 0; i < 4; ++i) a[i] = *(const float4*)&arow[i * 64 + ca];
#pragma unroll
        for (int k = 0; k < 4; ++k) b[k] = *(const float4*)&brow[k * 64 + cb];
#pragma unroll
        for (int i = 0; i < 4; ++i)
#pragma unroll
            for (int k = 0; k < 4; ++k) {
                ov[i][k] = fmaf(a[i].x, b[k].x, ov[i][k]);
                ov[i][k] = fmaf(a[i].y, b[k].y, ov[i][k]);
                ov[i][k] = fmaf(a[i].z, b[k].z, ov[i][k]);
                ov[i][k] = fmaf(a[i].w, b[k].w, ov[i][k]);
            }
    }
}

// ---- CSR build -------------------------------------------------------------
__global__ void k_deg(const int* __restrict__ ei, int* __restrict__ deg) {
    int e = blockIdx.x * 256 + threadIdx.x;
    if (e < E_) atomicAdd(&deg[ei[E_ + e]], 1);
}

__global__ void k_scan(const int* __restrict__ deg, int* __restrict__ offs,
                       int* __restrict__ cursor, float* __restrict__ dis) {
    __shared__ int part[1024];
    int t = threadIdx.x;
    int base = t * 10;
    int cnt = 0;
    for (int k = 0; k < 10; k++) { int i = base + k; if (i < N_) cnt += deg[i]; }
    part[t] = cnt;
    __syncthreads();
    for (int d = 1; d < 1024; d <<= 1) {
        int v = 0;
        if (t >= d) v = part[t - d];
        __syncthreads();
        if (t >= d) part[t] += v;
        __syncthreads();
    }
    int run = (t > 0) ? part[t - 1] : 0;
    for (int k = 0; k < 10; k++) {
        int i = base + k;
        if (i < N_) {
            offs[i] = run; cursor[i] = run;
            int dg = deg[i];
            dis[i] = dg > 0 ? rsqrtf((float)dg) : 0.f;
            run += dg;
        }
    }
    if (t == 1023) offs[N_] = part[1023];
}

__global__ void k_scatter(const int* __restrict__ ei, const float* __restrict__ dis,
                          int* __restrict__ cursor, int* __restrict__ csr_row,
                          float* __restrict__ csr_nrm) {
    int e = blockIdx.x * 256 + threadIdx.x;
    if (e >= E_) return;
    int r = ei[e], c = ei[E_ + e];
    float nm = dis[r] * dis[c];
    int p = atomicAdd(&cursor[c], 1);
    csr_row[p] = r;
    csr_nrm[p] = nm;
}

// ---- per-slice stats reduce ------------------------------------------------
__global__ void k_red(const float2* __restrict__ part, float* __restrict__ st, int count) {
    __shared__ float rsm[4], rsq[4];
    int s = blockIdx.x, t = threadIdx.x, w = t >> 6, lane = t & 63;
    float sm = 0.f, sq = 0.f;
    for (int k = t; k < count; k += 256) {
        float2 p = part[s * BPS_ + k];
        sm += p.x; sq += p.y;
    }
    sm = wred(sm); sq = wred(sq);
    if (lane == 0) { rsm[w] = sm; rsq[w] = sq; }
    __syncthreads();
    if (t == 0) {
        st[s * 2]     = rsm[0] + rsm[1] + rsm[2] + rsm[3];
        st[s * 2 + 1] = rsq[0] + rsq[1] + rsq[2] + rsq[3];
    }
}

// ---- pos projection: pos[N,64] -> pp[N,64] ---------------------------------
__global__ void k_posproj(const float* __restrict__ pos, const float* __restrict__ w1,
                          const float* __restrict__ b1, const float* __restrict__ w2,
                          const float* __restrict__ b2, float* __restrict__ out) {
    __shared__ float w1T[64 * 65], w2T[64 * 65];
    __shared__ float stage[4][64];
    int t = threadIdx.x;
    for (int k = t; k < 4096; k += 256) {
        int o = k >> 6, j = k & 63;
        w1T[j * 65 + o] = w1[k];
        w2T[j * 65 + o] = w2[k];
    }
    __syncthreads();
    int w = t >> 6, lane = t & 63;
    int n = blockIdx.x * 4 + w;
    float v = pos[n * 64 + lane];
    stage[w][lane] = v;
    float h = b1[lane];
#pragma unroll
    for (int j = 0; j < 64; j++) h = fmaf(w1T[j * 65 + lane], stage[w][j], h);
    h = fmaxf(h, 0.f);
    stage[w][lane] = h;
    float o2 = b2[lane];
#pragma unroll
    for (int j = 0; j < 64; j++) o2 = fmaf(w2T[j * 65 + lane], stage[w][j], o2);
    out[n * 64 + lane] = o2;
}

// ---- input projection (tile GEMM) + pos add + acc init + stats partials ----
__global__ void k_in(const float* __restrict__ xin, const float* __restrict__ iw1,
                     const float* __restrict__ ib1, const float* __restrict__ iw2,
                     const float* __restrict__ ib2, const float* __restrict__ pp,
                     const float* __restrict__ attn, float* __restrict__ x0,
                     float* __restrict__ acc, float2* __restrict__ part) {
    __shared__ __align__(16) float U[4096];     // hA (swizzled) -> out_s (plain)
    __shared__ __align__(16) float B2s[4096];
    __shared__ float xin_s[192], iw1_s[192], bias1[64], bias2[64];
    __shared__ float rsm[4], rsq[4], sa0s;
    int t = threadIdx.x;
    int blk = blockIdx.x;
    int s = blk / NB64_, bn = blk % NB64_;
    int n0 = bn * 64;
    int nvalid = min(64, N_ - n0);
    stage_swz((const float4*)iw2, B2s, t);
    if (t < 192) {
        iw1_s[t] = iw1[t];
        int n = n0 + t / 3;
        xin_s[t] = (n < N_) ? xin[(size_t)s * (N_ * 3) + n0 * 3 + t] : 0.f;
    }
    if (t < 64) { bias1[t] = ib1[t]; bias2[t] = ib2[t]; }
    if (t == 0) sa0s = softmax4(attn, 0);
    __syncthreads();
    int tn = t >> 4, to = t & 15;
    int tn4 = tn << 2, to4 = to << 2;
    // layer 1: IN=3 -> 64, write swizzled into U
    float h1[4][4];
#pragma unroll
    for (int i = 0; i < 4; i++) {
        float a0 = xin_s[(tn4 + i) * 3], a1 = xin_s[(tn4 + i) * 3 + 1],
              a2 = xin_s[(tn4 + i) * 3 + 2];
#pragma unroll
        for (int k = 0; k < 4; k++) {
            int o = to4 + k;
            float h = bias1[o];
            h = fmaf(iw1_s[o * 3], a0, h);
            h = fmaf(iw1_s[o * 3 + 1], a1, h);
            h = fmaf(iw1_s[o * 3 + 2], a2, h);
            h1[i][k] = fmaxf(h, 0.f);
        }
    }
#pragma unroll
    for (int i = 0; i < 4; i++)
        *(float4*)&U[(tn4 + i) * 64 + (to4 ^ tn4)] =
            make_float4(h1[i][0], h1[i][1], h1[i][2], h1[i][3]);
    __syncthreads();
    // layer 2: 64 -> 64
    float ov[4][4];
#pragma unroll
    for (int i = 0; i < 4; i++)
#pragma unroll
        for (int k = 0; k < 4; k++) ov[i][k] = bias2[to4 + k];
    gemm64(U, B2s, tn4, to4, ov);
    __syncthreads();
#pragma unroll
    for (int i = 0; i < 4; i++)
        *(float4*)&U[(tn4 + i) * 64 + to4] =
            make_float4(ov[i][0], ov[i][1], ov[i][2], ov[i][3]);
    __syncthreads();
    // cooperative: add pos-proj, store x0 & acc, accumulate stats
    const float4* pp4 = (const float4*)pp + n0 * 16;
    float4* x04 = (float4*)x0 + (size_t)s * (NH_ / 4) + n0 * 16;
    float4* ac4 = (float4*)acc + (size_t)s * (NH_ / 4) + n0 * 16;
    float sa0 = sa0s;
    float sm = 0.f, sq = 0.f;
    for (int f = t; f < 1024; f += 256) {
        int r = f >> 4;
        if (r < nvalid) {
            float4 v = ((const float4*)U)[f];
            float4 p = pp4[f];
            v.x += p.x; v.y += p.y; v.z += p.z; v.w += p.w;
            x04[f] = v;
            float4 a;
            a.x = sa0 * v.x; a.y = sa0 * v.y; a.z = sa0 * v.z; a.w = sa0 * v.w;
            ac4[f] = a;
            sm += v.x + v.y + v.z + v.w;
            sq += v.x * v.x + v.y * v.y + v.z * v.z + v.w * v.w;
        }
    }
    int w = t >> 6, lane = t & 63;
    sm = wred(sm); sq = wred(sq);
    if (lane == 0) { rsm[w] = sm; rsq[w] = sq; }
    __syncthreads();
    if (t == 0) {
        float2 pr;
        pr.x = rsm[0] + rsm[1] + rsm[2] + rsm[3];
        pr.y = rsq[0] + rsq[1] + rsq[2] + rsq[3];
        part[s * BPS_ + bn] = pr;
    }
}

// ---- in-place LayerNorm apply (per-slice scalar stats) ---------------------
__global__ void k_ln(float* __restrict__ x, const float* __restrict__ w,
                     const float* __restrict__ b, const float* __restrict__ st) {
    int g = blockIdx.x * 256 + threadIdx.x;  // float4 index, < S_*NH_/4
    int s = g / (NH_ / 4);
    int r = g % (NH_ / 4);
    float mu = st[s * 2] * (1.f / NH_);
    float var = st[s * 2 + 1] * (1.f / NH_) - mu * mu;
    float rs = rsqrtf(var + EPS_);
    float4 xv = ((const float4*)x)[g];
    float4 wv = ((const float4*)w)[r];
    float4 bv = ((const float4*)b)[r];
    float4 o;
    o.x = (xv.x - mu) * rs * wv.x + bv.x;
    o.y = (xv.y - mu) * rs * wv.y + bv.y;
    o.z = (xv.z - mu) * rs * wv.z + bv.z;
    o.w = (xv.w - mu) * rs * wv.w + bv.w;
    ((float4*)x)[g] = o;
}

// ---- LightGCN propagate (gather over CSR, 4 edge-streams/wave) -------------
__global__ void k_prop(const float* __restrict__ x, const int* __restrict__ offs,
                       const int* __restrict__ csr_row, const float* __restrict__ csr_nrm,
                       float* __restrict__ y, float2* __restrict__ part) {
    __shared__ float bsm[4], bsq[4];
    int t = threadIdx.x;
    int w = t >> 6, lane = t & 63;
    int sub = lane >> 4;
    int hl  = lane & 15;
    int wid = blockIdx.x * 4 + w;
    int s = wid / N_, n = wid % N_;
    const float4* xs = (const float4*)(x + (size_t)s * NH_);
    int e0 = offs[n], e1 = offs[n + 1];
    float4 acc = make_float4(0.f, 0.f, 0.f, 0.f);
    int e = e0 + sub;
    for (; e + 4 < e1; e += 8) {
        int   r0 = csr_row[e];
        int   r1 = csr_row[e + 4];
        float m0 = csr_nrm[e];
        float m1 = csr_nrm[e + 4];
        float4 a = xs[r0 * 16 + hl];
        float4 b = xs[r1 * 16 + hl];
        acc.x = fmaf(m0, a.x, acc.x); acc.y = fmaf(m0, a.y, acc.y);
        acc.z = fmaf(m0, a.z, acc.z); acc.w = fmaf(m0, a.w, acc.w);
        acc.x = fmaf(m1, b.x, acc.x); acc.y = fmaf(m1, b.y, acc.y);
        acc.z = fmaf(m1, b.z, acc.z); acc.w = fmaf(m1, b.w, acc.w);
    }
    if (e < e1) {
        int r = csr_row[e];
        float m = csr_nrm[e];
        float4 a = xs[r * 16 + hl];
        acc.x = fmaf(m, a.x, acc.x); acc.y = fmaf(m, a.y, acc.y);
        acc.z = fmaf(m, a.z, acc.z); acc.w = fmaf(m, a.w, acc.w);
    }
    acc.x += __shfl_xor(acc.x, 16, 64); acc.y += __shfl_xor(acc.y, 16, 64);
    acc.z += __shfl_xor(acc.z, 16, 64); acc.w += __shfl_xor(acc.w, 16, 64);
    acc.x += __shfl_xor(acc.x, 32, 64); acc.y += __shfl_xor(acc.y, 32, 64);
    acc.z += __shfl_xor(acc.z, 32, 64); acc.w += __shfl_xor(acc.w, 32, 64);
    if (sub == 0) ((float4*)(y + (size_t)s * NH_ + n * 64))[hl] = acc;
    float sm = 0.f, sq = 0.f;
    if (sub == 0) {
        sm = acc.x + acc.y + acc.z + acc.w;
        sq = acc.x * acc.x + acc.y * acc.y + acc.z * acc.z + acc.w * acc.w;
    }
    sm = wred(sm);
    sq = wred(sq);
    if (lane == 0) { bsm[w] = sm; bsq[w] = sq; }
    __syncthreads();
    if (t == 0) {
        float2 p;
        p.x = bsm[0] + bsm[1] + bsm[2] + bsm[3];
        p.y = bsq[0] + bsq[1] + bsq[2] + bsq[3];
        part[s * BPS_ + (blockIdx.x % BPS_)] = p;
    }
}

// ---- LN2 (inline) + 12x12 period mix + skip-acc + stats partials -----------
__global__ void k_mix(const float* __restrict__ y, const float* __restrict__ tnw,
                      const float* __restrict__ tnb, const float* __restrict__ tcw,
                      const float* __restrict__ tcb, const float* __restrict__ st2,
                      const float* __restrict__ attn, int ai, float* __restrict__ xn,
                      float* __restrict__ acc, float2* __restrict__ part) {
    __shared__ float smu[12], srs[12], scw[144], scb[12], sstat[24];
    __shared__ float sa;
    int t = threadIdx.x;
    int gt = blockIdx.x * 256 + t;
    int b = gt / NH_, r = gt % NH_;
    if (t < 12) {
        int s = b * 12 + t;
        float mu = st2[s * 2] * (1.f / NH_);
        float var = st2[s * 2 + 1] * (1.f / NH_) - mu * mu;
        smu[t] = mu;
        srs[t] = rsqrtf(var + EPS_);
        scb[t] = tcb[t];
    }
    if (t < 144) scw[t] = tcw[t];
    if (t < 24) sstat[t] = 0.f;
    if (t == 0) sa = softmax4(attn, ai);
    __syncthreads();
    float wv = tnw[r], bv = tnb[r];
    float yn[12];
#pragma unroll
    for (int p = 0; p < 12; p++) {
        float v = y[(size_t)(b * 12 + p) * NH_ + r];
        yn[p] = (v - smu[p]) * srs[p] * wv + bv;
    }
    float ov[12];
#pragma unroll
    for (int q = 0; q < 12; q++) {
        float o = scb[q];
#pragma unroll
        for (int p = 0; p < 12; p++) o = fmaf(scw[q * 12 + p], yn[p], o);
        ov[q] = o;
        size_t idx = (size_t)(b * 12 + q) * NH_ + r;
        xn[idx] = o;
        acc[idx] += sa * o;
    }
    int lane = t & 63;
#pragma unroll
    for (int q = 0; q < 12; q++) {
        float sm = wred(ov[q]);
        float sq = wred(ov[q] * ov[q]);
        if (lane == 0) { atomicAdd(&sstat[q * 2], sm); atomicAdd(&sstat[q * 2 + 1], sq); }
    }
    __syncthreads();
    if (t < 12) {
        int jb = blockIdx.x % BPS_;
        float2 p; p.x = sstat[t * 2]; p.y = sstat[t * 2 + 1];
        part[(b * 12 + t) * BPS_ + jb] = p;
    }
}

// ---- final output projection (tile GEMM), in-place on d_out ----------------
__global__ void k_out(float* __restrict__ io, const float* __restrict__ w1,
                      const float* __restrict__ b1, const float* __restrict__ w2,
                      const float* __restrict__ b2) {
    __shared__ __align__(16) float U[4096];     // As -> hA -> out_s
    __shared__ __align__(16) float B1s[4096], B2s[4096];
    __shared__ float bias1[64], bias2[64];
    int t = threadIdx.x;
    int blk = blockIdx.x;
    int s = blk / NB64_, bn = blk % NB64_;
    int n0 = bn * 64;
    int nvalid = min(64, N_ - n0);
    const float4* io4 = (const float4*)io + (size_t)s * (NH_ / 4) + n0 * 16;
    stage_swz((const float4*)w1, B1s, t);
    stage_swz((const float4*)w2, B2s, t);
    stage_swz_guard(io4, U, t, nvalid);
    if (t < 64) { bias1[t] = b1[t]; bias2[t] = b2[t]; }
    __syncthreads();
    int tn = t >> 4, to = t & 15;
    int tn4 = tn << 2, to4 = to << 2;
    float ov[4][4];
#pragma unroll
    for (int i = 0; i < 4; i++)
#pragma unroll
        for (int k = 0; k < 4; k++) ov[i][k] = bias1[to4 + k];
    gemm64(U, B1s, tn4, to4, ov);
#pragma unroll
    for (int i = 0; i < 4; i++)
#pragma unroll
        for (int k = 0; k < 4; k++) ov[i][k] = fmaxf(ov[i][k], 0.f);
    __syncthreads();
#pragma unroll
    for (int i = 0; i < 4; i++)
        *(float4*)&U[(tn4 + i) * 64 + (to4 ^ tn4)] =
            make_float4(ov[i][0], ov[i][1], ov[i][2], ov[i][3]);
    __syncthreads();
    float ov2[4][4];
#pragma unroll
    for (int i = 0; i < 4; i++)
#pragma unroll
        for (int k = 0; k < 4; k++) ov2[i][k] = bias2[to4 + k];
    gemm64(U, B2s, tn4, to4, ov2);
    __syncthreads();
#pragma unroll
    for (int i = 0; i < 4; i++)
        *(float4*)&U[(tn4 + i) * 64 + to4] =
            make_float4(ov2[i][0], ov2[i][1], ov2[i][2], ov2[i][3]);
    __syncthreads();
    float4* io4w = (float4*)io + (size_t)s * (NH_ / 4) + n0 * 16;
    for (int f = t; f < 1024; f += 256) {
        int r = f >> 4;
        if (r < nvalid) io4w[f] = ((const float4*)U)[f];
    }
}

extern "C" void kernel_launch(void* const* d_in, const int* in_sizes, int n_in,
                              void* d_out, int out_size, void* d_ws, size_t ws_size,
                              hipStream_t stream) {
    (void)in_sizes; (void)n_in; (void)out_size; (void)ws_size;
    const float* x    = (const float*)d_in[0];
    const int*   ei   = (const int*)d_in[1];
    const float* pos  = (const float*)d_in[2];
    const float* iw1  = (const float*)d_in[3];
    const float* ib1  = (const float*)d_in[4];
    const float* iw2  = (const float*)d_in[5];
    const float* ib2  = (const float*)d_in[6];
    const float* pw1  = (const float*)d_in[7];
    const float* pb1  = (const float*)d_in[8];
    const float* pw2  = (const float*)d_in[9];
    const float* pb2  = (const float*)d_in[10];
    const float* attn = (const float*)d_in[11];
    const float* gnw  = (const float*)d_in[12];
    const float* gnb  = (const float*)d_in[13];
    const float* tnw  = (const float*)d_in[14];
    const float* tnb  = (const float*)d_in[15];
    const float* tcw  = (const float*)d_in[16];
    const float* tcb  = (const float*)d_in[17];
    const float* ow1  = (const float*)d_in[18];
    const float* ob1  = (const float*)d_in[19];
    const float* ow2  = (const float*)d_in[20];
    const float* ob2  = (const float*)d_in[21];
    float* out = (float*)d_out;

    float* xA = (float*)d_ws;
    float* xB = xA + (size_t)S_ * NH_;
    float* yb = xB + (size_t)S_ * NH_;
    float* pp = yb + (size_t)S_ * NH_;
    float* csr_nrm = pp + NH_;
    int* csr_row = (int*)(csr_nrm + E_);
    int* deg     = csr_row + E_;
    int* offs    = deg + N_;
    int* cursor  = offs + N_ + 1;
    float* dis   = (float*)(cursor + N_);
    float* st1   = dis + N_;             // 4 iters * 24 slices * 2
    float* st2   = st1 + 4 * S_ * 2;     // 3 iters * 24 slices * 2
    float2* partA = (float2*)(((uintptr_t)(st2 + 3 * S_ * 2) + 15) & ~(uintptr_t)15);

    hipMemsetAsync(deg, 0, N_ * sizeof(int), stream);

    k_deg<<<(E_ + 255) / 256, 256, 0, stream>>>(ei, deg);
    k_scan<<<1, 1024, 0, stream>>>(deg, offs, cursor, dis);
    k_scatter<<<(E_ + 255) / 256, 256, 0, stream>>>(ei, dis, cursor, csr_row, csr_nrm);
    k_posproj<<<N_ / 4, 256, 0, stream>>>(pos, pw1, pb1, pw2, pb2, pp);
    k_in<<<S_ * NB64_, 256, 0, stream>>>(x, iw1, ib1, iw2, ib2, pp, attn, xA, out, partA);
    k_red<<<S_, 256, 0, stream>>>(partA, st1 + 0 * S_ * 2, NB64_);

    float* cur = xA;
    float* nxt = xB;
    for (int i = 0; i < NB_; i++) {
        k_ln<<<S_ * NH_ / 4 / 256, 256, 0, stream>>>(cur, gnw + (size_t)i * NH_,
                                                     gnb + (size_t)i * NH_, st1 + i * S_ * 2);
        k_prop<<<S_ * N_ / 4, 256, 0, stream>>>(cur, offs, csr_row, csr_nrm, yb, partA);
        k_red<<<S_, 256, 0, stream>>>(partA, st2 + i * S_ * 2, BPS_);
        k_mix<<<B_ * NH_ / 256, 256, 0, stream>>>(yb, tnw + (size_t)i * NH_,
                                                  tnb + (size_t)i * NH_, tcw + i * 144,
                                                  tcb + i * 12, st2 + i * S_ * 2, attn, i + 1,
                                                  nxt, out, partA);
        k_red<<<S_, 256, 0, stream>>>(partA, st1 + (i + 1) * S_ * 2, BPS_);
        float* tmp = cur; cur = nxt; nxt = tmp;
    }
    k_out<<<S_ * NB64_, 256, 0, stream>>>(out, ow1, ob1, ow2, ob2);
}

// Round 6
// 903.550 us; speedup vs baseline: 5.5833x; 1.0385x over previous
//
#include <hip/hip_runtime.h>
#include <stdint.h>

constexpr int N_ = 10000, H_ = 64, P_ = 12, NB_ = 3, IN_ = 3, E_ = 160000, B_ = 2;
constexpr int S_  = B_ * P_;       // 24 slices (b,p)
constexpr int NH_ = N_ * H_;       // 640000 elements per slice
constexpr int BPS_ = N_ / 4;       // 2500 partials/slice for prop/mix
constexpr int NB64_ = (N_ + 63) / 64;  // 157 64-node tiles per slice
constexpr int NXCD_ = 8;
constexpr int PROPBLK_ = S_ * N_ / 4;          // 60000, divisible by 8
constexpr int PROPPX_  = PROPBLK_ / NXCD_;     // 7500 blocks per XCD
constexpr float EPS_ = 1e-5f;

#define DEVFN __device__ __forceinline__

DEVFN float softmax4(const float* a, int k) {
    float m = fmaxf(fmaxf(a[0], a[1]), fmaxf(a[2], a[3]));
    float e0 = __expf(a[0] - m), e1 = __expf(a[1] - m);
    float e2 = __expf(a[2] - m), e3 = __expf(a[3] - m);
    float s = e0 + e1 + e2 + e3;
    float ek = (k == 0 ? e0 : k == 1 ? e1 : k == 2 ? e2 : e3);
    return ek / s;
}

DEVFN float wred(float v) {
#pragma unroll
    for (int d = 32; d; d >>= 1) v += __shfl_xor(v, d, 64);
    return v;
}

// ---- swizzled 64x64 tile helpers -------------------------------------------
DEVFN void stage_swz(const float4* __restrict__ src, float* __restrict__ dst, int t) {
    for (int f = t; f < 1024; f += 256) {
        int r = f >> 4, c4 = f & 15;
        float4 v = src[f];
        *(float4*)&dst[r * 64 + ((c4 ^ (r >> 2)) << 2)] = v;
    }
}

DEVFN void stage_swz_guard(const float4* __restrict__ src, float* __restrict__ dst,
                           int t, int nvalid) {
    for (int f = t; f < 1024; f += 256) {
        int r = f >> 4, c4 = f & 15;
        float4 v = make_float4(0.f, 0.f, 0.f, 0.f);
        if (r < nvalid) v = src[f];
        *(float4*)&dst[r * 64 + ((c4 ^ (r >> 2)) << 2)] = v;
    }
}

DEVFN void gemm64(const float* __restrict__ As, const float* __restrict__ Bs,
                  int tn4, int to4, float ov[4][4]) {
    const float* arow = As + tn4 * 64;
    const float* brow = Bs + to4 * 64;
#pragma unroll 4
    for (int j4 = 0; j4 < 16; ++j4) {
        int ca = (j4 << 2) ^ tn4;
        int cb = (j4 << 2) ^ to4;
        float4 a[4], b[4];
#pragma unroll
        for (int i = 0; i < 4; ++i) a[i] = *(const float4*)&arow[i * 64 + ca];
#pragma unroll
        for (int k = 0; k < 4; ++k) b[k] = *(const float4*)&brow[k * 64 + cb];
#pragma unroll
        for (int i = 0; i < 4; ++i)
#pragma unroll
            for (int k = 0; k < 4; ++k) {
                ov[i][k] = fmaf(a[i].x, b[k].x, ov[i][k]);
                ov[i][k] = fmaf(a[i].y, b[k].y, ov[i][k]);
                ov[i][k] = fmaf(a[i].z, b[k].z, ov[i][k]);
                ov[i][k] = fmaf(a[i].w, b[k].w, ov[i][k]);
            }
    }
}

// ---- CSR build -------------------------------------------------------------
__global__ void k_deg(const int* __restrict__ ei, int* __restrict__ deg) {
    int e = blockIdx.x * 256 + threadIdx.x;
    if (e < E_) atomicAdd(&deg[ei[E_ + e]], 1);
}

__global__ void k_scan(const int* __restrict__ deg, int* __restrict__ offs,
                       int* __restrict__ cursor, float* __restrict__ dis) {
    __shared__ int part[1024];
    int t = threadIdx.x;
    int base = t * 10;
    int cnt = 0;
    for (int k = 0; k < 10; k++) { int i = base + k; if (i < N_) cnt += deg[i]; }
    part[t] = cnt;
    __syncthreads();
    for (int d = 1; d < 1024; d <<= 1) {
        int v = 0;
        if (t >= d) v = part[t - d];
        __syncthreads();
        if (t >= d) part[t] += v;
        __syncthreads();
    }
    int run = (t > 0) ? part[t - 1] : 0;
    for (int k = 0; k < 10; k++) {
        int i = base + k;
        if (i < N_) {
            offs[i] = run; cursor[i] = run;
            int dg = deg[i];
            dis[i] = dg > 0 ? rsqrtf((float)dg) : 0.f;
            run += dg;
        }
    }
    if (t == 1023) offs[N_] = part[1023];
}

__global__ void k_scatter(const int* __restrict__ ei, const float* __restrict__ dis,
                          int* __restrict__ cursor, int2* __restrict__ csr_pack) {
    int e = blockIdx.x * 256 + threadIdx.x;
    if (e >= E_) return;
    int r = ei[e], c = ei[E_ + e];
    float nm = dis[r] * dis[c];
    int p = atomicAdd(&cursor[c], 1);
    csr_pack[p] = make_int2(r << 4, __float_as_int(nm));  // r*16 = float4 row base
}

// ---- per-slice stats reduce ------------------------------------------------
__global__ void k_red(const float2* __restrict__ part, float* __restrict__ st, int count) {
    __shared__ float rsm[4], rsq[4];
    int s = blockIdx.x, t = threadIdx.x, w = t >> 6, lane = t & 63;
    float sm = 0.f, sq = 0.f;
    for (int k = t; k < count; k += 256) {
        float2 p = part[s * BPS_ + k];
        sm += p.x; sq += p.y;
    }
    sm = wred(sm); sq = wred(sq);
    if (lane == 0) { rsm[w] = sm; rsq[w] = sq; }
    __syncthreads();
    if (t == 0) {
        st[s * 2]     = rsm[0] + rsm[1] + rsm[2] + rsm[3];
        st[s * 2 + 1] = rsq[0] + rsq[1] + rsq[2] + rsq[3];
    }
}

// ---- pos projection: pos[N,64] -> pp[N,64] ---------------------------------
__global__ void k_posproj(const float* __restrict__ pos, const float* __restrict__ w1,
                          const float* __restrict__ b1, const float* __restrict__ w2,
                          const float* __restrict__ b2, float* __restrict__ out) {
    __shared__ float w1T[64 * 65], w2T[64 * 65];
    __shared__ float stage[4][64];
    int t = threadIdx.x;
    for (int k = t; k < 4096; k += 256) {
        int o = k >> 6, j = k & 63;
        w1T[j * 65 + o] = w1[k];
        w2T[j * 65 + o] = w2[k];
    }
    __syncthreads();
    int w = t >> 6, lane = t & 63;
    int n = blockIdx.x * 4 + w;
    float v = pos[n * 64 + lane];
    stage[w][lane] = v;
    float h = b1[lane];
#pragma unroll
    for (int j = 0; j < 64; j++) h = fmaf(w1T[j * 65 + lane], stage[w][j], h);
    h = fmaxf(h, 0.f);
    stage[w][lane] = h;
    float o2 = b2[lane];
#pragma unroll
    for (int j = 0; j < 64; j++) o2 = fmaf(w2T[j * 65 + lane], stage[w][j], o2);
    out[n * 64 + lane] = o2;
}

// ---- input projection (tile GEMM) + pos add + acc init + stats partials ----
__global__ void k_in(const float* __restrict__ xin, const float* __restrict__ iw1,
                     const float* __restrict__ ib1, const float* __restrict__ iw2,
                     const float* __restrict__ ib2, const float* __restrict__ pp,
                     const float* __restrict__ attn, float* __restrict__ x0,
                     float* __restrict__ acc, float2* __restrict__ part) {
    __shared__ __align__(16) float U[4096];
    __shared__ __align__(16) float B2s[4096];
    __shared__ float xin_s[192], iw1_s[192], bias1[64], bias2[64];
    __shared__ float rsm[4], rsq[4], sa0s;
    int t = threadIdx.x;
    int blk = blockIdx.x;
    int s = blk / NB64_, bn = blk % NB64_;
    int n0 = bn * 64;
    int nvalid = min(64, N_ - n0);
    stage_swz((const float4*)iw2, B2s, t);
    if (t < 192) {
        iw1_s[t] = iw1[t];
        int n = n0 + t / 3;
        xin_s[t] = (n < N_) ? xin[(size_t)s * (N_ * 3) + n0 * 3 + t] : 0.f;
    }
    if (t < 64) { bias1[t] = ib1[t]; bias2[t] = ib2[t]; }
    if (t == 0) sa0s = softmax4(attn, 0);
    __syncthreads();
    int tn = t >> 4, to = t & 15;
    int tn4 = tn << 2, to4 = to << 2;
    float h1[4][4];
#pragma unroll
    for (int i = 0; i < 4; i++) {
        float a0 = xin_s[(tn4 + i) * 3], a1 = xin_s[(tn4 + i) * 3 + 1],
              a2 = xin_s[(tn4 + i) * 3 + 2];
#pragma unroll
        for (int k = 0; k < 4; k++) {
            int o = to4 + k;
            float h = bias1[o];
            h = fmaf(iw1_s[o * 3], a0, h);
            h = fmaf(iw1_s[o * 3 + 1], a1, h);
            h = fmaf(iw1_s[o * 3 + 2], a2, h);
            h1[i][k] = fmaxf(h, 0.f);
        }
    }
#pragma unroll
    for (int i = 0; i < 4; i++)
        *(float4*)&U[(tn4 + i) * 64 + (to4 ^ tn4)] =
            make_float4(h1[i][0], h1[i][1], h1[i][2], h1[i][3]);
    __syncthreads();
    float ov[4][4];
#pragma unroll
    for (int i = 0; i < 4; i++)
#pragma unroll
        for (int k = 0; k < 4; k++) ov[i][k] = bias2[to4 + k];
    gemm64(U, B2s, tn4, to4, ov);
    __syncthreads();
#pragma unroll
    for (int i = 0; i < 4; i++)
        *(float4*)&U[(tn4 + i) * 64 + to4] =
            make_float4(ov[i][0], ov[i][1], ov[i][2], ov[i][3]);
    __syncthreads();
    const float4* pp4 = (const float4*)pp + n0 * 16;
    float4* x04 = (float4*)x0 + (size_t)s * (NH_ / 4) + n0 * 16;
    float4* ac4 = (float4*)acc + (size_t)s * (NH_ / 4) + n0 * 16;
    float sa0 = sa0s;
    float sm = 0.f, sq = 0.f;
    for (int f = t; f < 1024; f += 256) {
        int r = f >> 4;
        if (r < nvalid) {
            float4 v = ((const float4*)U)[f];
            float4 p = pp4[f];
            v.x += p.x; v.y += p.y; v.z += p.z; v.w += p.w;
            x04[f] = v;
            float4 a;
            a.x = sa0 * v.x; a.y = sa0 * v.y; a.z = sa0 * v.z; a.w = sa0 * v.w;
            ac4[f] = a;
            sm += v.x + v.y + v.z + v.w;
            sq += v.x * v.x + v.y * v.y + v.z * v.z + v.w * v.w;
        }
    }
    int w = t >> 6, lane = t & 63;
    sm = wred(sm); sq = wred(sq);
    if (lane == 0) { rsm[w] = sm; rsq[w] = sq; }
    __syncthreads();
    if (t == 0) {
        float2 pr;
        pr.x = rsm[0] + rsm[1] + rsm[2] + rsm[3];
        pr.y = rsq[0] + rsq[1] + rsq[2] + rsq[3];
        part[s * BPS_ + bn] = pr;
    }
}

// ---- in-place LayerNorm apply (per-slice scalar stats) ---------------------
__global__ void k_ln(float* __restrict__ x, const float* __restrict__ w,
                     const float* __restrict__ b, const float* __restrict__ st) {
    int g = blockIdx.x * 256 + threadIdx.x;
    int s = g / (NH_ / 4);
    int r = g % (NH_ / 4);
    float mu = st[s * 2] * (1.f / NH_);
    float var = st[s * 2 + 1] * (1.f / NH_) - mu * mu;
    float rs = rsqrtf(var + EPS_);
    float4 xv = ((const float4*)x)[g];
    float4 wv = ((const float4*)w)[r];
    float4 bv = ((const float4*)b)[r];
    float4 o;
    o.x = (xv.x - mu) * rs * wv.x + bv.x;
    o.y = (xv.y - mu) * rs * wv.y + bv.y;
    o.z = (xv.z - mu) * rs * wv.z + bv.z;
    o.w = (xv.w - mu) * rs * wv.w + bv.w;
    ((float4*)x)[g] = o;
}

// ---- LightGCN propagate: XCD-affine swizzle, packed metadata ---------------
__global__ void k_prop(const float* __restrict__ x, const int* __restrict__ offs,
                       const int2* __restrict__ csr_pack,
                       float* __restrict__ y, float2* __restrict__ part) {
    __shared__ float bsm[4], bsq[4];
    int t = threadIdx.x;
    int w = t >> 6, lane = t & 63;
    int sub = lane >> 4;
    int hl  = lane & 15;
    // XCD k (= blockIdx % 8 under round-robin dispatch) owns slices [3k, 3k+3)
    int orig = blockIdx.x;
    int gw = (orig & (NXCD_ - 1)) * PROPPX_ + (orig >> 3);
    int s = gw / BPS_;
    int blkin = gw % BPS_;
    int n = blkin * 4 + w;
    const float4* xs = (const float4*)(x + (size_t)s * NH_);
    int e0 = offs[n], e1 = offs[n + 1];
    float4 acc = make_float4(0.f, 0.f, 0.f, 0.f);
    int e = e0 + sub;
    for (; e + 4 < e1; e += 8) {
        int2 p0 = csr_pack[e];
        int2 p1 = csr_pack[e + 4];
        float m0 = __int_as_float(p0.y);
        float m1 = __int_as_float(p1.y);
        float4 a = xs[p0.x + hl];
        float4 b = xs[p1.x + hl];
        acc.x = fmaf(m0, a.x, acc.x); acc.y = fmaf(m0, a.y, acc.y);
        acc.z = fmaf(m0, a.z, acc.z); acc.w = fmaf(m0, a.w, acc.w);
        acc.x = fmaf(m1, b.x, acc.x); acc.y = fmaf(m1, b.y, acc.y);
        acc.z = fmaf(m1, b.z, acc.z); acc.w = fmaf(m1, b.w, acc.w);
    }
    if (e < e1) {
        int2 p0 = csr_pack[e];
        float m = __int_as_float(p0.y);
        float4 a = xs[p0.x + hl];
        acc.x = fmaf(m, a.x, acc.x); acc.y = fmaf(m, a.y, acc.y);
        acc.z = fmaf(m, a.z, acc.z); acc.w = fmaf(m, a.w, acc.w);
    }
    acc.x += __shfl_xor(acc.x, 16, 64); acc.y += __shfl_xor(acc.y, 16, 64);
    acc.z += __shfl_xor(acc.z, 16, 64); acc.w += __shfl_xor(acc.w, 16, 64);
    acc.x += __shfl_xor(acc.x, 32, 64); acc.y += __shfl_xor(acc.y, 32, 64);
    acc.z += __shfl_xor(acc.z, 32, 64); acc.w += __shfl_xor(acc.w, 32, 64);
    if (sub == 0) ((float4*)(y + (size_t)s * NH_ + n * 64))[hl] = acc;
    float sm = 0.f, sq = 0.f;
    if (sub == 0) {
        sm = acc.x + acc.y + acc.z + acc.w;
        sq = acc.x * acc.x + acc.y * acc.y + acc.z * acc.z + acc.w * acc.w;
    }
    sm = wred(sm);
    sq = wred(sq);
    if (lane == 0) { bsm[w] = sm; bsq[w] = sq; }
    __syncthreads();
    if (t == 0) {
        float2 p;
        p.x = bsm[0] + bsm[1] + bsm[2] + bsm[3];
        p.y = bsq[0] + bsq[1] + bsq[2] + bsq[3];
        part[s * BPS_ + blkin] = p;
    }
}

// ---- LN2 (inline) + 12x12 period mix + skip-acc + stats partials -----------
__global__ void k_mix(const float* __restrict__ y, const float* __restrict__ tnw,
                      const float* __restrict__ tnb, const float* __restrict__ tcw,
                      const float* __restrict__ tcb, const float* __restrict__ st2,
                      const float* __restrict__ attn, int ai, float* __restrict__ xn,
                      float* __restrict__ acc, float2* __restrict__ part) {
    __shared__ float smu[12], srs[12], scw[144], scb[12], sstat[24];
    __shared__ float sa;
    int t = threadIdx.x;
    int gt = blockIdx.x * 256 + t;
    int b = gt / NH_, r = gt % NH_;
    if (t < 12) {
        int s = b * 12 + t;
        float mu = st2[s * 2] * (1.f / NH_);
        float var = st2[s * 2 + 1] * (1.f / NH_) - mu * mu;
        smu[t] = mu;
        srs[t] = rsqrtf(var + EPS_);
        scb[t] = tcb[t];
    }
    if (t < 144) scw[t] = tcw[t];
    if (t < 24) sstat[t] = 0.f;
    if (t == 0) sa = softmax4(attn, ai);
    __syncthreads();
    float wv = tnw[r], bv = tnb[r];
    float yn[12];
#pragma unroll
    for (int p = 0; p < 12; p++) {
        float v = y[(size_t)(b * 12 + p) * NH_ + r];
        yn[p] = (v - smu[p]) * srs[p] * wv + bv;
    }
    float ov[12];
#pragma unroll
    for (int q = 0; q < 12; q++) {
        float o = scb[q];
#pragma unroll
        for (int p = 0; p < 12; p++) o = fmaf(scw[q * 12 + p], yn[p], o);
        ov[q] = o;
        size_t idx = (size_t)(b * 12 + q) * NH_ + r;
        xn[idx] = o;
        acc[idx] += sa * o;
    }
    int lane = t & 63;
#pragma unroll
    for (int q = 0; q < 12; q++) {
        float sm = wred(ov[q]);
        float sq = wred(ov[q] * ov[q]);
        if (lane == 0) { atomicAdd(&sstat[q * 2], sm); atomicAdd(&sstat[q * 2 + 1], sq); }
    }
    __syncthreads();
    if (t < 12) {
        int jb = blockIdx.x % BPS_;
        float2 p; p.x = sstat[t * 2]; p.y = sstat[t * 2 + 1];
        part[(b * 12 + t) * BPS_ + jb] = p;
    }
}

// ---- final output projection (tile GEMM), in-place on d_out ----------------
__global__ void k_out(float* __restrict__ io, const float* __restrict__ w1,
                      const float* __restrict__ b1, const float* __restrict__ w2,
                      const float* __restrict__ b2) {
    __shared__ __align__(16) float U[4096];
    __shared__ __align__(16) float B1s[4096], B2s[4096];
    __shared__ float bias1[64], bias2[64];
    int t = threadIdx.x;
    int blk = blockIdx.x;
    int s = blk / NB64_, bn = blk % NB64_;
    int n0 = bn * 64;
    int nvalid = min(64, N_ - n0);
    const float4* io4 = (const float4*)io + (size_t)s * (NH_ / 4) + n0 * 16;
    stage_swz((const float4*)w1, B1s, t);
    stage_swz((const float4*)w2, B2s, t);
    stage_swz_guard(io4, U, t, nvalid);
    if (t < 64) { bias1[t] = b1[t]; bias2[t] = b2[t]; }
    __syncthreads();
    int tn = t >> 4, to = t & 15;
    int tn4 = tn << 2, to4 = to << 2;
    float ov[4][4];
#pragma unroll
    for (int i = 0; i < 4; i++)
#pragma unroll
        for (int k = 0; k < 4; k++) ov[i][k] = bias1[to4 + k];
    gemm64(U, B1s, tn4, to4, ov);
#pragma unroll
    for (int i = 0; i < 4; i++)
#pragma unroll
        for (int k = 0; k < 4; k++) ov[i][k] = fmaxf(ov[i][k], 0.f);
    __syncthreads();
#pragma unroll
    for (int i = 0; i < 4; i++)
        *(float4*)&U[(tn4 + i) * 64 + (to4 ^ tn4)] =
            make_float4(ov[i][0], ov[i][1], ov[i][2], ov[i][3]);
    __syncthreads();
    float ov2[4][4];
#pragma unroll
    for (int i = 0; i < 4; i++)
#pragma unroll
        for (int k = 0; k < 4; k++) ov2[i][k] = bias2[to4 + k];
    gemm64(U, B2s, tn4, to4, ov2);
    __syncthreads();
#pragma unroll
    for (int i = 0; i < 4; i++)
        *(float4*)&U[(tn4 + i) * 64 + to4] =
            make_float4(ov2[i][0], ov2[i][1], ov2[i][2], ov2[i][3]);
    __syncthreads();
    float4* io4w = (float4*)io + (size_t)s * (NH_ / 4) + n0 * 16;
    for (int f = t; f < 1024; f += 256) {
        int r = f >> 4;
        if (r < nvalid) io4w[f] = ((const float4*)U)[f];
    }
}

extern "C" void kernel_launch(void* const* d_in, const int* in_sizes, int n_in,
                              void* d_out, int out_size, void* d_ws, size_t ws_size,
                              hipStream_t stream) {
    (void)in_sizes; (void)n_in; (void)out_size; (void)ws_size;
    const float* x    = (const float*)d_in[0];
    const int*   ei   = (const int*)d_in[1];
    const float* pos  = (const float*)d_in[2];
    const float* iw1  = (const float*)d_in[3];
    const float* ib1  = (const float*)d_in[4];
    const float* iw2  = (const float*)d_in[5];
    const float* ib2  = (const float*)d_in[6];
    const float* pw1  = (const float*)d_in[7];
    const float* pb1  = (const float*)d_in[8];
    const float* pw2  = (const float*)d_in[9];
    const float* pb2  = (const float*)d_in[10];
    const float* attn = (const float*)d_in[11];
    const float* gnw  = (const float*)d_in[12];
    const float* gnb  = (const float*)d_in[13];
    const float* tnw  = (const float*)d_in[14];
    const float* tnb  = (const float*)d_in[15];
    const float* tcw  = (const float*)d_in[16];
    const float* tcb  = (const float*)d_in[17];
    const float* ow1  = (const float*)d_in[18];
    const float* ob1  = (const float*)d_in[19];
    const float* ow2  = (const float*)d_in[20];
    const float* ob2  = (const float*)d_in[21];
    float* out = (float*)d_out;

    float* xA = (float*)d_ws;
    float* xB = xA + (size_t)S_ * NH_;
    float* yb = xB + (size_t)S_ * NH_;
    float* pp = yb + (size_t)S_ * NH_;
    int2* csr_pack = (int2*)(pp + NH_);
    int* deg     = (int*)(csr_pack + E_);
    int* offs    = deg + N_;
    int* cursor  = offs + N_ + 1;
    float* dis   = (float*)(cursor + N_);
    float* st1   = dis + N_;             // 4 iters * 24 slices * 2
    float* st2   = st1 + 4 * S_ * 2;     // 3 iters * 24 slices * 2
    float2* partA = (float2*)(((uintptr_t)(st2 + 3 * S_ * 2) + 15) & ~(uintptr_t)15);

    hipMemsetAsync(deg, 0, N_ * sizeof(int), stream);

    k_deg<<<(E_ + 255) / 256, 256, 0, stream>>>(ei, deg);
    k_scan<<<1, 1024, 0, stream>>>(deg, offs, cursor, dis);
    k_scatter<<<(E_ + 255) / 256, 256, 0, stream>>>(ei, dis, cursor, csr_pack);
    k_posproj<<<N_ / 4, 256, 0, stream>>>(pos, pw1, pb1, pw2, pb2, pp);
    k_in<<<S_ * NB64_, 256, 0, stream>>>(x, iw1, ib1, iw2, ib2, pp, attn, xA, out, partA);
    k_red<<<S_, 256, 0, stream>>>(partA, st1 + 0 * S_ * 2, NB64_);

    float* cur = xA;
    float* nxt = xB;
    for (int i = 0; i < NB_; i++) {
        k_ln<<<S_ * NH_ / 4 / 256, 256, 0, stream>>>(cur, gnw + (size_t)i * NH_,
                                                     gnb + (size_t)i * NH_, st1 + i * S_ * 2);
        k_prop<<<PROPBLK_, 256, 0, stream>>>(cur, offs, csr_pack, yb, partA);
        k_red<<<S_, 256, 0, stream>>>(partA, st2 + i * S_ * 2, BPS_);
        k_mix<<<B_ * NH_ / 256, 256, 0, stream>>>(yb, tnw + (size_t)i * NH_,
                                                  tnb + (size_t)i * NH_, tcw + i * 144,
                                                  tcb + i * 12, st2 + i * S_ * 2, attn, i + 1,
                                                  nxt, out, partA);
        k_red<<<S_, 256, 0, stream>>>(partA, st1 + (i + 1) * S_ * 2, BPS_);
        float* tmp = cur; cur = nxt; nxt = tmp;
    }
    k_out<<<S_ * NB64_, 256, 0, stream>>>(out, ow1, ob1, ow2, ob2);
}

// Round 7
// 766.390 us; speedup vs baseline: 6.5826x; 1.1790x over previous
//
#include <hip/hip_runtime.h>
#include <stdint.h>

constexpr int N_ = 10000, H_ = 64, P_ = 12, NB_ = 3, IN_ = 3, E_ = 160000, B_ = 2;
constexpr int S_  = B_ * P_;       // 24 slices (b,p)
constexpr int NH_ = N_ * H_;       // 640000 elements per slice
constexpr int BPS_ = N_ / 4;       // 2500 partials/slice for prop/mix
constexpr int NB64_ = (N_ + 63) / 64;  // 157 64-node tiles per slice
constexpr int NPAIR_ = S_ / 2;     // 12 slice pairs
constexpr int PROPBLK_ = NPAIR_ * BPS_;   // 30000 blocks, %8==0
constexpr int PROPPX_  = PROPBLK_ / 8;    // 3750 per XCD
constexpr int EPAD_ = E_ + N_;     // CSR with per-node even padding
constexpr float EPS_ = 1e-5f;

#define DEVFN __device__ __forceinline__

DEVFN float softmax4(const float* a, int k) {
    float m = fmaxf(fmaxf(a[0], a[1]), fmaxf(a[2], a[3]));
    float e0 = __expf(a[0] - m), e1 = __expf(a[1] - m);
    float e2 = __expf(a[2] - m), e3 = __expf(a[3] - m);
    float s = e0 + e1 + e2 + e3;
    float ek = (k == 0 ? e0 : k == 1 ? e1 : k == 2 ? e2 : e3);
    return ek / s;
}

DEVFN float wred(float v) {
#pragma unroll
    for (int d = 32; d; d >>= 1) v += __shfl_xor(v, d, 64);
    return v;
}

DEVFN void fma4(float m, const float4& a, float4& acc) {
    acc.x = fmaf(m, a.x, acc.x); acc.y = fmaf(m, a.y, acc.y);
    acc.z = fmaf(m, a.z, acc.z); acc.w = fmaf(m, a.w, acc.w);
}

DEVFN void xred4(float4& a) {
    a.x += __shfl_xor(a.x, 16, 64); a.y += __shfl_xor(a.y, 16, 64);
    a.z += __shfl_xor(a.z, 16, 64); a.w += __shfl_xor(a.w, 16, 64);
    a.x += __shfl_xor(a.x, 32, 64); a.y += __shfl_xor(a.y, 32, 64);
    a.z += __shfl_xor(a.z, 32, 64); a.w += __shfl_xor(a.w, 32, 64);
}

// ---- swizzled 64x64 tile helpers -------------------------------------------
DEVFN void stage_swz(const float4* __restrict__ src, float* __restrict__ dst, int t) {
    for (int f = t; f < 1024; f += 256) {
        int r = f >> 4, c4 = f & 15;
        float4 v = src[f];
        *(float4*)&dst[r * 64 + ((c4 ^ (r >> 2)) << 2)] = v;
    }
}

DEVFN void stage_swz_guard(const float4* __restrict__ src, float* __restrict__ dst,
                           int t, int nvalid) {
    for (int f = t; f < 1024; f += 256) {
        int r = f >> 4, c4 = f & 15;
        float4 v = make_float4(0.f, 0.f, 0.f, 0.f);
        if (r < nvalid) v = src[f];
        *(float4*)&dst[r * 64 + ((c4 ^ (r >> 2)) << 2)] = v;
    }
}

DEVFN void gemm64(const float* __restrict__ As, const float* __restrict__ Bs,
                  int tn4, int to4, float ov[4][4]) {
    const float* arow = As + tn4 * 64;
    const float* brow = Bs + to4 * 64;
#pragma unroll 4
    for (int j4 = 0; j4 < 16; ++j4) {
        int ca = (j4 << 2) ^ tn4;
        int cb = (j4 << 2) ^ to4;
        float4 a[4], b[4];
#pragma unroll
        for (int i = 0; i < 4; ++i) a[i] = *(const float4*)&arow[i * 64 + ca];
#pragma unroll
        for (int k = 0; k < 4; ++k) b[k] = *(const float4*)&brow[k * 64 + cb];
#pragma unroll
        for (int i = 0; i < 4; ++i)
#pragma unroll
            for (int k = 0; k < 4; ++k) {
                ov[i][k] = fmaf(a[i].x, b[k].x, ov[i][k]);
                ov[i][k] = fmaf(a[i].y, b[k].y, ov[i][k]);
                ov[i][k] = fmaf(a[i].z, b[k].z, ov[i][k]);
                ov[i][k] = fmaf(a[i].w, b[k].w, ov[i][k]);
            }
    }
}

// ---- CSR build (degrees padded to even for int4 metadata loads) ------------
__global__ void k_deg(const int* __restrict__ ei, int* __restrict__ deg) {
    int e = blockIdx.x * 256 + threadIdx.x;
    if (e < E_) atomicAdd(&deg[ei[E_ + e]], 1);
}

__global__ void k_scan(const int* __restrict__ deg, int* __restrict__ offs,
                       int* __restrict__ cursor, float* __restrict__ dis) {
    __shared__ int part[1024];
    int t = threadIdx.x;
    int base = t * 10;
    int cnt = 0;
    for (int k = 0; k < 10; k++) {
        int i = base + k;
        if (i < N_) cnt += (deg[i] + 1) & ~1;   // padded degree
    }
    part[t] = cnt;
    __syncthreads();
    for (int d = 1; d < 1024; d <<= 1) {
        int v = 0;
        if (t >= d) v = part[t - d];
        __syncthreads();
        if (t >= d) part[t] += v;
        __syncthreads();
    }
    int run = (t > 0) ? part[t - 1] : 0;
    for (int k = 0; k < 10; k++) {
        int i = base + k;
        if (i < N_) {
            offs[i] = run; cursor[i] = run;
            int dg = deg[i];
            dis[i] = dg > 0 ? rsqrtf((float)dg) : 0.f;
            run += (dg + 1) & ~1;
        }
    }
    if (t == 1023) offs[N_] = part[1023];
}

__global__ void k_scatter(const int* __restrict__ ei, const float* __restrict__ dis,
                          int* __restrict__ cursor, int2* __restrict__ csr_pack) {
    int e = blockIdx.x * 256 + threadIdx.x;
    if (e >= E_) return;
    int r = ei[e], c = ei[E_ + e];
    float nm = dis[r] * dis[c];
    int p = atomicAdd(&cursor[c], 1);
    csr_pack[p] = make_int2(r << 4, __float_as_int(nm));  // r*16 = float4 row base
}

// ---- per-slice stats reduce ------------------------------------------------
__global__ void k_red(const float2* __restrict__ part, float* __restrict__ st, int count) {
    __shared__ float rsm[4], rsq[4];
    int s = blockIdx.x, t = threadIdx.x, w = t >> 6, lane = t & 63;
    float sm = 0.f, sq = 0.f;
    for (int k = t; k < count; k += 256) {
        float2 p = part[s * BPS_ + k];
        sm += p.x; sq += p.y;
    }
    sm = wred(sm); sq = wred(sq);
    if (lane == 0) { rsm[w] = sm; rsq[w] = sq; }
    __syncthreads();
    if (t == 0) {
        st[s * 2]     = rsm[0] + rsm[1] + rsm[2] + rsm[3];
        st[s * 2 + 1] = rsq[0] + rsq[1] + rsq[2] + rsq[3];
    }
}

// ---- W~ / B~ gather: Wt[c,h] = sum nrm*gw[r,h], Bt likewise ---------------
__global__ void k_wb(const int* __restrict__ offs, const int2* __restrict__ csr_pack,
                     const float* __restrict__ gw, const float* __restrict__ gb,
                     float* __restrict__ Wt, float* __restrict__ Bt) {
    int t = threadIdx.x;
    int w = t >> 6, lane = t & 63;
    int sub = lane >> 4, hl = lane & 15;
    int n = blockIdx.x * 4 + w;
    const float4* W4 = (const float4*)gw;
    const float4* B4 = (const float4*)gb;
    int e0 = offs[n], e1 = offs[n + 1];
    float4 AW = make_float4(0, 0, 0, 0), AB = make_float4(0, 0, 0, 0);
    for (int e = e0 + sub * 2; e < e1; e += 8) {
        int4 mp = *(const int4*)&csr_pack[e];
        float m0 = __int_as_float(mp.y), m1 = __int_as_float(mp.w);
        int i0 = mp.x + hl, i1 = mp.z + hl;
        float4 a = W4[i0], b = W4[i1], c = B4[i0], d = B4[i1];
        fma4(m0, a, AW); fma4(m1, b, AW);
        fma4(m0, c, AB); fma4(m1, d, AB);
    }
    xred4(AW); xred4(AB);
    if (sub == 0) {
        ((float4*)Wt)[n * 16 + hl] = AW;
        ((float4*)Bt)[n * 16 + hl] = AB;
    }
}

// ---- pos projection: pos[N,64] -> pp[N,64] ---------------------------------
__global__ void k_posproj(const float* __restrict__ pos, const float* __restrict__ w1,
                          const float* __restrict__ b1, const float* __restrict__ w2,
                          const float* __restrict__ b2, float* __restrict__ out) {
    __shared__ float w1T[64 * 65], w2T[64 * 65];
    __shared__ float stage[4][64];
    int t = threadIdx.x;
    for (int k = t; k < 4096; k += 256) {
        int o = k >> 6, j = k & 63;
        w1T[j * 65 + o] = w1[k];
        w2T[j * 65 + o] = w2[k];
    }
    __syncthreads();
    int w = t >> 6, lane = t & 63;
    int n = blockIdx.x * 4 + w;
    float v = pos[n * 64 + lane];
    stage[w][lane] = v;
    float h = b1[lane];
#pragma unroll
    for (int j = 0; j < 64; j++) h = fmaf(w1T[j * 65 + lane], stage[w][j], h);
    h = fmaxf(h, 0.f);
    stage[w][lane] = h;
    float o2 = b2[lane];
#pragma unroll
    for (int j = 0; j < 64; j++) o2 = fmaf(w2T[j * 65 + lane], stage[w][j], o2);
    out[n * 64 + lane] = o2;
}

// ---- input projection (tile GEMM) + pos add + acc init + stats + x*w write -
__global__ void k_in(const float* __restrict__ xin, const float* __restrict__ iw1,
                     const float* __restrict__ ib1, const float* __restrict__ iw2,
                     const float* __restrict__ ib2, const float* __restrict__ pp,
                     const float* __restrict__ attn, const float* __restrict__ gw0,
                     float* __restrict__ xw, float* __restrict__ acc,
                     float2* __restrict__ part) {
    __shared__ __align__(16) float U[4096];
    __shared__ __align__(16) float B2s[4096];
    __shared__ float xin_s[192], iw1_s[192], bias1[64], bias2[64];
    __shared__ float rsm[4], rsq[4], sa0s;
    int t = threadIdx.x;
    int blk = blockIdx.x;
    int s = blk / NB64_, bn = blk % NB64_;
    int n0 = bn * 64;
    int nvalid = min(64, N_ - n0);
    stage_swz((const float4*)iw2, B2s, t);
    if (t < 192) {
        iw1_s[t] = iw1[t];
        int n = n0 + t / 3;
        xin_s[t] = (n < N_) ? xin[(size_t)s * (N_ * 3) + n0 * 3 + t] : 0.f;
    }
    if (t < 64) { bias1[t] = ib1[t]; bias2[t] = ib2[t]; }
    if (t == 0) sa0s = softmax4(attn, 0);
    __syncthreads();
    int tn = t >> 4, to = t & 15;
    int tn4 = tn << 2, to4 = to << 2;
    float h1[4][4];
#pragma unroll
    for (int i = 0; i < 4; i++) {
        float a0 = xin_s[(tn4 + i) * 3], a1 = xin_s[(tn4 + i) * 3 + 1],
              a2 = xin_s[(tn4 + i) * 3 + 2];
#pragma unroll
        for (int k = 0; k < 4; k++) {
            int o = to4 + k;
            float h = bias1[o];
            h = fmaf(iw1_s[o * 3], a0, h);
            h = fmaf(iw1_s[o * 3 + 1], a1, h);
            h = fmaf(iw1_s[o * 3 + 2], a2, h);
            h1[i][k] = fmaxf(h, 0.f);
        }
    }
#pragma unroll
    for (int i = 0; i < 4; i++)
        *(float4*)&U[(tn4 + i) * 64 + (to4 ^ tn4)] =
            make_float4(h1[i][0], h1[i][1], h1[i][2], h1[i][3]);
    __syncthreads();
    float ov[4][4];
#pragma unroll
    for (int i = 0; i < 4; i++)
#pragma unroll
        for (int k = 0; k < 4; k++) ov[i][k] = bias2[to4 + k];
    gemm64(U, B2s, tn4, to4, ov);
    __syncthreads();
#pragma unroll
    for (int i = 0; i < 4; i++)
        *(float4*)&U[(tn4 + i) * 64 + to4] =
            make_float4(ov[i][0], ov[i][1], ov[i][2], ov[i][3]);
    __syncthreads();
    const float4* pp4 = (const float4*)pp + n0 * 16;
    const float4* gw4 = (const float4*)gw0 + n0 * 16;
    float4* xw4 = (float4*)xw + (size_t)s * (NH_ / 4) + n0 * 16;
    float4* ac4 = (float4*)acc + (size_t)s * (NH_ / 4) + n0 * 16;
    float sa0 = sa0s;
    float sm = 0.f, sq = 0.f;
    for (int f = t; f < 1024; f += 256) {
        int r = f >> 4;
        if (r < nvalid) {
            float4 v = ((const float4*)U)[f];
            float4 p = pp4[f];
            v.x += p.x; v.y += p.y; v.z += p.z; v.w += p.w;
            float4 a;
            a.x = sa0 * v.x; a.y = sa0 * v.y; a.z = sa0 * v.z; a.w = sa0 * v.w;
            ac4[f] = a;
            sm += v.x + v.y + v.z + v.w;
            sq += v.x * v.x + v.y * v.y + v.z * v.z + v.w * v.w;
            float4 g = gw4[f];
            v.x *= g.x; v.y *= g.y; v.z *= g.z; v.w *= g.w;
            xw4[f] = v;
        }
    }
    int w = t >> 6, lane = t & 63;
    sm = wred(sm); sq = wred(sq);
    if (lane == 0) { rsm[w] = sm; rsq[w] = sq; }
    __syncthreads();
    if (t == 0) {
        float2 pr;
        pr.x = rsm[0] + rsm[1] + rsm[2] + rsm[3];
        pr.y = rsq[0] + rsq[1] + rsq[2] + rsq[3];
        part[s * BPS_ + bn] = pr;
    }
}

// ---- LightGCN propagate: 2 slices/wave, LN folded via Wt/Bt correction -----
__global__ void k_prop(const float* __restrict__ xw, const int* __restrict__ offs,
                       const int2* __restrict__ csr_pack, const float* __restrict__ Wt,
                       const float* __restrict__ Bt, const float* __restrict__ st,
                       float* __restrict__ y, float2* __restrict__ part) {
    __shared__ float bs[4][4];   // [wave][sm0,sq0,sm1,sq1]
    int t = threadIdx.x;
    int w = t >> 6, lane = t & 63;
    int sub = lane >> 4, hl = lane & 15;
    int orig = blockIdx.x;
    int gw = (orig & 7) * PROPPX_ + (orig >> 3);
    int pr = gw / BPS_;           // slice pair 0..11
    int blkin = gw % BPS_;
    int n = blkin * 4 + w;
    int s0 = pr * 2;
    const float4* xs0 = (const float4*)(xw + (size_t)s0 * NH_);
    const float4* xs1 = xs0 + (NH_ / 4);
    int e0 = offs[n], e1 = offs[n + 1];
    float4 A0 = make_float4(0, 0, 0, 0), A1 = make_float4(0, 0, 0, 0);
    for (int e = e0 + sub * 2; e < e1; e += 8) {
        int4 mp = *(const int4*)&csr_pack[e];     // edges e, e+1 (aligned: e even)
        float m0 = __int_as_float(mp.y), m1 = __int_as_float(mp.w);
        int i0 = mp.x + hl, i1 = mp.z + hl;
        float4 a = xs0[i0], b = xs0[i1];
        float4 c = xs1[i0], d = xs1[i1];
        fma4(m0, a, A0); fma4(m1, b, A0);
        fma4(m0, c, A1); fma4(m1, d, A1);
    }
    xred4(A0); xred4(A1);
    float mu0 = st[s0 * 2] * (1.f / NH_);
    float v0  = st[s0 * 2 + 1] * (1.f / NH_) - mu0 * mu0;
    float rs0 = rsqrtf(v0 + EPS_);
    float mu1 = st[s0 * 2 + 2] * (1.f / NH_);
    float v1  = st[s0 * 2 + 3] * (1.f / NH_) - mu1 * mu1;
    float rs1 = rsqrtf(v1 + EPS_);
    float sm0 = 0.f, sq0 = 0.f, sm1 = 0.f, sq1 = 0.f;
    if (sub == 0) {
        float4 wt = ((const float4*)Wt)[n * 16 + hl];
        float4 bt = ((const float4*)Bt)[n * 16 + hl];
        float c0 = -mu0 * rs0, c1 = -mu1 * rs1;
        float4 y0, y1;
        y0.x = fmaf(rs0, A0.x, fmaf(c0, wt.x, bt.x));
        y0.y = fmaf(rs0, A0.y, fmaf(c0, wt.y, bt.y));
        y0.z = fmaf(rs0, A0.z, fmaf(c0, wt.z, bt.z));
        y0.w = fmaf(rs0, A0.w, fmaf(c0, wt.w, bt.w));
        y1.x = fmaf(rs1, A1.x, fmaf(c1, wt.x, bt.x));
        y1.y = fmaf(rs1, A1.y, fmaf(c1, wt.y, bt.y));
        y1.z = fmaf(rs1, A1.z, fmaf(c1, wt.z, bt.z));
        y1.w = fmaf(rs1, A1.w, fmaf(c1, wt.w, bt.w));
        float4* yp = (float4*)(y + (size_t)s0 * NH_ + n * 64);
        yp[hl] = y0;
        yp[NH_ / 4 + hl] = y1;
        sm0 = y0.x + y0.y + y0.z + y0.w;
        sq0 = y0.x * y0.x + y0.y * y0.y + y0.z * y0.z + y0.w * y0.w;
        sm1 = y1.x + y1.y + y1.z + y1.w;
        sq1 = y1.x * y1.x + y1.y * y1.y + y1.z * y1.z + y1.w * y1.w;
    }
    sm0 = wred(sm0); sq0 = wred(sq0);
    sm1 = wred(sm1); sq1 = wred(sq1);
    if (lane == 0) { bs[w][0] = sm0; bs[w][1] = sq0; bs[w][2] = sm1; bs[w][3] = sq1; }
    __syncthreads();
    if (t < 2) {   // t=0 -> slice s0, t=1 -> slice s0+1
        float2 p;
        p.x = bs[0][t * 2] + bs[1][t * 2] + bs[2][t * 2] + bs[3][t * 2];
        p.y = bs[0][t * 2 + 1] + bs[1][t * 2 + 1] + bs[2][t * 2 + 1] + bs[3][t * 2 + 1];
        part[(s0 + t) * BPS_ + blkin] = p;
    }
}

// ---- LN2 (inline) + 12x12 period mix + skip-acc + stats + x*w_next write ---
__global__ void k_mix(const float* __restrict__ y, const float* __restrict__ tnw,
                      const float* __restrict__ tnb, const float* __restrict__ tcw,
                      const float* __restrict__ tcb, const float* __restrict__ st2,
                      const float* __restrict__ attn, int ai,
                      const float* __restrict__ wnext, int wx,
                      float* __restrict__ xn, float* __restrict__ acc,
                      float2* __restrict__ part) {
    __shared__ float smu[12], srs[12], scw[144], scb[12], sstat[24];
    __shared__ float sa;
    int t = threadIdx.x;
    int gt = blockIdx.x * 256 + t;
    int b = gt / NH_, r = gt % NH_;
    if (t < 12) {
        int s = b * 12 + t;
        float mu = st2[s * 2] * (1.f / NH_);
        float var = st2[s * 2 + 1] * (1.f / NH_) - mu * mu;
        smu[t] = mu;
        srs[t] = rsqrtf(var + EPS_);
        scb[t] = tcb[t];
    }
    if (t < 144) scw[t] = tcw[t];
    if (t < 24) sstat[t] = 0.f;
    if (t == 0) sa = softmax4(attn, ai);
    __syncthreads();
    float wv = tnw[r], bv = tnb[r];
    float wn = wx ? wnext[r] : 0.f;
    float yn[12];
#pragma unroll
    for (int p = 0; p < 12; p++) {
        float v = y[(size_t)(b * 12 + p) * NH_ + r];
        yn[p] = (v - smu[p]) * srs[p] * wv + bv;
    }
    float ov[12];
#pragma unroll
    for (int q = 0; q < 12; q++) {
        float o = scb[q];
#pragma unroll
        for (int p = 0; p < 12; p++) o = fmaf(scw[q * 12 + p], yn[p], o);
        ov[q] = o;
        size_t idx = (size_t)(b * 12 + q) * NH_ + r;
        if (wx) xn[idx] = o * wn;
        acc[idx] += sa * o;
    }
    int lane = t & 63;
#pragma unroll
    for (int q = 0; q < 12; q++) {
        float sm = wred(ov[q]);
        float sq = wred(ov[q] * ov[q]);
        if (lane == 0) { atomicAdd(&sstat[q * 2], sm); atomicAdd(&sstat[q * 2 + 1], sq); }
    }
    __syncthreads();
    if (t < 12) {
        int jb = blockIdx.x % BPS_;
        float2 p; p.x = sstat[t * 2]; p.y = sstat[t * 2 + 1];
        part[(b * 12 + t) * BPS_ + jb] = p;
    }
}

// ---- final output projection (tile GEMM), in-place on d_out ----------------
__global__ void k_out(float* __restrict__ io, const float* __restrict__ w1,
                      const float* __restrict__ b1, const float* __restrict__ w2,
                      const float* __restrict__ b2) {
    __shared__ __align__(16) float U[4096];
    __shared__ __align__(16) float B1s[4096], B2s[4096];
    __shared__ float bias1[64], bias2[64];
    int t = threadIdx.x;
    int blk = blockIdx.x;
    int s = blk / NB64_, bn = blk % NB64_;
    int n0 = bn * 64;
    int nvalid = min(64, N_ - n0);
    const float4* io4 = (const float4*)io + (size_t)s * (NH_ / 4) + n0 * 16;
    stage_swz((const float4*)w1, B1s, t);
    stage_swz((const float4*)w2, B2s, t);
    stage_swz_guard(io4, U, t, nvalid);
    if (t < 64) { bias1[t] = b1[t]; bias2[t] = b2[t]; }
    __syncthreads();
    int tn = t >> 4, to = t & 15;
    int tn4 = tn << 2, to4 = to << 2;
    float ov[4][4];
#pragma unroll
    for (int i = 0; i < 4; i++)
#pragma unroll
        for (int k = 0; k < 4; k++) ov[i][k] = bias1[to4 + k];
    gemm64(U, B1s, tn4, to4, ov);
#pragma unroll
    for (int i = 0; i < 4; i++)
#pragma unroll
        for (int k = 0; k < 4; k++) ov[i][k] = fmaxf(ov[i][k], 0.f);
    __syncthreads();
#pragma unroll
    for (int i = 0; i < 4; i++)
        *(float4*)&U[(tn4 + i) * 64 + (to4 ^ tn4)] =
            make_float4(ov[i][0], ov[i][1], ov[i][2], ov[i][3]);
    __syncthreads();
    float ov2[4][4];
#pragma unroll
    for (int i = 0; i < 4; i++)
#pragma unroll
        for (int k = 0; k < 4; k++) ov2[i][k] = bias2[to4 + k];
    gemm64(U, B2s, tn4, to4, ov2);
    __syncthreads();
#pragma unroll
    for (int i = 0; i < 4; i++)
        *(float4*)&U[(tn4 + i) * 64 + to4] =
            make_float4(ov2[i][0], ov2[i][1], ov2[i][2], ov2[i][3]);
    __syncthreads();
    float4* io4w = (float4*)io + (size_t)s * (NH_ / 4) + n0 * 16;
    for (int f = t; f < 1024; f += 256) {
        int r = f >> 4;
        if (r < nvalid) io4w[f] = ((const float4*)U)[f];
    }
}

extern "C" void kernel_launch(void* const* d_in, const int* in_sizes, int n_in,
                              void* d_out, int out_size, void* d_ws, size_t ws_size,
                              hipStream_t stream) {
    (void)in_sizes; (void)n_in; (void)out_size; (void)ws_size;
    const float* x    = (const float*)d_in[0];
    const int*   ei   = (const int*)d_in[1];
    const float* pos  = (const float*)d_in[2];
    const float* iw1  = (const float*)d_in[3];
    const float* ib1  = (const float*)d_in[4];
    const float* iw2  = (const float*)d_in[5];
    const float* ib2  = (const float*)d_in[6];
    const float* pw1  = (const float*)d_in[7];
    const float* pb1  = (const float*)d_in[8];
    const float* pw2  = (const float*)d_in[9];
    const float* pb2  = (const float*)d_in[10];
    const float* attn = (const float*)d_in[11];
    const float* gnw  = (const float*)d_in[12];
    const float* gnb  = (const float*)d_in[13];
    const float* tnw  = (const float*)d_in[14];
    const float* tnb  = (const float*)d_in[15];
    const float* tcw  = (const float*)d_in[16];
    const float* tcb  = (const float*)d_in[17];
    const float* ow1  = (const float*)d_in[18];
    const float* ob1  = (const float*)d_in[19];
    const float* ow2  = (const float*)d_in[20];
    const float* ob2  = (const float*)d_in[21];
    float* out = (float*)d_out;

    float* xA = (float*)d_ws;
    float* xB = xA + (size_t)S_ * NH_;
    float* yb = xB + (size_t)S_ * NH_;
    float* pp = yb + (size_t)S_ * NH_;
    float* Wt = pp + NH_;
    float* Bt = Wt + NH_;
    int2* csr_pack = (int2*)(Bt + NH_);
    int* deg     = (int*)(csr_pack + EPAD_);
    int* offs    = deg + N_;
    int* cursor  = offs + N_ + 1;
    float* dis   = (float*)(cursor + N_);
    float* st1   = dis + N_;             // 4 iters * 24 slices * 2
    float* st2   = st1 + 4 * S_ * 2;     // 3 iters * 24 slices * 2
    float2* partA = (float2*)(((uintptr_t)(st2 + 3 * S_ * 2) + 15) & ~(uintptr_t)15);

    // zero csr_pack (pad entries must be {0, 0.0f}) and deg, contiguous region
    hipMemsetAsync(csr_pack, 0, (size_t)EPAD_ * sizeof(int2) + N_ * sizeof(int), stream);

    k_deg<<<(E_ + 255) / 256, 256, 0, stream>>>(ei, deg);
    k_scan<<<1, 1024, 0, stream>>>(deg, offs, cursor, dis);
    k_scatter<<<(E_ + 255) / 256, 256, 0, stream>>>(ei, dis, cursor, csr_pack);
    k_posproj<<<N_ / 4, 256, 0, stream>>>(pos, pw1, pb1, pw2, pb2, pp);
    k_in<<<S_ * NB64_, 256, 0, stream>>>(x, iw1, ib1, iw2, ib2, pp, attn, gnw,
                                         xA, out, partA);
    k_red<<<S_, 256, 0, stream>>>(partA, st1 + 0 * S_ * 2, NB64_);

    float* cur = xA;
    float* nxt = xB;
    for (int i = 0; i < NB_; i++) {
        k_wb<<<N_ / 4, 256, 0, stream>>>(offs, csr_pack, gnw + (size_t)i * NH_,
                                         gnb + (size_t)i * NH_, Wt, Bt);
        k_prop<<<PROPBLK_, 256, 0, stream>>>(cur, offs, csr_pack, Wt, Bt,
                                             st1 + i * S_ * 2, yb, partA);
        k_red<<<S_, 256, 0, stream>>>(partA, st2 + i * S_ * 2, BPS_);
        int wx = (i < NB_ - 1) ? 1 : 0;
        const float* wnext = gnw + (size_t)(i + 1 < NB_ ? i + 1 : 0) * NH_;
        k_mix<<<B_ * NH_ / 256, 256, 0, stream>>>(yb, tnw + (size_t)i * NH_,
                                                  tnb + (size_t)i * NH_, tcw + i * 144,
                                                  tcb + i * 12, st2 + i * S_ * 2, attn, i + 1,
                                                  wnext, wx, nxt, out, partA);
        if (i < NB_ - 1)
            k_red<<<S_, 256, 0, stream>>>(partA, st1 + (i + 1) * S_ * 2, BPS_);
        float* tmp = cur; cur = nxt; nxt = tmp;
    }
    k_out<<<S_ * NB64_, 256, 0, stream>>>(out, ow1, ob1, ow2, ob2);
}

// Round 9
// 755.711 us; speedup vs baseline: 6.6756x; 1.0141x over previous
//
#include <hip/hip_runtime.h>
#include <stdint.h>

constexpr int N_ = 10000, H_ = 64, P_ = 12, NB_ = 3, IN_ = 3, E_ = 160000, B_ = 2;
constexpr int S_  = B_ * P_;       // 24 slices (b,p)
constexpr int NH_ = N_ * H_;       // 640000 elements per slice
constexpr int BPS_ = N_ / 4;       // 2500 partials/slice for prop/mix
constexpr int NB64_ = (N_ + 63) / 64;  // 157 64-node tiles per slice
constexpr int NPAIR_ = S_ / 2;     // 12 slice pairs
constexpr int PROPBLK_ = NPAIR_ * BPS_;   // 30000 blocks, %8==0
constexpr int PROPPX_  = PROPBLK_ / 8;    // 3750 per XCD
constexpr int EPAD_ = E_ + N_;     // CSR with per-node even padding
constexpr float EPS_ = 1e-5f;

#define DEVFN __device__ __forceinline__

DEVFN float softmax4(const float* a, int k) {
    float m = fmaxf(fmaxf(a[0], a[1]), fmaxf(a[2], a[3]));
    float e0 = __expf(a[0] - m), e1 = __expf(a[1] - m);
    float e2 = __expf(a[2] - m), e3 = __expf(a[3] - m);
    float s = e0 + e1 + e2 + e3;
    float ek = (k == 0 ? e0 : k == 1 ? e1 : k == 2 ? e2 : e3);
    return ek / s;
}

DEVFN float wred(float v) {
#pragma unroll
    for (int d = 32; d; d >>= 1) v += __shfl_xor(v, d, 64);
    return v;
}

DEVFN void fma4(float m, const float4& a, float4& acc) {
    acc.x = fmaf(m, a.x, acc.x); acc.y = fmaf(m, a.y, acc.y);
    acc.z = fmaf(m, a.z, acc.z); acc.w = fmaf(m, a.w, acc.w);
}

DEVFN void xred4(float4& a) {
    a.x += __shfl_xor(a.x, 16, 64); a.y += __shfl_xor(a.y, 16, 64);
    a.z += __shfl_xor(a.z, 16, 64); a.w += __shfl_xor(a.w, 16, 64);
    a.x += __shfl_xor(a.x, 32, 64); a.y += __shfl_xor(a.y, 32, 64);
    a.z += __shfl_xor(a.z, 32, 64); a.w += __shfl_xor(a.w, 32, 64);
}

// ---- swizzled 64x64 tile helpers -------------------------------------------
DEVFN void stage_swz(const float4* __restrict__ src, float* __restrict__ dst, int t) {
    for (int f = t; f < 1024; f += 256) {
        int r = f >> 4, c4 = f & 15;
        float4 v = src[f];
        *(float4*)&dst[r * 64 + ((c4 ^ (r >> 2)) << 2)] = v;
    }
}

DEVFN void stage_swz_guard(const float4* __restrict__ src, float* __restrict__ dst,
                           int t, int nvalid) {
    for (int f = t; f < 1024; f += 256) {
        int r = f >> 4, c4 = f & 15;
        float4 v = make_float4(0.f, 0.f, 0.f, 0.f);
        if (r < nvalid) v = src[f];
        *(float4*)&dst[r * 64 + ((c4 ^ (r >> 2)) << 2)] = v;
    }
}

DEVFN void gemm64(const float* __restrict__ As, const float* __restrict__ Bs,
                  int tn4, int to4, float ov[4][4]) {
    const float* arow = As + tn4 * 64;
    const float* brow = Bs + to4 * 64;
#pragma unroll 4
    for (int j4 = 0; j4 < 16; ++j4) {
        int ca = (j4 << 2) ^ tn4;
        int cb = (j4 << 2) ^ to4;
        float4 a[4], b[4];
#pragma unroll
        for (int i = 0; i < 4; ++i) a[i] = *(const float4*)&arow[i * 64 + ca];
#pragma unroll
        for (int k = 0; k < 4; ++k) b[k] = *(const float4*)&brow[k * 64 + cb];
#pragma unroll
        for (int i = 0; i < 4; ++i)
#pragma unroll
            for (int k = 0; k < 4; ++k) {
                ov[i][k] = fmaf(a[i].x, b[k].x, ov[i][k]);
                ov[i][k] = fmaf(a[i].y, b[k].y, ov[i][k]);
                ov[i][k] = fmaf(a[i].z, b[k].z, ov[i][k]);
                ov[i][k] = fmaf(a[i].w, b[k].w, ov[i][k]);
            }
    }
}

// ---- CSR build (degrees padded to even for int4 metadata loads) ------------
__global__ void k_deg(const int* __restrict__ ei, int* __restrict__ deg) {
    int e = blockIdx.x * 256 + threadIdx.x;
    if (e < E_) atomicAdd(&deg[ei[E_ + e]], 1);
}

__global__ void k_scan(const int* __restrict__ deg, int* __restrict__ offs,
                       int* __restrict__ cursor, float* __restrict__ dis) {
    __shared__ int part[1024];
    int t = threadIdx.x;
    int base = t * 10;
    int cnt = 0;
    for (int k = 0; k < 10; k++) {
        int i = base + k;
        if (i < N_) cnt += (deg[i] + 1) & ~1;   // padded degree
    }
    part[t] = cnt;
    __syncthreads();
    for (int d = 1; d < 1024; d <<= 1) {
        int v = 0;
        if (t >= d) v = part[t - d];
        __syncthreads();
        if (t >= d) part[t] += v;
        __syncthreads();
    }
    int run = (t > 0) ? part[t - 1] : 0;
    for (int k = 0; k < 10; k++) {
        int i = base + k;
        if (i < N_) {
            offs[i] = run; cursor[i] = run;
            int dg = deg[i];
            dis[i] = dg > 0 ? rsqrtf((float)dg) : 0.f;
            run += (dg + 1) & ~1;
        }
    }
    if (t == 1023) offs[N_] = part[1023];
}

__global__ void k_scatter(const int* __restrict__ ei, const float* __restrict__ dis,
                          int* __restrict__ cursor, int2* __restrict__ csr_pack) {
    int e = blockIdx.x * 256 + threadIdx.x;
    if (e >= E_) return;
    int r = ei[e], c = ei[E_ + e];
    float nm = dis[r] * dis[c];
    int p = atomicAdd(&cursor[c], 1);
    csr_pack[p] = make_int2(r << 4, __float_as_int(nm));  // r*16 = float4 row base
}

// ---- per-slice stats reduce ------------------------------------------------
__global__ void k_red(const float2* __restrict__ part, float* __restrict__ st, int count) {
    __shared__ float rsm[4], rsq[4];
    int s = blockIdx.x, t = threadIdx.x, w = t >> 6, lane = t & 63;
    float sm = 0.f, sq = 0.f;
    for (int k = t; k < count; k += 256) {
        float2 p = part[s * BPS_ + k];
        sm += p.x; sq += p.y;
    }
    sm = wred(sm); sq = wred(sq);
    if (lane == 0) { rsm[w] = sm; rsq[w] = sq; }
    __syncthreads();
    if (t == 0) {
        st[s * 2]     = rsm[0] + rsm[1] + rsm[2] + rsm[3];
        st[s * 2 + 1] = rsq[0] + rsq[1] + rsq[2] + rsq[3];
    }
}

// ---- W~ / B~ gather: Wt[c,h] = sum nrm*gw[r,h], Bt likewise ---------------
__global__ void k_wb(const int* __restrict__ offs, const int2* __restrict__ csr_pack,
                     const float* __restrict__ gw, const float* __restrict__ gb,
                     float* __restrict__ Wt, float* __restrict__ Bt) {
    int t = threadIdx.x;
    int w = t >> 6, lane = t & 63;
    int sub = lane >> 4, hl = lane & 15;
    int n = blockIdx.x * 4 + w;
    const float4* W4 = (const float4*)gw;
    const float4* B4 = (const float4*)gb;
    int e0 = offs[n], e1 = offs[n + 1];
    float4 AW = make_float4(0, 0, 0, 0), AB = make_float4(0, 0, 0, 0);
    for (int e = e0 + sub * 2; e < e1; e += 8) {
        int4 mp = *(const int4*)&csr_pack[e];
        float m0 = __int_as_float(mp.y), m1 = __int_as_float(mp.w);
        int i0 = mp.x + hl, i1 = mp.z + hl;
        float4 a = W4[i0], b = W4[i1], c = B4[i0], d = B4[i1];
        fma4(m0, a, AW); fma4(m1, b, AW);
        fma4(m0, c, AB); fma4(m1, d, AB);
    }
    xred4(AW); xred4(AB);
    if (sub == 0) {
        ((float4*)Wt)[n * 16 + hl] = AW;
        ((float4*)Bt)[n * 16 + hl] = AB;
    }
}

// ---- pos projection: pos[N,64] -> pp[N,64] ---------------------------------
__global__ void k_posproj(const float* __restrict__ pos, const float* __restrict__ w1,
                          const float* __restrict__ b1, const float* __restrict__ w2,
                          const float* __restrict__ b2, float* __restrict__ out) {
    __shared__ float w1T[64 * 65], w2T[64 * 65];
    __shared__ float stage[4][64];
    int t = threadIdx.x;
    for (int k = t; k < 4096; k += 256) {
        int o = k >> 6, j = k & 63;
        w1T[j * 65 + o] = w1[k];
        w2T[j * 65 + o] = w2[k];
    }
    __syncthreads();
    int w = t >> 6, lane = t & 63;
    int n = blockIdx.x * 4 + w;
    float v = pos[n * 64 + lane];
    stage[w][lane] = v;
    float h = b1[lane];
#pragma unroll
    for (int j = 0; j < 64; j++) h = fmaf(w1T[j * 65 + lane], stage[w][j], h);
    h = fmaxf(h, 0.f);
    stage[w][lane] = h;
    float o2 = b2[lane];
#pragma unroll
    for (int j = 0; j < 64; j++) o2 = fmaf(w2T[j * 65 + lane], stage[w][j], o2);
    out[n * 64 + lane] = o2;
}

// ---- input projection (tile GEMM) + pos add + acc init + stats + x*w write -
__global__ void k_in(const float* __restrict__ xin, const float* __restrict__ iw1,
                     const float* __restrict__ ib1, const float* __restrict__ iw2,
                     const float* __restrict__ ib2, const float* __restrict__ pp,
                     const float* __restrict__ attn, const float* __restrict__ gw0,
                     float* __restrict__ xw, float* __restrict__ acc,
                     float2* __restrict__ part) {
    __shared__ __align__(16) float U[4096];
    __shared__ __align__(16) float B2s[4096];
    __shared__ float xin_s[192], iw1_s[192], bias1[64], bias2[64];
    __shared__ float rsm[4], rsq[4], sa0s;
    int t = threadIdx.x;
    int blk = blockIdx.x;
    int s = blk / NB64_, bn = blk % NB64_;
    int n0 = bn * 64;
    int nvalid = min(64, N_ - n0);
    stage_swz((const float4*)iw2, B2s, t);
    if (t < 192) {
        iw1_s[t] = iw1[t];
        int n = n0 + t / 3;
        xin_s[t] = (n < N_) ? xin[(size_t)s * (N_ * 3) + n0 * 3 + t] : 0.f;
    }
    if (t < 64) { bias1[t] = ib1[t]; bias2[t] = ib2[t]; }
    if (t == 0) sa0s = softmax4(attn, 0);
    __syncthreads();
    int tn = t >> 4, to = t & 15;
    int tn4 = tn << 2, to4 = to << 2;
    float h1[4][4];
#pragma unroll
    for (int i = 0; i < 4; i++) {
        float a0 = xin_s[(tn4 + i) * 3], a1 = xin_s[(tn4 + i) * 3 + 1],
              a2 = xin_s[(tn4 + i) * 3 + 2];
#pragma unroll
        for (int k = 0; k < 4; k++) {
            int o = to4 + k;
            float h = bias1[o];
            h = fmaf(iw1_s[o * 3], a0, h);
            h = fmaf(iw1_s[o * 3 + 1], a1, h);
            h = fmaf(iw1_s[o * 3 + 2], a2, h);
            h1[i][k] = fmaxf(h, 0.f);
        }
    }
#pragma unroll
    for (int i = 0; i < 4; i++)
        *(float4*)&U[(tn4 + i) * 64 + (to4 ^ tn4)] =
            make_float4(h1[i][0], h1[i][1], h1[i][2], h1[i][3]);
    __syncthreads();
    float ov[4][4];
#pragma unroll
    for (int i = 0; i < 4; i++)
#pragma unroll
        for (int k = 0; k < 4; k++) ov[i][k] = bias2[to4 + k];
    gemm64(U, B2s, tn4, to4, ov);
    __syncthreads();
#pragma unroll
    for (int i = 0; i < 4; i++)
        *(float4*)&U[(tn4 + i) * 64 + to4] =
            make_float4(ov[i][0], ov[i][1], ov[i][2], ov[i][3]);
    __syncthreads();
    const float4* pp4 = (const float4*)pp + n0 * 16;
    const float4* gw4 = (const float4*)gw0 + n0 * 16;
    float4* xw4 = (float4*)xw + (size_t)s * (NH_ / 4) + n0 * 16;
    float4* ac4 = (float4*)acc + (size_t)s * (NH_ / 4) + n0 * 16;
    float sa0 = sa0s;
    float sm = 0.f, sq = 0.f;
    for (int f = t; f < 1024; f += 256) {
        int r = f >> 4;
        if (r < nvalid) {
            float4 v = ((const float4*)U)[f];
            float4 p = pp4[f];
            v.x += p.x; v.y += p.y; v.z += p.z; v.w += p.w;
            float4 a;
            a.x = sa0 * v.x; a.y = sa0 * v.y; a.z = sa0 * v.z; a.w = sa0 * v.w;
            ac4[f] = a;
            sm += v.x + v.y + v.z + v.w;
            sq += v.x * v.x + v.y * v.y + v.z * v.z + v.w * v.w;
            float4 g = gw4[f];
            v.x *= g.x; v.y *= g.y; v.z *= g.z; v.w *= g.w;
            xw4[f] = v;
        }
    }
    int w = t >> 6, lane = t & 63;
    sm = wred(sm); sq = wred(sq);
    if (lane == 0) { rsm[w] = sm; rsq[w] = sq; }
    __syncthreads();
    if (t == 0) {
        float2 pr;
        pr.x = rsm[0] + rsm[1] + rsm[2] + rsm[3];
        pr.y = rsq[0] + rsq[1] + rsq[2] + rsq[3];
        part[s * BPS_ + bn] = pr;
    }
}

// ---- LightGCN propagate: 2 slices/wave, LN folded, slim stat epilogue ------
__global__ void k_prop(const float* __restrict__ xw, const int* __restrict__ offs,
                       const int2* __restrict__ csr_pack, const float* __restrict__ Wt,
                       const float* __restrict__ Bt, const float* __restrict__ st,
                       float* __restrict__ y, float2* __restrict__ part) {
    __shared__ float bs[4][4];   // [wave][sm0,sq0,sm1,sq1]
    int t = threadIdx.x;
    int w = t >> 6, lane = t & 63;
    int sub = lane >> 4, hl = lane & 15;
    int orig = blockIdx.x;
    int gw = (orig & 7) * PROPPX_ + (orig >> 3);
    int pr = gw / BPS_;           // slice pair 0..11
    int blkin = gw % BPS_;
    int n = blkin * 4 + w;
    int s0 = pr * 2;
    const float4* xh0 = (const float4*)(xw + (size_t)s0 * NH_) + hl;
    const float4* xh1 = xh0 + (NH_ / 4);
    int e0 = offs[n], e1 = offs[n + 1];
    float4 A0 = make_float4(0, 0, 0, 0), A1 = make_float4(0, 0, 0, 0);
    for (int e = e0 + sub * 2; e < e1; e += 8) {
        int4 mp = *(const int4*)&csr_pack[e];     // edges e, e+1 (aligned: e even)
        float m0 = __int_as_float(mp.y), m1 = __int_as_float(mp.w);
        float4 a = xh0[mp.x], b = xh0[mp.z];
        float4 c = xh1[mp.x], d = xh1[mp.z];
        fma4(m0, a, A0); fma4(m1, b, A0);
        fma4(m0, c, A1); fma4(m1, d, A1);
    }
    xred4(A0); xred4(A1);       // substream totals; per-hl components remain distinct
    float mu0 = st[s0 * 2] * (1.f / NH_);
    float v0  = st[s0 * 2 + 1] * (1.f / NH_) - mu0 * mu0;
    float rs0 = rsqrtf(v0 + EPS_);
    float mu1 = st[s0 * 2 + 2] * (1.f / NH_);
    float v1  = st[s0 * 2 + 3] * (1.f / NH_) - mu1 * mu1;
    float rs1 = rsqrtf(v1 + EPS_);
    // all lanes compute y redundantly (free: formerly exec-masked slots)
    float4 wt = ((const float4*)Wt)[n * 16 + hl];
    float4 bt = ((const float4*)Bt)[n * 16 + hl];
    float c0 = -mu0 * rs0, c1 = -mu1 * rs1;
    float4 y0, y1;
    y0.x = fmaf(rs0, A0.x, fmaf(c0, wt.x, bt.x));
    y0.y = fmaf(rs0, A0.y, fmaf(c0, wt.y, bt.y));
    y0.z = fmaf(rs0, A0.z, fmaf(c0, wt.z, bt.z));
    y0.w = fmaf(rs0, A0.w, fmaf(c0, wt.w, bt.w));
    y1.x = fmaf(rs1, A1.x, fmaf(c1, wt.x, bt.x));
    y1.y = fmaf(rs1, A1.y, fmaf(c1, wt.y, bt.y));
    y1.z = fmaf(rs1, A1.z, fmaf(c1, wt.z, bt.z));
    y1.w = fmaf(rs1, A1.w, fmaf(c1, wt.w, bt.w));
    if (sub == 0) {
        float4* yp = (float4*)(y + (size_t)s0 * NH_ + n * 64);
        yp[hl] = y0;
        yp[NH_ / 4 + hl] = y1;
    }
    // sub-specialized stats: sub0=sum(y0) sub1=sumsq(y0) sub2=sum(y1) sub3=sumsq(y1)
    float4 ys;
    ys.x = (sub >= 2) ? y1.x : y0.x;
    ys.y = (sub >= 2) ? y1.y : y0.y;
    ys.z = (sub >= 2) ? y1.z : y0.z;
    ys.w = (sub >= 2) ? y1.w : y0.w;
    float sums = ys.x + ys.y + ys.z + ys.w;
    float dots = fmaf(ys.x, ys.x, fmaf(ys.y, ys.y, fmaf(ys.z, ys.z, ys.w * ys.w)));
    float val = (sub & 1) ? dots : sums;
#pragma unroll
    for (int d = 1; d <= 8; d <<= 1) val += __shfl_xor(val, d, 64);
    if ((lane & 15) == 0) bs[w][sub] = val;
    __syncthreads();
    if (t < 2) {   // t=0 -> slice s0, t=1 -> slice s0+1
        float2 p;
        p.x = bs[0][t * 2] + bs[1][t * 2] + bs[2][t * 2] + bs[3][t * 2];
        p.y = bs[0][t * 2 + 1] + bs[1][t * 2 + 1] + bs[2][t * 2 + 1] + bs[3][t * 2 + 1];
        part[(s0 + t) * BPS_ + blkin] = p;
    }
}

// ---- LN2 (inline) + 12x12 period mix + skip-acc + stats + x*w_next write ---
__global__ void k_mix(const float* __restrict__ y, const float* __restrict__ tnw,
                      const float* __restrict__ tnb, const float* __restrict__ tcw,
                      const float* __restrict__ tcb, const float* __restrict__ st2,
                      const float* __restrict__ attn, int ai,
                      const float* __restrict__ wnext, int wx,
                      float* __restrict__ xn, float* __restrict__ acc,
                      float2* __restrict__ part) {
    __shared__ float smu[12], srs[12], scw[144], scb[12], sstat[24];
    __shared__ float sa;
    int t = threadIdx.x;
    int gt = blockIdx.x * 256 + t;
    int b = gt / NH_, r = gt % NH_;
    if (t < 12) {
        int s = b * 12 + t;
        float mu = st2[s * 2] * (1.f / NH_);
        float var = st2[s * 2 + 1] * (1.f / NH_) - mu * mu;
        smu[t] = mu;
        srs[t] = rsqrtf(var + EPS_);
        scb[t] = tcb[t];
    }
    if (t < 144) scw[t] = tcw[t];
    if (t < 24) sstat[t] = 0.f;
    if (t == 0) sa = softmax4(attn, ai);
    __syncthreads();
    float wv = tnw[r], bv = tnb[r];
    float wn = wx ? wnext[r] : 0.f;
    float yn[12];
#pragma unroll
    for (int p = 0; p < 12; p++) {
        float v = y[(size_t)(b * 12 + p) * NH_ + r];
        yn[p] = (v - smu[p]) * srs[p] * wv + bv;
    }
    float ov[12];
#pragma unroll
    for (int q = 0; q < 12; q++) {
        float o = scb[q];
#pragma unroll
        for (int p = 0; p < 12; p++) o = fmaf(scw[q * 12 + p], yn[p], o);
        ov[q] = o;
        size_t idx = (size_t)(b * 12 + q) * NH_ + r;
        if (wx) xn[idx] = o * wn;
        acc[idx] += sa * o;
    }
    int lane = t & 63;
#pragma unroll
    for (int q = 0; q < 12; q++) {
        float sm = wred(ov[q]);
        float sq = wred(ov[q] * ov[q]);
        if (lane == 0) { atomicAdd(&sstat[q * 2], sm); atomicAdd(&sstat[q * 2 + 1], sq); }
    }
    __syncthreads();
    if (t < 12) {
        int jb = blockIdx.x % BPS_;
        float2 p; p.x = sstat[t * 2]; p.y = sstat[t * 2 + 1];
        part[(b * 12 + t) * BPS_ + jb] = p;
    }
}

// ---- final output projection (tile GEMM), in-place on d_out ----------------
__global__ void k_out(float* __restrict__ io, const float* __restrict__ w1,
                      const float* __restrict__ b1, const float* __restrict__ w2,
                      const float* __restrict__ b2) {
    __shared__ __align__(16) float U[4096];
    __shared__ __align__(16) float B1s[4096], B2s[4096];
    __shared__ float bias1[64], bias2[64];
    int t = threadIdx.x;
    int blk = blockIdx.x;
    int s = blk / NB64_, bn = blk % NB64_;
    int n0 = bn * 64;
    int nvalid = min(64, N_ - n0);
    const float4* io4 = (const float4*)io + (size_t)s * (NH_ / 4) + n0 * 16;
    stage_swz((const float4*)w1, B1s, t);
    stage_swz((const float4*)w2, B2s, t);
    stage_swz_guard(io4, U, t, nvalid);
    if (t < 64) { bias1[t] = b1[t]; bias2[t] = b2[t]; }
    __syncthreads();
    int tn = t >> 4, to = t & 15;
    int tn4 = tn << 2, to4 = to << 2;
    float ov[4][4];
#pragma unroll
    for (int i = 0; i < 4; i++)
#pragma unroll
        for (int k = 0; k < 4; k++) ov[i][k] = bias1[to4 + k];
    gemm64(U, B1s, tn4, to4, ov);
#pragma unroll
    for (int i = 0; i < 4; i++)
#pragma unroll
        for (int k = 0; k < 4; k++) ov[i][k] = fmaxf(ov[i][k], 0.f);
    __syncthreads();
#pragma unroll
    for (int i = 0; i < 4; i++)
        *(float4*)&U[(tn4 + i) * 64 + (to4 ^ tn4)] =
            make_float4(ov[i][0], ov[i][1], ov[i][2], ov[i][3]);
    __syncthreads();
    float ov2[4][4];
#pragma unroll
    for (int i = 0; i < 4; i++)
#pragma unroll
        for (int k = 0; k < 4; k++) ov2[i][k] = bias2[to4 + k];
    gemm64(U, B2s, tn4, to4, ov2);
    __syncthreads();
#pragma unroll
    for (int i = 0; i < 4; i++)
        *(float4*)&U[(tn4 + i) * 64 + to4] =
            make_float4(ov2[i][0], ov2[i][1], ov2[i][2], ov2[i][3]);
    __syncthreads();
    float4* io4w = (float4*)io + (size_t)s * (NH_ / 4) + n0 * 16;
    for (int f = t; f < 1024; f += 256) {
        int r = f >> 4;
        if (r < nvalid) io4w[f] = ((const float4*)U)[f];
    }
}

extern "C" void kernel_launch(void* const* d_in, const int* in_sizes, int n_in,
                              void* d_out, int out_size, void* d_ws, size_t ws_size,
                              hipStream_t stream) {
    (void)in_sizes; (void)n_in; (void)out_size; (void)ws_size;
    const float* x    = (const float*)d_in[0];
    const int*   ei   = (const int*)d_in[1];
    const float* pos  = (const float*)d_in[2];
    const float* iw1  = (const float*)d_in[3];
    const float* ib1  = (const float*)d_in[4];
    const float* iw2  = (const float*)d_in[5];
    const float* ib2  = (const float*)d_in[6];
    const float* pw1  = (const float*)d_in[7];
    const float* pb1  = (const float*)d_in[8];
    const float* pw2  = (const float*)d_in[9];
    const float* pb2  = (const float*)d_in[10];
    const float* attn = (const float*)d_in[11];
    const float* gnw  = (const float*)d_in[12];
    const float* gnb  = (const float*)d_in[13];
    const float* tnw  = (const float*)d_in[14];
    const float* tnb  = (const float*)d_in[15];
    const float* tcw  = (const float*)d_in[16];
    const float* tcb  = (const float*)d_in[17];
    const float* ow1  = (const float*)d_in[18];
    const float* ob1  = (const float*)d_in[19];
    const float* ow2  = (const float*)d_in[20];
    const float* ob2  = (const float*)d_in[21];
    float* out = (float*)d_out;

    float* xA = (float*)d_ws;
    float* xB = xA + (size_t)S_ * NH_;
    float* yb = xB + (size_t)S_ * NH_;
    float* pp = yb + (size_t)S_ * NH_;
    float* Wt = pp + NH_;
    float* Bt = Wt + NH_;
    int2* csr_pack = (int2*)(Bt + NH_);
    int* deg     = (int*)(csr_pack + EPAD_);
    int* offs    = deg + N_;
    int* cursor  = offs + N_ + 1;
    float* dis   = (float*)(cursor + N_);
    float* st1   = dis + N_;             // 4 iters * 24 slices * 2
    float* st2   = st1 + 4 * S_ * 2;     // 3 iters * 24 slices * 2
    float2* partA = (float2*)(((uintptr_t)(st2 + 3 * S_ * 2) + 15) & ~(uintptr_t)15);

    // zero csr_pack (pad entries must be {0, 0.0f}) and deg, contiguous region
    hipMemsetAsync(csr_pack, 0, (size_t)EPAD_ * sizeof(int2) + N_ * sizeof(int), stream);

    k_deg<<<(E_ + 255) / 256, 256, 0, stream>>>(ei, deg);
    k_scan<<<1, 1024, 0, stream>>>(deg, offs, cursor, dis);
    k_scatter<<<(E_ + 255) / 256, 256, 0, stream>>>(ei, dis, cursor, csr_pack);
    k_posproj<<<N_ / 4, 256, 0, stream>>>(pos, pw1, pb1, pw2, pb2, pp);
    k_in<<<S_ * NB64_, 256, 0, stream>>>(x, iw1, ib1, iw2, ib2, pp, attn, gnw,
                                         xA, out, partA);
    k_red<<<S_, 256, 0, stream>>>(partA, st1 + 0 * S_ * 2, NB64_);

    float* cur = xA;
    float* nxt = xB;
    for (int i = 0; i < NB_; i++) {
        k_wb<<<N_ / 4, 256, 0, stream>>>(offs, csr_pack, gnw + (size_t)i * NH_,
                                         gnb + (size_t)i * NH_, Wt, Bt);
        k_prop<<<PROPBLK_, 256, 0, stream>>>(cur, offs, csr_pack, Wt, Bt,
                                             st1 + i * S_ * 2, yb, partA);
        k_red<<<S_, 256, 0, stream>>>(partA, st2 + i * S_ * 2, BPS_);
        int wx = (i < NB_ - 1) ? 1 : 0;
        const float* wnext = gnw + (size_t)(i + 1 < NB_ ? i + 1 : 0) * NH_;
        k_mix<<<B_ * NH_ / 256, 256, 0, stream>>>(yb, tnw + (size_t)i * NH_,
                                                  tnb + (size_t)i * NH_, tcw + i * 144,
                                                  tcb + i * 12, st2 + i * S_ * 2, attn, i + 1,
                                                  wnext, wx, nxt, out, partA);
        if (i < NB_ - 1)
            k_red<<<S_, 256, 0, stream>>>(partA, st1 + (i + 1) * S_ * 2, BPS_);
        float* tmp = cur; cur = nxt; nxt = tmp;
    }
    k_out<<<S_ * NB64_, 256, 0, stream>>>(out, ow1, ob1, ow2, ob2);
}

// Round 10
// 731.241 us; speedup vs baseline: 6.8990x; 1.0335x over previous
//
#include <hip/hip_runtime.h>
#include <stdint.h>

constexpr int N_ = 10000, H_ = 64, P_ = 12, NB_ = 3, IN_ = 3, E_ = 160000, B_ = 2;
constexpr int S_  = B_ * P_;       // 24 slices (b,p)
constexpr int NH_ = N_ * H_;       // 640000 elements per slice
constexpr int BPS_ = N_ / 4;       // 2500 partial stride
constexpr int NB64_ = (N_ + 63) / 64;  // 157 64-node tiles per slice
constexpr int NPAIR_ = S_ / 2;     // 12 slice pairs
constexpr int PROPNB_ = N_ / 8;    // 1250 blocks per pair (8 nodes/block)
constexpr int PROPBLK_ = NPAIR_ * PROPNB_;  // 15000 blocks, %8==0
constexpr int PROPPX_  = PROPBLK_ / 8;      // 1875 per XCD
constexpr int EPAD_ = E_ + N_;     // CSR with per-node even padding
constexpr float EPS_ = 1e-5f;

#define DEVFN __device__ __forceinline__

DEVFN float softmax4(const float* a, int k) {
    float m = fmaxf(fmaxf(a[0], a[1]), fmaxf(a[2], a[3]));
    float e0 = __expf(a[0] - m), e1 = __expf(a[1] - m);
    float e2 = __expf(a[2] - m), e3 = __expf(a[3] - m);
    float s = e0 + e1 + e2 + e3;
    float ek = (k == 0 ? e0 : k == 1 ? e1 : k == 2 ? e2 : e3);
    return ek / s;
}

DEVFN float wred(float v) {
#pragma unroll
    for (int d = 32; d; d >>= 1) v += __shfl_xor(v, d, 64);
    return v;
}

DEVFN void fma4(float m, const float4& a, float4& acc) {
    acc.x = fmaf(m, a.x, acc.x); acc.y = fmaf(m, a.y, acc.y);
    acc.z = fmaf(m, a.z, acc.z); acc.w = fmaf(m, a.w, acc.w);
}

DEVFN void xred4(float4& a) {
    a.x += __shfl_xor(a.x, 16, 64); a.y += __shfl_xor(a.y, 16, 64);
    a.z += __shfl_xor(a.z, 16, 64); a.w += __shfl_xor(a.w, 16, 64);
    a.x += __shfl_xor(a.x, 32, 64); a.y += __shfl_xor(a.y, 32, 64);
    a.z += __shfl_xor(a.z, 32, 64); a.w += __shfl_xor(a.w, 32, 64);
}

// ---- swizzled 64x64 tile helpers -------------------------------------------
DEVFN void stage_swz(const float4* __restrict__ src, float* __restrict__ dst, int t) {
    for (int f = t; f < 1024; f += 256) {
        int r = f >> 4, c4 = f & 15;
        float4 v = src[f];
        *(float4*)&dst[r * 64 + ((c4 ^ (r >> 2)) << 2)] = v;
    }
}

DEVFN void stage_swz_guard(const float4* __restrict__ src, float* __restrict__ dst,
                           int t, int nvalid) {
    for (int f = t; f < 1024; f += 256) {
        int r = f >> 4, c4 = f & 15;
        float4 v = make_float4(0.f, 0.f, 0.f, 0.f);
        if (r < nvalid) v = src[f];
        *(float4*)&dst[r * 64 + ((c4 ^ (r >> 2)) << 2)] = v;
    }
}

DEVFN void gemm64(const float* __restrict__ As, const float* __restrict__ Bs,
                  int tn4, int to4, float ov[4][4]) {
    const float* arow = As + tn4 * 64;
    const float* brow = Bs + to4 * 64;
#pragma unroll 4
    for (int j4 = 0; j4 < 16; ++j4) {
        int ca = (j4 << 2) ^ tn4;
        int cb = (j4 << 2) ^ to4;
        float4 a[4], b[4];
#pragma unroll
        for (int i = 0; i < 4; ++i) a[i] = *(const float4*)&arow[i * 64 + ca];
#pragma unroll
        for (int k = 0; k < 4; ++k) b[k] = *(const float4*)&brow[k * 64 + cb];
#pragma unroll
        for (int i = 0; i < 4; ++i)
#pragma unroll
            for (int k = 0; k < 4; ++k) {
                ov[i][k] = fmaf(a[i].x, b[k].x, ov[i][k]);
                ov[i][k] = fmaf(a[i].y, b[k].y, ov[i][k]);
                ov[i][k] = fmaf(a[i].z, b[k].z, ov[i][k]);
                ov[i][k] = fmaf(a[i].w, b[k].w, ov[i][k]);
            }
    }
}

// ---- CSR build (degrees padded to even for int4 metadata loads) ------------
__global__ void k_deg(const int* __restrict__ ei, int* __restrict__ deg) {
    int e = blockIdx.x * 256 + threadIdx.x;
    if (e < E_) atomicAdd(&deg[ei[E_ + e]], 1);
}

__global__ void k_scan(const int* __restrict__ deg, int* __restrict__ offs,
                       int* __restrict__ cursor, float* __restrict__ dis) {
    __shared__ int part[1024];
    int t = threadIdx.x;
    int base = t * 10;
    int cnt = 0;
    for (int k = 0; k < 10; k++) {
        int i = base + k;
        if (i < N_) cnt += (deg[i] + 1) & ~1;   // padded degree
    }
    part[t] = cnt;
    __syncthreads();
    for (int d = 1; d < 1024; d <<= 1) {
        int v = 0;
        if (t >= d) v = part[t - d];
        __syncthreads();
        if (t >= d) part[t] += v;
        __syncthreads();
    }
    int run = (t > 0) ? part[t - 1] : 0;
    for (int k = 0; k < 10; k++) {
        int i = base + k;
        if (i < N_) {
            offs[i] = run; cursor[i] = run;
            int dg = deg[i];
            dis[i] = dg > 0 ? rsqrtf((float)dg) : 0.f;
            run += (dg + 1) & ~1;
        }
    }
    if (t == 1023) offs[N_] = part[1023];
}

__global__ void k_scatter(const int* __restrict__ ei, const float* __restrict__ dis,
                          int* __restrict__ cursor, int2* __restrict__ csr_pack) {
    int e = blockIdx.x * 256 + threadIdx.x;
    if (e >= E_) return;
    int r = ei[e], c = ei[E_ + e];
    float nm = dis[r] * dis[c];
    int p = atomicAdd(&cursor[c], 1);
    csr_pack[p] = make_int2(r << 4, __float_as_int(nm));  // r*16 = float4 row base
}

// ---- per-slice stats reduce ------------------------------------------------
__global__ void k_red(const float2* __restrict__ part, float* __restrict__ st, int count) {
    __shared__ float rsm[4], rsq[4];
    int s = blockIdx.x, t = threadIdx.x, w = t >> 6, lane = t & 63;
    float sm = 0.f, sq = 0.f;
    for (int k = t; k < count; k += 256) {
        float2 p = part[s * BPS_ + k];
        sm += p.x; sq += p.y;
    }
    sm = wred(sm); sq = wred(sq);
    if (lane == 0) { rsm[w] = sm; rsq[w] = sq; }
    __syncthreads();
    if (t == 0) {
        st[s * 2]     = rsm[0] + rsm[1] + rsm[2] + rsm[3];
        st[s * 2 + 1] = rsq[0] + rsq[1] + rsq[2] + rsq[3];
    }
}

// ---- W~ / B~ gather: Wt[c,h] = sum nrm*gw[r,h], Bt likewise ---------------
__global__ void k_wb(const int* __restrict__ offs, const int2* __restrict__ csr_pack,
                     const float* __restrict__ gw, const float* __restrict__ gb,
                     float* __restrict__ Wt, float* __restrict__ Bt) {
    int t = threadIdx.x;
    int w = t >> 6, lane = t & 63;
    int sub = lane >> 4, hl = lane & 15;
    int n = blockIdx.x * 4 + w;
    const float4* W4 = (const float4*)gw;
    const float4* B4 = (const float4*)gb;
    int e0 = offs[n], e1 = offs[n + 1];
    float4 AW = make_float4(0, 0, 0, 0), AB = make_float4(0, 0, 0, 0);
    for (int e = e0 + sub * 2; e < e1; e += 8) {
        int4 mp = *(const int4*)&csr_pack[e];
        float m0 = __int_as_float(mp.y), m1 = __int_as_float(mp.w);
        int i0 = mp.x + hl, i1 = mp.z + hl;
        float4 a = W4[i0], b = W4[i1], c = B4[i0], d = B4[i1];
        fma4(m0, a, AW); fma4(m1, b, AW);
        fma4(m0, c, AB); fma4(m1, d, AB);
    }
    xred4(AW); xred4(AB);
    if (sub == 0) {
        ((float4*)Wt)[n * 16 + hl] = AW;
        ((float4*)Bt)[n * 16 + hl] = AB;
    }
}

// ---- pos projection: pos[N,64] -> pp[N,64] ---------------------------------
__global__ void k_posproj(const float* __restrict__ pos, const float* __restrict__ w1,
                          const float* __restrict__ b1, const float* __restrict__ w2,
                          const float* __restrict__ b2, float* __restrict__ out) {
    __shared__ float w1T[64 * 65], w2T[64 * 65];
    __shared__ float stage[4][64];
    int t = threadIdx.x;
    for (int k = t; k < 4096; k += 256) {
        int o = k >> 6, j = k & 63;
        w1T[j * 65 + o] = w1[k];
        w2T[j * 65 + o] = w2[k];
    }
    __syncthreads();
    int w = t >> 6, lane = t & 63;
    int n = blockIdx.x * 4 + w;
    float v = pos[n * 64 + lane];
    stage[w][lane] = v;
    float h = b1[lane];
#pragma unroll
    for (int j = 0; j < 64; j++) h = fmaf(w1T[j * 65 + lane], stage[w][j], h);
    h = fmaxf(h, 0.f);
    stage[w][lane] = h;
    float o2 = b2[lane];
#pragma unroll
    for (int j = 0; j < 64; j++) o2 = fmaf(w2T[j * 65 + lane], stage[w][j], o2);
    out[n * 64 + lane] = o2;
}

// ---- input projection (tile GEMM) + pos add + acc init + stats + x*w write -
__global__ void k_in(const float* __restrict__ xin, const float* __restrict__ iw1,
                     const float* __restrict__ ib1, const float* __restrict__ iw2,
                     const float* __restrict__ ib2, const float* __restrict__ pp,
                     const float* __restrict__ attn, const float* __restrict__ gw0,
                     float* __restrict__ xw, float* __restrict__ acc,
                     float2* __restrict__ part) {
    __shared__ __align__(16) float U[4096];
    __shared__ __align__(16) float B2s[4096];
    __shared__ float xin_s[192], iw1_s[192], bias1[64], bias2[64];
    __shared__ float rsm[4], rsq[4], sa0s;
    int t = threadIdx.x;
    int blk = blockIdx.x;
    int s = blk / NB64_, bn = blk % NB64_;
    int n0 = bn * 64;
    int nvalid = min(64, N_ - n0);
    stage_swz((const float4*)iw2, B2s, t);
    if (t < 192) {
        iw1_s[t] = iw1[t];
        int n = n0 + t / 3;
        xin_s[t] = (n < N_) ? xin[(size_t)s * (N_ * 3) + n0 * 3 + t] : 0.f;
    }
    if (t < 64) { bias1[t] = ib1[t]; bias2[t] = ib2[t]; }
    if (t == 0) sa0s = softmax4(attn, 0);
    __syncthreads();
    int tn = t >> 4, to = t & 15;
    int tn4 = tn << 2, to4 = to << 2;
    float h1[4][4];
#pragma unroll
    for (int i = 0; i < 4; i++) {
        float a0 = xin_s[(tn4 + i) * 3], a1 = xin_s[(tn4 + i) * 3 + 1],
              a2 = xin_s[(tn4 + i) * 3 + 2];
#pragma unroll
        for (int k = 0; k < 4; k++) {
            int o = to4 + k;
            float h = bias1[o];
            h = fmaf(iw1_s[o * 3], a0, h);
            h = fmaf(iw1_s[o * 3 + 1], a1, h);
            h = fmaf(iw1_s[o * 3 + 2], a2, h);
            h1[i][k] = fmaxf(h, 0.f);
        }
    }
#pragma unroll
    for (int i = 0; i < 4; i++)
        *(float4*)&U[(tn4 + i) * 64 + (to4 ^ tn4)] =
            make_float4(h1[i][0], h1[i][1], h1[i][2], h1[i][3]);
    __syncthreads();
    float ov[4][4];
#pragma unroll
    for (int i = 0; i < 4; i++)
#pragma unroll
        for (int k = 0; k < 4; k++) ov[i][k] = bias2[to4 + k];
    gemm64(U, B2s, tn4, to4, ov);
    __syncthreads();
#pragma unroll
    for (int i = 0; i < 4; i++)
        *(float4*)&U[(tn4 + i) * 64 + to4] =
            make_float4(ov[i][0], ov[i][1], ov[i][2], ov[i][3]);
    __syncthreads();
    const float4* pp4 = (const float4*)pp + n0 * 16;
    const float4* gw4 = (const float4*)gw0 + n0 * 16;
    float4* xw4 = (float4*)xw + (size_t)s * (NH_ / 4) + n0 * 16;
    float4* ac4 = (float4*)acc + (size_t)s * (NH_ / 4) + n0 * 16;
    float sa0 = sa0s;
    float sm = 0.f, sq = 0.f;
    for (int f = t; f < 1024; f += 256) {
        int r = f >> 4;
        if (r < nvalid) {
            float4 v = ((const float4*)U)[f];
            float4 p = pp4[f];
            v.x += p.x; v.y += p.y; v.z += p.z; v.w += p.w;
            float4 a;
            a.x = sa0 * v.x; a.y = sa0 * v.y; a.z = sa0 * v.z; a.w = sa0 * v.w;
            ac4[f] = a;
            sm += v.x + v.y + v.z + v.w;
            sq += v.x * v.x + v.y * v.y + v.z * v.z + v.w * v.w;
            float4 g = gw4[f];
            v.x *= g.x; v.y *= g.y; v.z *= g.z; v.w *= g.w;
            xw4[f] = v;
        }
    }
    int w = t >> 6, lane = t & 63;
    sm = wred(sm); sq = wred(sq);
    if (lane == 0) { rsm[w] = sm; rsq[w] = sq; }
    __syncthreads();
    if (t == 0) {
        float2 pr;
        pr.x = rsm[0] + rsm[1] + rsm[2] + rsm[3];
        pr.y = rsq[0] + rsq[1] + rsq[2] + rsq[3];
        part[s * BPS_ + bn] = pr;
    }
}

// ---- LightGCN propagate: 2 slices x 2 nodes per wave, LN folded ------------
__global__ void k_prop(const float* __restrict__ xw, const int* __restrict__ offs,
                       const int2* __restrict__ csr_pack, const float* __restrict__ Wt,
                       const float* __restrict__ Bt, const float* __restrict__ st,
                       float* __restrict__ y, float2* __restrict__ part) {
    __shared__ float bs[4][2][4];   // [wave][node][sum0,sq0,sum1,sq1]
    int t = threadIdx.x;
    int w = t >> 6, lane = t & 63;
    int nsel = lane >> 5;          // node within wave (half-wave per node)
    int str  = (lane >> 4) & 1;    // edge stream within node
    int hl   = lane & 15;          // float4 column
    int orig = blockIdx.x;
    int gw = (orig & 7) * PROPPX_ + (orig >> 3);
    int pr = gw / PROPNB_;         // slice pair 0..11
    int blkin = gw % PROPNB_;      // 0..1249
    int n = blkin * 8 + w * 2 + nsel;
    int s0 = pr * 2;
    const float4* xh0 = (const float4*)(xw + (size_t)s0 * NH_) + hl;
    const float4* xh1 = xh0 + (NH_ / 4);
    int e0 = offs[n], e1 = offs[n + 1];
    float4 A0 = make_float4(0, 0, 0, 0), A1 = make_float4(0, 0, 0, 0);
    int e = e0 + str * 2;
    while (__any(e < e1)) {
        if (e < e1) {
            int4 mp = *(const int4*)&csr_pack[e];   // edges e, e+1 (e even)
            float m0 = __int_as_float(mp.y), m1 = __int_as_float(mp.w);
            float4 a = xh0[mp.x], b = xh0[mp.z];
            float4 c = xh1[mp.x], d = xh1[mp.z];
            fma4(m0, a, A0); fma4(m1, b, A0);
            fma4(m0, c, A1); fma4(m1, d, A1);
        }
        e += 4;
    }
    // reduce the 2 streams of each half-wave (lanes differing in bit 4)
    A0.x += __shfl_xor(A0.x, 16, 64); A0.y += __shfl_xor(A0.y, 16, 64);
    A0.z += __shfl_xor(A0.z, 16, 64); A0.w += __shfl_xor(A0.w, 16, 64);
    A1.x += __shfl_xor(A1.x, 16, 64); A1.y += __shfl_xor(A1.y, 16, 64);
    A1.z += __shfl_xor(A1.z, 16, 64); A1.w += __shfl_xor(A1.w, 16, 64);
    float mu0 = st[s0 * 2] * (1.f / NH_);
    float v0  = st[s0 * 2 + 1] * (1.f / NH_) - mu0 * mu0;
    float rs0 = rsqrtf(v0 + EPS_);
    float mu1 = st[s0 * 2 + 2] * (1.f / NH_);
    float v1  = st[s0 * 2 + 3] * (1.f / NH_) - mu1 * mu1;
    float rs1 = rsqrtf(v1 + EPS_);
    float4 wt = ((const float4*)Wt)[n * 16 + hl];
    float4 bt = ((const float4*)Bt)[n * 16 + hl];
    float c0 = -mu0 * rs0, c1 = -mu1 * rs1;
    float4 y0, y1;
    y0.x = fmaf(rs0, A0.x, fmaf(c0, wt.x, bt.x));
    y0.y = fmaf(rs0, A0.y, fmaf(c0, wt.y, bt.y));
    y0.z = fmaf(rs0, A0.z, fmaf(c0, wt.z, bt.z));
    y0.w = fmaf(rs0, A0.w, fmaf(c0, wt.w, bt.w));
    y1.x = fmaf(rs1, A1.x, fmaf(c1, wt.x, bt.x));
    y1.y = fmaf(rs1, A1.y, fmaf(c1, wt.y, bt.y));
    y1.z = fmaf(rs1, A1.z, fmaf(c1, wt.z, bt.z));
    y1.w = fmaf(rs1, A1.w, fmaf(c1, wt.w, bt.w));
    if (str == 0) {
        float4* yp = (float4*)(y + (size_t)s0 * NH_ + (size_t)n * 64);
        yp[hl] = y0;
        yp[NH_ / 4 + hl] = y1;
    }
    // per-half stats: str0 reduces sums, str1 reduces sumsqs (both slices)
    float sum0 = y0.x + y0.y + y0.z + y0.w;
    float dot0 = fmaf(y0.x, y0.x, fmaf(y0.y, y0.y, fmaf(y0.z, y0.z, y0.w * y0.w)));
    float sum1 = y1.x + y1.y + y1.z + y1.w;
    float dot1 = fmaf(y1.x, y1.x, fmaf(y1.y, y1.y, fmaf(y1.z, y1.z, y1.w * y1.w)));
    float va = str ? dot0 : sum0;
    float vb = str ? dot1 : sum1;
#pragma unroll
    for (int d = 1; d <= 8; d <<= 1) {
        va += __shfl_xor(va, d, 64);
        vb += __shfl_xor(vb, d, 64);
    }
    if (hl == 0) {
        bs[w][nsel][str] = va;        // [0]=sum(y0) [1]=sumsq(y0)
        bs[w][nsel][2 + str] = vb;    // [2]=sum(y1) [3]=sumsq(y1)
    }
    __syncthreads();
    if (t < 2) {   // t -> slice s0+t
        float psm = 0.f, psq = 0.f;
#pragma unroll
        for (int w2 = 0; w2 < 4; w2++)
#pragma unroll
            for (int ns = 0; ns < 2; ns++) {
                psm += bs[w2][ns][t * 2];
                psq += bs[w2][ns][t * 2 + 1];
            }
        part[(s0 + t) * BPS_ + blkin] = make_float2(psm, psq);
    }
}

// ---- LN2 (inline) + 12x12 period mix + skip-acc + slim stats ---------------
__global__ void k_mix(const float* __restrict__ y, const float* __restrict__ tnw,
                      const float* __restrict__ tnb, const float* __restrict__ tcw,
                      const float* __restrict__ tcb, const float* __restrict__ st2,
                      const float* __restrict__ attn, int ai,
                      const float* __restrict__ wnext, int wx,
                      float* __restrict__ xn, float* __restrict__ acc,
                      float2* __restrict__ part) {
    __shared__ float smu[12], srs[12], scw[144], scb[12];
    __shared__ float sred[24][16];
    __shared__ float sa;
    int t = threadIdx.x;
    int gt = blockIdx.x * 256 + t;
    int b = gt / NH_, r = gt % NH_;
    if (t < 12) {
        int s = b * 12 + t;
        float mu = st2[s * 2] * (1.f / NH_);
        float var = st2[s * 2 + 1] * (1.f / NH_) - mu * mu;
        smu[t] = mu;
        srs[t] = rsqrtf(var + EPS_);
        scb[t] = tcb[t];
    }
    if (t < 144) scw[t] = tcw[t];
    if (t == 0) sa = softmax4(attn, ai);
    __syncthreads();
    float wv = tnw[r], bv = tnb[r];
    float wn = wx ? wnext[r] : 0.f;
    float yn[12];
#pragma unroll
    for (int p = 0; p < 12; p++) {
        float v = y[(size_t)(b * 12 + p) * NH_ + r];
        yn[p] = (v - smu[p]) * srs[p] * wv + bv;
    }
    float ov[12];
#pragma unroll
    for (int q = 0; q < 12; q++) {
        float o = scb[q];
#pragma unroll
        for (int p = 0; p < 12; p++) o = fmaf(scw[q * 12 + p], yn[p], o);
        ov[q] = o;
        size_t idx = (size_t)(b * 12 + q) * NH_ + r;
        if (wx) xn[idx] = o * wn;
        acc[idx] += sa * o;
    }
    int lane = t & 63;
    int w = t >> 6;
#pragma unroll
    for (int q = 0; q < 12; q++) {
        float sm = ov[q];
        float sq = ov[q] * ov[q];
#pragma unroll
        for (int d = 1; d <= 8; d <<= 1) {
            sm += __shfl_xor(sm, d, 64);
            sq += __shfl_xor(sq, d, 64);
        }
        if ((lane & 15) == 0) {
            int widx = (w << 2) | (lane >> 4);
            sred[q * 2][widx] = sm;
            sred[q * 2 + 1][widx] = sq;
        }
    }
    __syncthreads();
    if (t < 12) {
        float psm = 0.f, psq = 0.f;
#pragma unroll
        for (int k = 0; k < 16; k++) {
            psm += sred[t * 2][k];
            psq += sred[t * 2 + 1][k];
        }
        int jb = blockIdx.x % BPS_;
        part[(b * 12 + t) * BPS_ + jb] = make_float2(psm, psq);
    }
}

// ---- final output projection (tile GEMM), in-place on d_out ----------------
__global__ void k_out(float* __restrict__ io, const float* __restrict__ w1,
                      const float* __restrict__ b1, const float* __restrict__ w2,
                      const float* __restrict__ b2) {
    __shared__ __align__(16) float U[4096];
    __shared__ __align__(16) float B1s[4096], B2s[4096];
    __shared__ float bias1[64], bias2[64];
    int t = threadIdx.x;
    int blk = blockIdx.x;
    int s = blk / NB64_, bn = blk % NB64_;
    int n0 = bn * 64;
    int nvalid = min(64, N_ - n0);
    const float4* io4 = (const float4*)io + (size_t)s * (NH_ / 4) + n0 * 16;
    stage_swz((const float4*)w1, B1s, t);
    stage_swz((const float4*)w2, B2s, t);
    stage_swz_guard(io4, U, t, nvalid);
    if (t < 64) { bias1[t] = b1[t]; bias2[t] = b2[t]; }
    __syncthreads();
    int tn = t >> 4, to = t & 15;
    int tn4 = tn << 2, to4 = to << 2;
    float ov[4][4];
#pragma unroll
    for (int i = 0; i < 4; i++)
#pragma unroll
        for (int k = 0; k < 4; k++) ov[i][k] = bias1[to4 + k];
    gemm64(U, B1s, tn4, to4, ov);
#pragma unroll
    for (int i = 0; i < 4; i++)
#pragma unroll
        for (int k = 0; k < 4; k++) ov[i][k] = fmaxf(ov[i][k], 0.f);
    __syncthreads();
#pragma unroll
    for (int i = 0; i < 4; i++)
        *(float4*)&U[(tn4 + i) * 64 + (to4 ^ tn4)] =
            make_float4(ov[i][0], ov[i][1], ov[i][2], ov[i][3]);
    __syncthreads();
    float ov2[4][4];
#pragma unroll
    for (int i = 0; i < 4; i++)
#pragma unroll
        for (int k = 0; k < 4; k++) ov2[i][k] = bias2[to4 + k];
    gemm64(U, B2s, tn4, to4, ov2);
    __syncthreads();
#pragma unroll
    for (int i = 0; i < 4; i++)
        *(float4*)&U[(tn4 + i) * 64 + to4] =
            make_float4(ov2[i][0], ov2[i][1], ov2[i][2], ov2[i][3]);
    __syncthreads();
    float4* io4w = (float4*)io + (size_t)s * (NH_ / 4) + n0 * 16;
    for (int f = t; f < 1024; f += 256) {
        int r = f >> 4;
        if (r < nvalid) io4w[f] = ((const float4*)U)[f];
    }
}

extern "C" void kernel_launch(void* const* d_in, const int* in_sizes, int n_in,
                              void* d_out, int out_size, void* d_ws, size_t ws_size,
                              hipStream_t stream) {
    (void)in_sizes; (void)n_in; (void)out_size; (void)ws_size;
    const float* x    = (const float*)d_in[0];
    const int*   ei   = (const int*)d_in[1];
    const float* pos  = (const float*)d_in[2];
    const float* iw1  = (const float*)d_in[3];
    const float* ib1  = (const float*)d_in[4];
    const float* iw2  = (const float*)d_in[5];
    const float* ib2  = (const float*)d_in[6];
    const float* pw1  = (const float*)d_in[7];
    const float* pb1  = (const float*)d_in[8];
    const float* pw2  = (const float*)d_in[9];
    const float* pb2  = (const float*)d_in[10];
    const float* attn = (const float*)d_in[11];
    const float* gnw  = (const float*)d_in[12];
    const float* gnb  = (const float*)d_in[13];
    const float* tnw  = (const float*)d_in[14];
    const float* tnb  = (const float*)d_in[15];
    const float* tcw  = (const float*)d_in[16];
    const float* tcb  = (const float*)d_in[17];
    const float* ow1  = (const float*)d_in[18];
    const float* ob1  = (const float*)d_in[19];
    const float* ow2  = (const float*)d_in[20];
    const float* ob2  = (const float*)d_in[21];
    float* out = (float*)d_out;

    float* xA = (float*)d_ws;
    float* xB = xA + (size_t)S_ * NH_;
    float* yb = xB + (size_t)S_ * NH_;
    float* pp = yb + (size_t)S_ * NH_;
    float* Wt = pp + NH_;
    float* Bt = Wt + NH_;
    int2* csr_pack = (int2*)(Bt + NH_);
    int* deg     = (int*)(csr_pack + EPAD_);
    int* offs    = deg + N_;
    int* cursor  = offs + N_ + 1;
    float* dis   = (float*)(cursor + N_);
    float* st1   = dis + N_;             // 4 iters * 24 slices * 2
    float* st2   = st1 + 4 * S_ * 2;     // 3 iters * 24 slices * 2
    float2* partA = (float2*)(((uintptr_t)(st2 + 3 * S_ * 2) + 15) & ~(uintptr_t)15);

    // zero csr_pack (pad entries must be {0, 0.0f}) and deg, contiguous region
    hipMemsetAsync(csr_pack, 0, (size_t)EPAD_ * sizeof(int2) + N_ * sizeof(int), stream);

    k_deg<<<(E_ + 255) / 256, 256, 0, stream>>>(ei, deg);
    k_scan<<<1, 1024, 0, stream>>>(deg, offs, cursor, dis);
    k_scatter<<<(E_ + 255) / 256, 256, 0, stream>>>(ei, dis, cursor, csr_pack);
    k_posproj<<<N_ / 4, 256, 0, stream>>>(pos, pw1, pb1, pw2, pb2, pp);
    k_in<<<S_ * NB64_, 256, 0, stream>>>(x, iw1, ib1, iw2, ib2, pp, attn, gnw,
                                         xA, out, partA);
    k_red<<<S_, 256, 0, stream>>>(partA, st1 + 0 * S_ * 2, NB64_);

    float* cur = xA;
    float* nxt = xB;
    for (int i = 0; i < NB_; i++) {
        k_wb<<<N_ / 4, 256, 0, stream>>>(offs, csr_pack, gnw + (size_t)i * NH_,
                                         gnb + (size_t)i * NH_, Wt, Bt);
        k_prop<<<PROPBLK_, 256, 0, stream>>>(cur, offs, csr_pack, Wt, Bt,
                                             st1 + i * S_ * 2, yb, partA);
        k_red<<<S_, 256, 0, stream>>>(partA, st2 + i * S_ * 2, PROPNB_);
        int wx = (i < NB_ - 1) ? 1 : 0;
        const float* wnext = gnw + (size_t)(i + 1 < NB_ ? i + 1 : 0) * NH_;
        k_mix<<<B_ * NH_ / 256, 256, 0, stream>>>(yb, tnw + (size_t)i * NH_,
                                                  tnb + (size_t)i * NH_, tcw + i * 144,
                                                  tcb + i * 12, st2 + i * S_ * 2, attn, i + 1,
                                                  wnext, wx, nxt, out, partA);
        if (i < NB_ - 1)
            k_red<<<S_, 256, 0, stream>>>(partA, st1 + (i + 1) * S_ * 2, BPS_);
        float* tmp = cur; cur = nxt; nxt = tmp;
    }
    k_out<<<S_ * NB64_, 256, 0, stream>>>(out, ow1, ob1, ow2, ob2);
}

// Round 11
// 722.527 us; speedup vs baseline: 6.9822x; 1.0121x over previous
//
#include <hip/hip_runtime.h>
#include <stdint.h>

constexpr int N_ = 10000, H_ = 64, P_ = 12, NB_ = 3, IN_ = 3, E_ = 160000, B_ = 2;
constexpr int S_  = B_ * P_;       // 24 slices (b,p)
constexpr int NH_ = N_ * H_;       // 640000 elements per slice
constexpr int BPS_ = N_ / 4;       // 2500 partial stride
constexpr int NB64_ = (N_ + 63) / 64;  // 157 64-node tiles per slice
constexpr int PROPNB_ = N_ / 16;   // 625 blocks per slice (16 nodes/block)
constexpr int PROPBLK_ = S_ * PROPNB_;  // 15000 blocks, %8==0
constexpr int PROPPX_  = PROPBLK_ / 8;  // 1875 per XCD -> 3 slices per XCD
constexpr int EPAD_ = E_ + N_;     // CSR with per-node even padding
constexpr float EPS_ = 1e-5f;

#define DEVFN __device__ __forceinline__

DEVFN float softmax4(const float* a, int k) {
    float m = fmaxf(fmaxf(a[0], a[1]), fmaxf(a[2], a[3]));
    float e0 = __expf(a[0] - m), e1 = __expf(a[1] - m);
    float e2 = __expf(a[2] - m), e3 = __expf(a[3] - m);
    float s = e0 + e1 + e2 + e3;
    float ek = (k == 0 ? e0 : k == 1 ? e1 : k == 2 ? e2 : e3);
    return ek / s;
}

DEVFN float wred(float v) {
#pragma unroll
    for (int d = 32; d; d >>= 1) v += __shfl_xor(v, d, 64);
    return v;
}

DEVFN void fma4(float m, const float4& a, float4& acc) {
    acc.x = fmaf(m, a.x, acc.x); acc.y = fmaf(m, a.y, acc.y);
    acc.z = fmaf(m, a.z, acc.z); acc.w = fmaf(m, a.w, acc.w);
}

DEVFN void xred4(float4& a) {
    a.x += __shfl_xor(a.x, 16, 64); a.y += __shfl_xor(a.y, 16, 64);
    a.z += __shfl_xor(a.z, 16, 64); a.w += __shfl_xor(a.w, 16, 64);
    a.x += __shfl_xor(a.x, 32, 64); a.y += __shfl_xor(a.y, 32, 64);
    a.z += __shfl_xor(a.z, 32, 64); a.w += __shfl_xor(a.w, 32, 64);
}

// ---- swizzled 64x64 tile helpers -------------------------------------------
DEVFN void stage_swz(const float4* __restrict__ src, float* __restrict__ dst, int t) {
    for (int f = t; f < 1024; f += 256) {
        int r = f >> 4, c4 = f & 15;
        float4 v = src[f];
        *(float4*)&dst[r * 64 + ((c4 ^ (r >> 2)) << 2)] = v;
    }
}

DEVFN void stage_swz_guard(const float4* __restrict__ src, float* __restrict__ dst,
                           int t, int nvalid) {
    for (int f = t; f < 1024; f += 256) {
        int r = f >> 4, c4 = f & 15;
        float4 v = make_float4(0.f, 0.f, 0.f, 0.f);
        if (r < nvalid) v = src[f];
        *(float4*)&dst[r * 64 + ((c4 ^ (r >> 2)) << 2)] = v;
    }
}

DEVFN void gemm64(const float* __restrict__ As, const float* __restrict__ Bs,
                  int tn4, int to4, float ov[4][4]) {
    const float* arow = As + tn4 * 64;
    const float* brow = Bs + to4 * 64;
#pragma unroll 4
    for (int j4 = 0; j4 < 16; ++j4) {
        int ca = (j4 << 2) ^ tn4;
        int cb = (j4 << 2) ^ to4;
        float4 a[4], b[4];
#pragma unroll
        for (int i = 0; i < 4; ++i) a[i] = *(const float4*)&arow[i * 64 + ca];
#pragma unroll
        for (int k = 0; k < 4; ++k) b[k] = *(const float4*)&brow[k * 64 + cb];
#pragma unroll
        for (int i = 0; i < 4; ++i)
#pragma unroll
            for (int k = 0; k < 4; ++k) {
                ov[i][k] = fmaf(a[i].x, b[k].x, ov[i][k]);
                ov[i][k] = fmaf(a[i].y, b[k].y, ov[i][k]);
                ov[i][k] = fmaf(a[i].z, b[k].z, ov[i][k]);
                ov[i][k] = fmaf(a[i].w, b[k].w, ov[i][k]);
            }
    }
}

// ---- CSR build (degrees padded to even for int4 metadata loads) ------------
__global__ void k_deg(const int* __restrict__ ei, int* __restrict__ deg) {
    int e = blockIdx.x * 256 + threadIdx.x;
    if (e < E_) atomicAdd(&deg[ei[E_ + e]], 1);
}

__global__ void k_scan(const int* __restrict__ deg, int* __restrict__ offs,
                       int* __restrict__ cursor, float* __restrict__ dis) {
    __shared__ int part[1024];
    int t = threadIdx.x;
    int base = t * 10;
    int cnt = 0;
    for (int k = 0; k < 10; k++) {
        int i = base + k;
        if (i < N_) cnt += (deg[i] + 1) & ~1;   // padded degree
    }
    part[t] = cnt;
    __syncthreads();
    for (int d = 1; d < 1024; d <<= 1) {
        int v = 0;
        if (t >= d) v = part[t - d];
        __syncthreads();
        if (t >= d) part[t] += v;
        __syncthreads();
    }
    int run = (t > 0) ? part[t - 1] : 0;
    for (int k = 0; k < 10; k++) {
        int i = base + k;
        if (i < N_) {
            offs[i] = run; cursor[i] = run;
            int dg = deg[i];
            dis[i] = dg > 0 ? rsqrtf((float)dg) : 0.f;
            run += (dg + 1) & ~1;
        }
    }
    if (t == 1023) offs[N_] = part[1023];
}

__global__ void k_scatter(const int* __restrict__ ei, const float* __restrict__ dis,
                          int* __restrict__ cursor, int2* __restrict__ csr_pack) {
    int e = blockIdx.x * 256 + threadIdx.x;
    if (e >= E_) return;
    int r = ei[e], c = ei[E_ + e];
    float nm = dis[r] * dis[c];
    int p = atomicAdd(&cursor[c], 1);
    csr_pack[p] = make_int2(r << 4, __float_as_int(nm));  // r*16 = float4 row base
}

// ---- per-slice stats reduce ------------------------------------------------
__global__ void k_red(const float2* __restrict__ part, float* __restrict__ st, int count) {
    __shared__ float rsm[4], rsq[4];
    int s = blockIdx.x, t = threadIdx.x, w = t >> 6, lane = t & 63;
    float sm = 0.f, sq = 0.f;
    for (int k = t; k < count; k += 256) {
        float2 p = part[s * BPS_ + k];
        sm += p.x; sq += p.y;
    }
    sm = wred(sm); sq = wred(sq);
    if (lane == 0) { rsm[w] = sm; rsq[w] = sq; }
    __syncthreads();
    if (t == 0) {
        st[s * 2]     = rsm[0] + rsm[1] + rsm[2] + rsm[3];
        st[s * 2 + 1] = rsq[0] + rsq[1] + rsq[2] + rsq[3];
    }
}

// ---- W~ / B~ gather: Wt[c,h] = sum nrm*gw[r,h], Bt likewise ---------------
__global__ void k_wb(const int* __restrict__ offs, const int2* __restrict__ csr_pack,
                     const float* __restrict__ gw, const float* __restrict__ gb,
                     float* __restrict__ Wt, float* __restrict__ Bt) {
    int t = threadIdx.x;
    int w = t >> 6, lane = t & 63;
    int sub = lane >> 4, hl = lane & 15;
    int n = blockIdx.x * 4 + w;
    const float4* W4 = (const float4*)gw;
    const float4* B4 = (const float4*)gb;
    int e0 = offs[n], e1 = offs[n + 1];
    float4 AW = make_float4(0, 0, 0, 0), AB = make_float4(0, 0, 0, 0);
    for (int e = e0 + sub * 2; e < e1; e += 8) {
        int4 mp = *(const int4*)&csr_pack[e];
        float m0 = __int_as_float(mp.y), m1 = __int_as_float(mp.w);
        int i0 = mp.x + hl, i1 = mp.z + hl;
        float4 a = W4[i0], b = W4[i1], c = B4[i0], d = B4[i1];
        fma4(m0, a, AW); fma4(m1, b, AW);
        fma4(m0, c, AB); fma4(m1, d, AB);
    }
    xred4(AW); xred4(AB);
    if (sub == 0) {
        ((float4*)Wt)[n * 16 + hl] = AW;
        ((float4*)Bt)[n * 16 + hl] = AB;
    }
}

// ---- pos projection: pos[N,64] -> pp[N,64] ---------------------------------
__global__ void k_posproj(const float* __restrict__ pos, const float* __restrict__ w1,
                          const float* __restrict__ b1, const float* __restrict__ w2,
                          const float* __restrict__ b2, float* __restrict__ out) {
    __shared__ float w1T[64 * 65], w2T[64 * 65];
    __shared__ float stage[4][64];
    int t = threadIdx.x;
    for (int k = t; k < 4096; k += 256) {
        int o = k >> 6, j = k & 63;
        w1T[j * 65 + o] = w1[k];
        w2T[j * 65 + o] = w2[k];
    }
    __syncthreads();
    int w = t >> 6, lane = t & 63;
    int n = blockIdx.x * 4 + w;
    float v = pos[n * 64 + lane];
    stage[w][lane] = v;
    float h = b1[lane];
#pragma unroll
    for (int j = 0; j < 64; j++) h = fmaf(w1T[j * 65 + lane], stage[w][j], h);
    h = fmaxf(h, 0.f);
    stage[w][lane] = h;
    float o2 = b2[lane];
#pragma unroll
    for (int j = 0; j < 64; j++) o2 = fmaf(w2T[j * 65 + lane], stage[w][j], o2);
    out[n * 64 + lane] = o2;
}

// ---- input projection (tile GEMM) + pos add + acc init + stats + x*w write -
__global__ void k_in(const float* __restrict__ xin, const float* __restrict__ iw1,
                     const float* __restrict__ ib1, const float* __restrict__ iw2,
                     const float* __restrict__ ib2, const float* __restrict__ pp,
                     const float* __restrict__ attn, const float* __restrict__ gw0,
                     float* __restrict__ xw, float* __restrict__ acc,
                     float2* __restrict__ part) {
    __shared__ __align__(16) float U[4096];
    __shared__ __align__(16) float B2s[4096];
    __shared__ float xin_s[192], iw1_s[192], bias1[64], bias2[64];
    __shared__ float rsm[4], rsq[4], sa0s;
    int t = threadIdx.x;
    int blk = blockIdx.x;
    int s = blk / NB64_, bn = blk % NB64_;
    int n0 = bn * 64;
    int nvalid = min(64, N_ - n0);
    stage_swz((const float4*)iw2, B2s, t);
    if (t < 192) {
        iw1_s[t] = iw1[t];
        int n = n0 + t / 3;
        xin_s[t] = (n < N_) ? xin[(size_t)s * (N_ * 3) + n0 * 3 + t] : 0.f;
    }
    if (t < 64) { bias1[t] = ib1[t]; bias2[t] = ib2[t]; }
    if (t == 0) sa0s = softmax4(attn, 0);
    __syncthreads();
    int tn = t >> 4, to = t & 15;
    int tn4 = tn << 2, to4 = to << 2;
    float h1[4][4];
#pragma unroll
    for (int i = 0; i < 4; i++) {
        float a0 = xin_s[(tn4 + i) * 3], a1 = xin_s[(tn4 + i) * 3 + 1],
              a2 = xin_s[(tn4 + i) * 3 + 2];
#pragma unroll
        for (int k = 0; k < 4; k++) {
            int o = to4 + k;
            float h = bias1[o];
            h = fmaf(iw1_s[o * 3], a0, h);
            h = fmaf(iw1_s[o * 3 + 1], a1, h);
            h = fmaf(iw1_s[o * 3 + 2], a2, h);
            h1[i][k] = fmaxf(h, 0.f);
        }
    }
#pragma unroll
    for (int i = 0; i < 4; i++)
        *(float4*)&U[(tn4 + i) * 64 + (to4 ^ tn4)] =
            make_float4(h1[i][0], h1[i][1], h1[i][2], h1[i][3]);
    __syncthreads();
    float ov[4][4];
#pragma unroll
    for (int i = 0; i < 4; i++)
#pragma unroll
        for (int k = 0; k < 4; k++) ov[i][k] = bias2[to4 + k];
    gemm64(U, B2s, tn4, to4, ov);
    __syncthreads();
#pragma unroll
    for (int i = 0; i < 4; i++)
        *(float4*)&U[(tn4 + i) * 64 + to4] =
            make_float4(ov[i][0], ov[i][1], ov[i][2], ov[i][3]);
    __syncthreads();
    const float4* pp4 = (const float4*)pp + n0 * 16;
    const float4* gw4 = (const float4*)gw0 + n0 * 16;
    float4* xw4 = (float4*)xw + (size_t)s * (NH_ / 4) + n0 * 16;
    float4* ac4 = (float4*)acc + (size_t)s * (NH_ / 4) + n0 * 16;
    float sa0 = sa0s;
    float sm = 0.f, sq = 0.f;
    for (int f = t; f < 1024; f += 256) {
        int r = f >> 4;
        if (r < nvalid) {
            float4 v = ((const float4*)U)[f];
            float4 p = pp4[f];
            v.x += p.x; v.y += p.y; v.z += p.z; v.w += p.w;
            float4 a;
            a.x = sa0 * v.x; a.y = sa0 * v.y; a.z = sa0 * v.z; a.w = sa0 * v.w;
            ac4[f] = a;
            sm += v.x + v.y + v.z + v.w;
            sq += v.x * v.x + v.y * v.y + v.z * v.z + v.w * v.w;
            float4 g = gw4[f];
            v.x *= g.x; v.y *= g.y; v.z *= g.z; v.w *= g.w;
            xw4[f] = v;
        }
    }
    int w = t >> 6, lane = t & 63;
    sm = wred(sm); sq = wred(sq);
    if (lane == 0) { rsm[w] = sm; rsq[w] = sq; }
    __syncthreads();
    if (t == 0) {
        float2 pr;
        pr.x = rsm[0] + rsm[1] + rsm[2] + rsm[3];
        pr.y = rsq[0] + rsq[1] + rsq[2] + rsq[3];
        part[s * BPS_ + bn] = pr;
    }
}

// ---- LightGCN propagate: 1 slice, 4 nodes/wave, LN folded ------------------
__global__ void k_prop(const float* __restrict__ xw, const int* __restrict__ offs,
                       const int2* __restrict__ csr_pack, const float* __restrict__ Wt,
                       const float* __restrict__ Bt, const float* __restrict__ st,
                       float* __restrict__ y, float2* __restrict__ part) {
    __shared__ float2 bs[4][4];   // [wave][group]
    int t = threadIdx.x;
    int w = t >> 6, lane = t & 63;
    int g = lane >> 4, hl = lane & 15;
    int orig = blockIdx.x;
    int gw = (orig & 7) * PROPPX_ + (orig >> 3);
    int s = gw / PROPNB_;          // slice 0..23; XCD k owns slices [3k,3k+3)
    int blkin = gw % PROPNB_;      // 0..624
    int n = blkin * 16 + w * 4 + g;
    const float4* xh = (const float4*)(xw + (size_t)s * NH_) + hl;
    int e0 = offs[n], e1 = offs[n + 1];
    float4 A = make_float4(0, 0, 0, 0);
    int e = e0;
    // unroll-2: 4 edges in flight per 16-lane group
    for (; e + 2 < e1; e += 4) {
        int4 m0 = *(const int4*)&csr_pack[e];
        int4 m1 = *(const int4*)&csr_pack[e + 2];
        float4 a = xh[m0.x], b = xh[m0.z];
        float4 c = xh[m1.x], d = xh[m1.z];
        fma4(__int_as_float(m0.y), a, A); fma4(__int_as_float(m0.w), b, A);
        fma4(__int_as_float(m1.y), c, A); fma4(__int_as_float(m1.w), d, A);
    }
    if (e < e1) {   // remaining pair (padded degree is even)
        int4 m0 = *(const int4*)&csr_pack[e];
        float4 a = xh[m0.x], b = xh[m0.z];
        fma4(__int_as_float(m0.y), a, A); fma4(__int_as_float(m0.w), b, A);
    }
    float mu = st[s * 2] * (1.f / NH_);
    float va = st[s * 2 + 1] * (1.f / NH_) - mu * mu;
    float rs = rsqrtf(va + EPS_);
    float c0 = -mu * rs;
    float4 wt = ((const float4*)Wt)[n * 16 + hl];
    float4 bt = ((const float4*)Bt)[n * 16 + hl];
    float4 y0;
    y0.x = fmaf(rs, A.x, fmaf(c0, wt.x, bt.x));
    y0.y = fmaf(rs, A.y, fmaf(c0, wt.y, bt.y));
    y0.z = fmaf(rs, A.z, fmaf(c0, wt.z, bt.z));
    y0.w = fmaf(rs, A.w, fmaf(c0, wt.w, bt.w));
    ((float4*)(y + (size_t)s * NH_ + (size_t)n * 64))[hl] = y0;
    // stats: 16-lane butterfly per group (sum, sumsq simultaneously live)
    float sm = y0.x + y0.y + y0.z + y0.w;
    float sq = fmaf(y0.x, y0.x, fmaf(y0.y, y0.y, fmaf(y0.z, y0.z, y0.w * y0.w)));
#pragma unroll
    for (int d = 1; d <= 8; d <<= 1) {
        sm += __shfl_xor(sm, d, 64);
        sq += __shfl_xor(sq, d, 64);
    }
    if (hl == 0) bs[w][g] = make_float2(sm, sq);
    __syncthreads();
    if (t == 0) {
        float psm = 0.f, psq = 0.f;
#pragma unroll
        for (int w2 = 0; w2 < 4; w2++)
#pragma unroll
            for (int g2 = 0; g2 < 4; g2++) {
                psm += bs[w2][g2].x;
                psq += bs[w2][g2].y;
            }
        part[s * BPS_ + blkin] = make_float2(psm, psq);
    }
}

// ---- LN2 (inline) + 12x12 period mix + skip-acc + slim stats ---------------
__global__ void k_mix(const float* __restrict__ y, const float* __restrict__ tnw,
                      const float* __restrict__ tnb, const float* __restrict__ tcw,
                      const float* __restrict__ tcb, const float* __restrict__ st2,
                      const float* __restrict__ attn, int ai,
                      const float* __restrict__ wnext, int wx,
                      float* __restrict__ xn, float* __restrict__ acc,
                      float2* __restrict__ part) {
    __shared__ float smu[12], srs[12], scw[144], scb[12];
    __shared__ float sred[24][16];
    __shared__ float sa;
    int t = threadIdx.x;
    int gt = blockIdx.x * 256 + t;
    int b = gt / NH_, r = gt % NH_;
    if (t < 12) {
        int s = b * 12 + t;
        float mu = st2[s * 2] * (1.f / NH_);
        float var = st2[s * 2 + 1] * (1.f / NH_) - mu * mu;
        smu[t] = mu;
        srs[t] = rsqrtf(var + EPS_);
        scb[t] = tcb[t];
    }
    if (t < 144) scw[t] = tcw[t];
    if (t == 0) sa = softmax4(attn, ai);
    __syncthreads();
    float wv = tnw[r], bv = tnb[r];
    float wn = wx ? wnext[r] : 0.f;
    float yn[12];
#pragma unroll
    for (int p = 0; p < 12; p++) {
        float v = y[(size_t)(b * 12 + p) * NH_ + r];
        yn[p] = (v - smu[p]) * srs[p] * wv + bv;
    }
    float ov[12];
#pragma unroll
    for (int q = 0; q < 12; q++) {
        float o = scb[q];
#pragma unroll
        for (int p = 0; p < 12; p++) o = fmaf(scw[q * 12 + p], yn[p], o);
        ov[q] = o;
        size_t idx = (size_t)(b * 12 + q) * NH_ + r;
        if (wx) xn[idx] = o * wn;
        acc[idx] += sa * o;
    }
    int lane = t & 63;
    int w = t >> 6;
#pragma unroll
    for (int q = 0; q < 12; q++) {
        float sm = ov[q];
        float sq = ov[q] * ov[q];
#pragma unroll
        for (int d = 1; d <= 8; d <<= 1) {
            sm += __shfl_xor(sm, d, 64);
            sq += __shfl_xor(sq, d, 64);
        }
        if ((lane & 15) == 0) {
            int widx = (w << 2) | (lane >> 4);
            sred[q * 2][widx] = sm;
            sred[q * 2 + 1][widx] = sq;
        }
    }
    __syncthreads();
    if (t < 12) {
        float psm = 0.f, psq = 0.f;
#pragma unroll
        for (int k = 0; k < 16; k++) {
            psm += sred[t * 2][k];
            psq += sred[t * 2 + 1][k];
        }
        int jb = blockIdx.x % BPS_;
        part[(b * 12 + t) * BPS_ + jb] = make_float2(psm, psq);
    }
}

// ---- final output projection (tile GEMM), in-place on d_out ----------------
__global__ void k_out(float* __restrict__ io, const float* __restrict__ w1,
                      const float* __restrict__ b1, const float* __restrict__ w2,
                      const float* __restrict__ b2) {
    __shared__ __align__(16) float U[4096];
    __shared__ __align__(16) float B1s[4096], B2s[4096];
    __shared__ float bias1[64], bias2[64];
    int t = threadIdx.x;
    int blk = blockIdx.x;
    int s = blk / NB64_, bn = blk % NB64_;
    int n0 = bn * 64;
    int nvalid = min(64, N_ - n0);
    const float4* io4 = (const float4*)io + (size_t)s * (NH_ / 4) + n0 * 16;
    stage_swz((const float4*)w1, B1s, t);
    stage_swz((const float4*)w2, B2s, t);
    stage_swz_guard(io4, U, t, nvalid);
    if (t < 64) { bias1[t] = b1[t]; bias2[t] = b2[t]; }
    __syncthreads();
    int tn = t >> 4, to = t & 15;
    int tn4 = tn << 2, to4 = to << 2;
    float ov[4][4];
#pragma unroll
    for (int i = 0; i < 4; i++)
#pragma unroll
        for (int k = 0; k < 4; k++) ov[i][k] = bias1[to4 + k];
    gemm64(U, B1s, tn4, to4, ov);
#pragma unroll
    for (int i = 0; i < 4; i++)
#pragma unroll
        for (int k = 0; k < 4; k++) ov[i][k] = fmaxf(ov[i][k], 0.f);
    __syncthreads();
#pragma unroll
    for (int i = 0; i < 4; i++)
        *(float4*)&U[(tn4 + i) * 64 + (to4 ^ tn4)] =
            make_float4(ov[i][0], ov[i][1], ov[i][2], ov[i][3]);
    __syncthreads();
    float ov2[4][4];
#pragma unroll
    for (int i = 0; i < 4; i++)
#pragma unroll
        for (int k = 0; k < 4; k++) ov2[i][k] = bias2[to4 + k];
    gemm64(U, B2s, tn4, to4, ov2);
    __syncthreads();
#pragma unroll
    for (int i = 0; i < 4; i++)
        *(float4*)&U[(tn4 + i) * 64 + to4] =
            make_float4(ov2[i][0], ov2[i][1], ov2[i][2], ov2[i][3]);
    __syncthreads();
    float4* io4w = (float4*)io + (size_t)s * (NH_ / 4) + n0 * 16;
    for (int f = t; f < 1024; f += 256) {
        int r = f >> 4;
        if (r < nvalid) io4w[f] = ((const float4*)U)[f];
    }
}

extern "C" void kernel_launch(void* const* d_in, const int* in_sizes, int n_in,
                              void* d_out, int out_size, void* d_ws, size_t ws_size,
                              hipStream_t stream) {
    (void)in_sizes; (void)n_in; (void)out_size; (void)ws_size;
    const float* x    = (const float*)d_in[0];
    const int*   ei   = (const int*)d_in[1];
    const float* pos  = (const float*)d_in[2];
    const float* iw1  = (const float*)d_in[3];
    const float* ib1  = (const float*)d_in[4];
    const float* iw2  = (const float*)d_in[5];
    const float* ib2  = (const float*)d_in[6];
    const float* pw1  = (const float*)d_in[7];
    const float* pb1  = (const float*)d_in[8];
    const float* pw2  = (const float*)d_in[9];
    const float* pb2  = (const float*)d_in[10];
    const float* attn = (const float*)d_in[11];
    const float* gnw  = (const float*)d_in[12];
    const float* gnb  = (const float*)d_in[13];
    const float* tnw  = (const float*)d_in[14];
    const float* tnb  = (const float*)d_in[15];
    const float* tcw  = (const float*)d_in[16];
    const float* tcb  = (const float*)d_in[17];
    const float* ow1  = (const float*)d_in[18];
    const float* ob1  = (const float*)d_in[19];
    const float* ow2  = (const float*)d_in[20];
    const float* ob2  = (const float*)d_in[21];
    float* out = (float*)d_out;

    float* xA = (float*)d_ws;
    float* xB = xA + (size_t)S_ * NH_;
    float* yb = xB + (size_t)S_ * NH_;
    float* pp = yb + (size_t)S_ * NH_;
    float* Wt = pp + NH_;
    float* Bt = Wt + NH_;
    int2* csr_pack = (int2*)(Bt + NH_);
    int* deg     = (int*)(csr_pack + EPAD_);
    int* offs    = deg + N_;
    int* cursor  = offs + N_ + 1;
    float* dis   = (float*)(cursor + N_);
    float* st1   = dis + N_;             // 4 iters * 24 slices * 2
    float* st2   = st1 + 4 * S_ * 2;     // 3 iters * 24 slices * 2
    float2* partA = (float2*)(((uintptr_t)(st2 + 3 * S_ * 2) + 15) & ~(uintptr_t)15);

    // zero csr_pack (pad entries must be {0, 0.0f}) and deg, contiguous region
    hipMemsetAsync(csr_pack, 0, (size_t)EPAD_ * sizeof(int2) + N_ * sizeof(int), stream);

    k_deg<<<(E_ + 255) / 256, 256, 0, stream>>>(ei, deg);
    k_scan<<<1, 1024, 0, stream>>>(deg, offs, cursor, dis);
    k_scatter<<<(E_ + 255) / 256, 256, 0, stream>>>(ei, dis, cursor, csr_pack);
    k_posproj<<<N_ / 4, 256, 0, stream>>>(pos, pw1, pb1, pw2, pb2, pp);
    k_in<<<S_ * NB64_, 256, 0, stream>>>(x, iw1, ib1, iw2, ib2, pp, attn, gnw,
                                         xA, out, partA);
    k_red<<<S_, 256, 0, stream>>>(partA, st1 + 0 * S_ * 2, NB64_);

    float* cur = xA;
    float* nxt = xB;
    for (int i = 0; i < NB_; i++) {
        k_wb<<<N_ / 4, 256, 0, stream>>>(offs, csr_pack, gnw + (size_t)i * NH_,
                                         gnb + (size_t)i * NH_, Wt, Bt);
        k_prop<<<PROPBLK_, 256, 0, stream>>>(cur, offs, csr_pack, Wt, Bt,
                                             st1 + i * S_ * 2, yb, partA);
        k_red<<<S_, 256, 0, stream>>>(partA, st2 + i * S_ * 2, PROPNB_);
        int wx = (i < NB_ - 1) ? 1 : 0;
        const float* wnext = gnw + (size_t)(i + 1 < NB_ ? i + 1 : 0) * NH_;
        k_mix<<<B_ * NH_ / 256, 256, 0, stream>>>(yb, tnw + (size_t)i * NH_,
                                                  tnb + (size_t)i * NH_, tcw + i * 144,
                                                  tcb + i * 12, st2 + i * S_ * 2, attn, i + 1,
                                                  wnext, wx, nxt, out, partA);
        if (i < NB_ - 1)
            k_red<<<S_, 256, 0, stream>>>(partA, st1 + (i + 1) * S_ * 2, BPS_);
        float* tmp = cur; cur = nxt; nxt = tmp;
    }
    k_out<<<S_ * NB64_, 256, 0, stream>>>(out, ow1, ob1, ow2, ob2);
}